// Round 8
// baseline (3742.287 us; speedup 1.0000x reference)
//
#include <hip/hip_runtime.h>
#include <math.h>

#define HID 25
#define STR 32   // padded node-feature row stride (128B rows)
#define CHUNK 1024
#define FBTHR 0.1f

typedef __attribute__((ext_vector_type(8))) short short8;
typedef __attribute__((ext_vector_type(4))) short short4v;
typedef __attribute__((ext_vector_type(4))) float f32x4;

__device__ __forceinline__ float gelu_f(float x) {
    return 0.5f * x * (1.0f + erff(x * 0.70710678118654752f));
}

__device__ __forceinline__ short f2bf(float f) {
    unsigned u = __float_as_uint(f);
    u = (u + 0x7fffu + ((u >> 16) & 1u)) >> 16;
    return (short)u;
}

// ---------------- node input linear ----------------
__global__ void k_node_in(const float* __restrict__ x, const float* __restrict__ token,
                          const float* __restrict__ W, const float* __restrict__ b,
                          float* __restrict__ hn, int N) {
    int gid = blockIdx.x * blockDim.x + threadIdx.x;
    int n = gid >> 5, j = gid & 31;
    if (n >= N || j >= HID) return;
    float acc = b[j];
    acc += x[n] * W[j];
    #pragma unroll
    for (int i = 0; i < 5; i++) acc += token[n * 5 + i] * W[(i + 1) * HID + j];
    hn[(size_t)n * STR + j] = acc;
}

// ---------------- edge MLP via MFMA (bf16), 16 edges per wave-tile ----------------
// k-mapping g(grp,j) = grp*4 + (j&3) + 16*(j>>2) applied identically to A and B
// fragments (any common k-permutation cancels in A.B). M/N index = lane&15.
// C/D: row=(lane>>4)*4+reg, col=lane&15 (m89-verified).
// Edges with |gate margin| < FBTHR appended to fllist for exact-fp32 re-decision.
__global__ __launch_bounds__(256) void k_edge_mlp_mfma(
    const int* __restrict__ ei, const float* __restrict__ x, const float* __restrict__ token,
    const float* __restrict__ attr, const float* __restrict__ gumbel,
    const float* __restrict__ W0, const float* __restrict__ b0,
    const float* __restrict__ W1, const float* __restrict__ b1,
    const float* __restrict__ W2, const float* __restrict__ b2,
    const float* __restrict__ W3, const float* __restrict__ b3,
    float* __restrict__ eval_, int* __restrict__ flcnt, int* __restrict__ fllist,
    int E, int ntiles, int nwaves) {
    __shared__ short hbuf[4][1024];   // per-wave 16x64 bf16 activation tile (swizzled)
    const int lane = threadIdx.x & 63;
    const int wv = threadIdx.x >> 6;
    const int wid = blockIdx.x * 4 + wv;
    const int grp = lane >> 4, r2 = lane & 15;

    // ---- weight fragments (registers, loaded once) ----
    short8 w0f[4], w1f[2][4], w2f[2][4];
    #pragma unroll
    for (int nt = 0; nt < 4; nt++) {
        int col = r2 + 16 * nt;
        #pragma unroll
        for (int j = 0; j < 8; j++) {
            int k = grp * 4 + (j & 3) + 16 * (j >> 2);
            w0f[nt][j] = (k < 13 && col < 50) ? f2bf(W0[k * 50 + col]) : (short)0;
        }
    }
    #pragma unroll
    for (int kt = 0; kt < 2; kt++) {
        #pragma unroll
        for (int nt = 0; nt < 4; nt++) {
            int col = r2 + 16 * nt;
            #pragma unroll
            for (int j = 0; j < 8; j++) {
                int k = kt * 32 + grp * 4 + (j & 3) + 16 * (j >> 2);
                w1f[kt][nt][j] = (k < 50 && col < 50) ? f2bf(W1[k * 50 + col]) : (short)0;
                w2f[kt][nt][j] = (k < 50 && col < 50) ? f2bf(W2[k * 50 + col]) : (short)0;
            }
        }
    }
    float b0v[4], b1v[4], b2v[4], w3dv[4];
    #pragma unroll
    for (int nt = 0; nt < 4; nt++) {
        int col = r2 + 16 * nt;
        b0v[nt] = (col < 50) ? b0[col] : 0.f;
        b1v[nt] = (col < 50) ? b1[col] : 0.f;
        b2v[nt] = (col < 50) ? b2[col] : 0.f;
        w3dv[nt] = (col < 50) ? (W3[col * 2 + 1] - W3[col * 2]) : 0.f;
    }
    const float b3d = b3[1] - b3[0];
    const f32x4 z4 = {0.f, 0.f, 0.f, 0.f};

    for (int t = wid; t < ntiles; t += nwaves) {
        const int base = t * 16;
        // ---- gather A0 (13 inputs, k-slots per group; elems 4-7 are k>=16 -> 0) ----
        int e = base + r2;
        float v0 = 0.f, v1 = 0.f, v2 = 0.f, v3 = 0.f;
        if (e < E) {
            if (grp == 0)      { int s = ei[e]; v0 = x[s]; v1 = token[s * 5]; v2 = token[s * 5 + 1]; v3 = token[s * 5 + 2]; }
            else if (grp == 1) { int s = ei[e]; int d = ei[E + e]; v0 = token[s * 5 + 3]; v1 = token[s * 5 + 4]; v2 = x[d]; v3 = token[d * 5]; }
            else if (grp == 2) { int d = ei[E + e]; v0 = token[d * 5 + 1]; v1 = token[d * 5 + 2]; v2 = token[d * 5 + 3]; v3 = token[d * 5 + 4]; }
            else               { v0 = attr[e]; }
        }
        short8 a0 = {f2bf(v0), f2bf(v1), f2bf(v2), f2bf(v3), 0, 0, 0, 0};

        // ---- layer 0 ----
        f32x4 acc0_0 = __builtin_amdgcn_mfma_f32_16x16x32_bf16(a0, w0f[0], z4, 0, 0, 0);
        f32x4 acc0_1 = __builtin_amdgcn_mfma_f32_16x16x32_bf16(a0, w0f[1], z4, 0, 0, 0);
        f32x4 acc0_2 = __builtin_amdgcn_mfma_f32_16x16x32_bf16(a0, w0f[2], z4, 0, 0, 0);
        f32x4 acc0_3 = __builtin_amdgcn_mfma_f32_16x16x32_bf16(a0, w0f[3], z4, 0, 0, 0);
        #pragma unroll
        for (int i = 0; i < 4; i++) {
            int row = grp * 4 + i;
            int sw = (row & 7) << 3;
            hbuf[wv][(row * 64 + r2)      ^ sw] = f2bf(gelu_f(acc0_0[i] + b0v[0]));
            hbuf[wv][(row * 64 + r2 + 16) ^ sw] = f2bf(gelu_f(acc0_1[i] + b0v[1]));
            hbuf[wv][(row * 64 + r2 + 32) ^ sw] = f2bf(gelu_f(acc0_2[i] + b0v[2]));
            hbuf[wv][(row * 64 + r2 + 48) ^ sw] = f2bf(gelu_f(acc0_3[i] + b0v[3]));
        }

        // ---- layer 1: read A frags (two b64 per kt), 2 K-steps x 4 N-tiles ----
        {
            int row = r2, sw = (row & 7) << 3;
            short4v lo0 = *(const short4v*)&hbuf[wv][(row * 64 + 0  + grp * 4) ^ sw];
            short4v hi0 = *(const short4v*)&hbuf[wv][(row * 64 + 16 + grp * 4) ^ sw];
            short4v lo1 = *(const short4v*)&hbuf[wv][(row * 64 + 32 + grp * 4) ^ sw];
            short4v hi1 = *(const short4v*)&hbuf[wv][(row * 64 + 48 + grp * 4) ^ sw];
            short8 aK0 = {lo0[0], lo0[1], lo0[2], lo0[3], hi0[0], hi0[1], hi0[2], hi0[3]};
            short8 aK1 = {lo1[0], lo1[1], lo1[2], lo1[3], hi1[0], hi1[1], hi1[2], hi1[3]};
            f32x4 a1_0 = __builtin_amdgcn_mfma_f32_16x16x32_bf16(aK1, w1f[1][0],
                         __builtin_amdgcn_mfma_f32_16x16x32_bf16(aK0, w1f[0][0], z4, 0, 0, 0), 0, 0, 0);
            f32x4 a1_1 = __builtin_amdgcn_mfma_f32_16x16x32_bf16(aK1, w1f[1][1],
                         __builtin_amdgcn_mfma_f32_16x16x32_bf16(aK0, w1f[0][1], z4, 0, 0, 0), 0, 0, 0);
            f32x4 a1_2 = __builtin_amdgcn_mfma_f32_16x16x32_bf16(aK1, w1f[1][2],
                         __builtin_amdgcn_mfma_f32_16x16x32_bf16(aK0, w1f[0][2], z4, 0, 0, 0), 0, 0, 0);
            f32x4 a1_3 = __builtin_amdgcn_mfma_f32_16x16x32_bf16(aK1, w1f[1][3],
                         __builtin_amdgcn_mfma_f32_16x16x32_bf16(aK0, w1f[0][3], z4, 0, 0, 0), 0, 0, 0);
            #pragma unroll
            for (int i = 0; i < 4; i++) {
                int rw = grp * 4 + i;
                int sw2 = (rw & 7) << 3;
                hbuf[wv][(rw * 64 + r2)      ^ sw2] = f2bf(gelu_f(a1_0[i] + b1v[0]));
                hbuf[wv][(rw * 64 + r2 + 16) ^ sw2] = f2bf(gelu_f(a1_1[i] + b1v[1]));
                hbuf[wv][(rw * 64 + r2 + 32) ^ sw2] = f2bf(gelu_f(a1_2[i] + b1v[2]));
                hbuf[wv][(rw * 64 + r2 + 48) ^ sw2] = f2bf(gelu_f(a1_3[i] + b1v[3]));
            }
        }

        // ---- layer 2 ----
        float h3v0[4], h3v1[4], h3v2[4], h3v3[4];
        {
            int row = r2, sw = (row & 7) << 3;
            short4v lo0 = *(const short4v*)&hbuf[wv][(row * 64 + 0  + grp * 4) ^ sw];
            short4v hi0 = *(const short4v*)&hbuf[wv][(row * 64 + 16 + grp * 4) ^ sw];
            short4v lo1 = *(const short4v*)&hbuf[wv][(row * 64 + 32 + grp * 4) ^ sw];
            short4v hi1 = *(const short4v*)&hbuf[wv][(row * 64 + 48 + grp * 4) ^ sw];
            short8 aK0 = {lo0[0], lo0[1], lo0[2], lo0[3], hi0[0], hi0[1], hi0[2], hi0[3]};
            short8 aK1 = {lo1[0], lo1[1], lo1[2], lo1[3], hi1[0], hi1[1], hi1[2], hi1[3]};
            f32x4 a2_0 = __builtin_amdgcn_mfma_f32_16x16x32_bf16(aK1, w2f[1][0],
                         __builtin_amdgcn_mfma_f32_16x16x32_bf16(aK0, w2f[0][0], z4, 0, 0, 0), 0, 0, 0);
            f32x4 a2_1 = __builtin_amdgcn_mfma_f32_16x16x32_bf16(aK1, w2f[1][1],
                         __builtin_amdgcn_mfma_f32_16x16x32_bf16(aK0, w2f[0][1], z4, 0, 0, 0), 0, 0, 0);
            f32x4 a2_2 = __builtin_amdgcn_mfma_f32_16x16x32_bf16(aK1, w2f[1][2],
                         __builtin_amdgcn_mfma_f32_16x16x32_bf16(aK0, w2f[0][2], z4, 0, 0, 0), 0, 0, 0);
            f32x4 a2_3 = __builtin_amdgcn_mfma_f32_16x16x32_bf16(aK1, w2f[1][3],
                         __builtin_amdgcn_mfma_f32_16x16x32_bf16(aK0, w2f[0][3], z4, 0, 0, 0), 0, 0, 0);
            #pragma unroll
            for (int i = 0; i < 4; i++) {
                h3v0[i] = gelu_f(a2_0[i] + b2v[0]);
                h3v1[i] = gelu_f(a2_1[i] + b2v[1]);
                h3v2[i] = gelu_f(a2_2[i] + b2v[2]);
                h3v3[i] = gelu_f(a2_3[i] + b2v[3]);
            }
        }

        // ---- z-diff + 16-lane group reduce ----
        float zp0, zp1, zp2, zp3;
        zp0 = h3v0[0] * w3dv[0] + h3v1[0] * w3dv[1] + h3v2[0] * w3dv[2] + h3v3[0] * w3dv[3];
        zp1 = h3v0[1] * w3dv[0] + h3v1[1] * w3dv[1] + h3v2[1] * w3dv[2] + h3v3[1] * w3dv[3];
        zp2 = h3v0[2] * w3dv[0] + h3v1[2] * w3dv[1] + h3v2[2] * w3dv[2] + h3v3[2] * w3dv[3];
        zp3 = h3v0[3] * w3dv[0] + h3v1[3] * w3dv[1] + h3v2[3] * w3dv[2] + h3v3[3] * w3dv[3];
        #pragma unroll
        for (int off = 1; off < 16; off <<= 1) {
            zp0 += __shfl_xor(zp0, off);
            zp1 += __shfl_xor(zp1, off);
            zp2 += __shfl_xor(zp2, off);
            zp3 += __shfl_xor(zp3, off);
        }
        if (r2 < 4) {
            int e2 = base + grp * 4 + r2;
            if (e2 < E) {
                float zsel = (r2 == 0) ? zp0 : (r2 == 1) ? zp1 : (r2 == 2) ? zp2 : zp3;
                float g0v = gumbel[2 * (long long)e2], g1v = gumbel[2 * (long long)e2 + 1];
                float m = zsel + b3d + g1v - g0v;
                eval_[e2] = (m > 0.f) ? 1.f : 0.f;
                if (fabsf(m) < FBTHR) {
                    int p = atomicAdd(flcnt, 1);
                    fllist[p] = e2;
                }
            }
        }
    }
}

// ---------------- exact-fp32 fallback for near-margin edges (R2-validated math) ----------------
__global__ __launch_bounds__(256) void k_edge_fb(
    const int* __restrict__ ei, const float* __restrict__ x, const float* __restrict__ token,
    const float* __restrict__ attr, const float* __restrict__ gumbel,
    const float* __restrict__ W0, const float* __restrict__ b0,
    const float* __restrict__ W1, const float* __restrict__ b1,
    const float* __restrict__ W2, const float* __restrict__ b2,
    const float* __restrict__ W3, const float* __restrict__ b3,
    const int* __restrict__ fllist, const int* __restrict__ flcnt,
    float* __restrict__ eval_, int E, int stride) {
    int cnt = *flcnt;
    for (int i = blockIdx.x * 256 + threadIdx.x; i < cnt; i += stride) {
        int e = fllist[i];
        int s = ei[e], d = ei[E + e];
        float in[13];
        in[0] = x[s];
        #pragma unroll
        for (int q = 0; q < 5; q++) in[1 + q] = token[s * 5 + q];
        in[6] = x[d];
        #pragma unroll
        for (int q = 0; q < 5; q++) in[7 + q] = token[d * 5 + q];
        in[12] = attr[e];

        float hA[50], hB[50];
        #pragma unroll
        for (int half = 0; half < 2; half++) {
            float t[25];
            #pragma unroll
            for (int jj = 0; jj < 25; jj++) t[jj] = b0[half * 25 + jj];
            #pragma unroll
            for (int k = 0; k < 13; k++) {
                float hv = in[k];
                #pragma unroll
                for (int jj = 0; jj < 25; jj++) t[jj] += hv * W0[k * 50 + half * 25 + jj];
            }
            #pragma unroll
            for (int jj = 0; jj < 25; jj++) hA[half * 25 + jj] = gelu_f(t[jj]);
        }
        #pragma unroll
        for (int half = 0; half < 2; half++) {
            float t[25];
            #pragma unroll
            for (int jj = 0; jj < 25; jj++) t[jj] = b1[half * 25 + jj];
            #pragma unroll
            for (int k = 0; k < 50; k++) {
                float hv = hA[k];
                #pragma unroll
                for (int jj = 0; jj < 25; jj++) t[jj] += hv * W1[k * 50 + half * 25 + jj];
            }
            #pragma unroll
            for (int jj = 0; jj < 25; jj++) hB[half * 25 + jj] = gelu_f(t[jj]);
        }
        #pragma unroll
        for (int half = 0; half < 2; half++) {
            float t[25];
            #pragma unroll
            for (int jj = 0; jj < 25; jj++) t[jj] = b2[half * 25 + jj];
            #pragma unroll
            for (int k = 0; k < 50; k++) {
                float hv = hB[k];
                #pragma unroll
                for (int jj = 0; jj < 25; jj++) t[jj] += hv * W2[k * 50 + half * 25 + jj];
            }
            #pragma unroll
            for (int jj = 0; jj < 25; jj++) hA[half * 25 + jj] = gelu_f(t[jj]);
        }
        float z0 = b3[0], z1 = b3[1];
        #pragma unroll
        for (int k = 0; k < 50; k++) { z0 += hA[k] * W3[k * 2]; z1 += hA[k] * W3[k * 2 + 1]; }
        float g0v = gumbel[2 * (long long)e], g1v = gumbel[2 * (long long)e + 1];
        eval_[e] = (z1 + g1v > z0 + g0v) ? 1.f : 0.f;
    }
}

// ---------------- CSR build: histogram + scan + scatter ----------------
__global__ void k_hist(const int* __restrict__ ei, int* __restrict__ cnt, int E) {
    int e = blockIdx.x * blockDim.x + threadIdx.x;
    if (e >= E) return;
    atomicAdd(&cnt[ei[E + e]], 1);
}

__global__ void k_scan_partial(const int* __restrict__ cnt, int* __restrict__ bsum, int N) {
    __shared__ int s[256];
    int b = blockIdx.x, t = threadIdx.x;
    int base = b * CHUNK + t * 4;
    int sum = 0;
    #pragma unroll
    for (int u = 0; u < 4; u++) { int idx = base + u; if (idx < N) sum += cnt[idx]; }
    s[t] = sum; __syncthreads();
    for (int off = 128; off > 0; off >>= 1) {
        if (t < off) s[t] += s[t + off];
        __syncthreads();
    }
    if (t == 0) bsum[b] = s[0];
}

__global__ void k_scan_top(const int* __restrict__ bsum, int* __restrict__ boff,
                           int* __restrict__ rowptr, int nb, int N, int E) {
    if (threadIdx.x == 0 && blockIdx.x == 0) {
        int run = 0;
        for (int i = 0; i < nb; i++) { boff[i] = run; run += bsum[i]; }
        rowptr[N] = E;
    }
}

__global__ void k_scan_final(const int* __restrict__ cnt, const int* __restrict__ boff,
                             int* __restrict__ rowptr, int* __restrict__ wpos, int N) {
    __shared__ int s[256];
    int b = blockIdx.x, t = threadIdx.x;
    int base = b * CHUNK + t * 4;
    int v0 = 0, v1 = 0, v2 = 0, v3 = 0;
    if (base     < N) v0 = cnt[base];
    if (base + 1 < N) v1 = cnt[base + 1];
    if (base + 2 < N) v2 = cnt[base + 2];
    if (base + 3 < N) v3 = cnt[base + 3];
    int ts = v0 + v1 + v2 + v3;
    s[t] = ts; __syncthreads();
    for (int off = 1; off < 256; off <<= 1) {
        int xv = (t >= off) ? s[t - off] : 0;
        __syncthreads();
        s[t] += xv;
        __syncthreads();
    }
    int excl = s[t] - ts + boff[b];
    if (base     < N) { rowptr[base]     = excl;                 wpos[base]     = excl; }
    if (base + 1 < N) { int p = excl + v0;           rowptr[base + 1] = p; wpos[base + 1] = p; }
    if (base + 2 < N) { int p = excl + v0 + v1;      rowptr[base + 2] = p; wpos[base + 2] = p; }
    if (base + 3 < N) { int p = excl + v0 + v1 + v2; rowptr[base + 3] = p; wpos[base + 3] = p; }
}

__global__ void k_scatter(const int* __restrict__ ei, int* __restrict__ wpos,
                          int* __restrict__ col, int E) {
    int e = blockIdx.x * blockDim.x + threadIdx.x;
    if (e >= E) return;
    int d = ei[E + e];
    int p = atomicAdd(&wpos[d], 1);
    col[p] = e;
}

// ---------------- per-layer node transform ----------------
__global__ void k_qkvs(const float* __restrict__ hn,
                       const float* __restrict__ Wq, const float* __restrict__ bq,
                       const float* __restrict__ Wk, const float* __restrict__ bk,
                       const float* __restrict__ Wv, const float* __restrict__ bv,
                       const float* __restrict__ Ws, const float* __restrict__ bs,
                       float* __restrict__ q, float* __restrict__ k, float* __restrict__ v,
                       float* __restrict__ hnext, int N) {
    __shared__ float sWq[625], sWk[625], sWv[625], sWs[625], sbq[25], sbk[25], sbv[25], sbs[25];
    for (int i = threadIdx.x; i < 625; i += blockDim.x) {
        sWq[i] = Wq[i]; sWk[i] = Wk[i]; sWv[i] = Wv[i]; sWs[i] = Ws[i];
    }
    if (threadIdx.x < 25) {
        sbq[threadIdx.x] = bq[threadIdx.x]; sbk[threadIdx.x] = bk[threadIdx.x];
        sbv[threadIdx.x] = bv[threadIdx.x]; sbs[threadIdx.x] = bs[threadIdx.x];
    }
    __syncthreads();
    int gid = blockIdx.x * blockDim.x + threadIdx.x;
    int n = gid >> 5, j = gid & 31;
    if (n >= N || j >= HID) return;
    float h[25];
    #pragma unroll
    for (int i = 0; i < 25; i++) h[i] = hn[(size_t)n * STR + i];
    float aq = sbq[j], ak = sbk[j], av = sbv[j], as = sbs[j];
    #pragma unroll
    for (int i = 0; i < 25; i++) {
        float hi = h[i];
        aq += hi * sWq[i * 25 + j];
        ak += hi * sWk[i * 25 + j];
        av += hi * sWv[i * 25 + j];
        as += hi * sWs[i * 25 + j];
    }
    size_t o = (size_t)n * STR + j;
    q[o] = aq; k[o] = ak; v[o] = av; hnext[o] = as;
}

// ---------------- fused node-centric attention ----------------
__global__ void k_attn_node(const int* __restrict__ rowptr, const int* __restrict__ col,
                            const int* __restrict__ ei,
                            const float* __restrict__ q, const float* __restrict__ kk,
                            const float* __restrict__ v, const float* __restrict__ attr,
                            const float* __restrict__ eval_,
                            const float* __restrict__ We, const float* __restrict__ be,
                            float* __restrict__ hnext, int N, int E) {
    int n = blockIdx.x * blockDim.x + threadIdx.x;
    if (n >= N) return;
    const float scale = 0.44721359549995793f;

    float qr[25];
    #pragma unroll
    for (int i = 0; i < 25; i++) qr[i] = q[(size_t)n * STR + i];

    float qW0[5], qW1[5], qbe[5];
    #pragma unroll
    for (int h = 0; h < 5; h++) {
        float a0 = 0.f, a1 = 0.f, ab = 0.f;
        #pragma unroll
        for (int c = 0; c < 5; c++) {
            int i = h * 5 + c;
            a0 += qr[i] * We[i];
            a1 += qr[i] * We[25 + i];
            ab += qr[i] * be[i];
        }
        qW0[h] = a0; qW1[h] = a1; qbe[h] = ab;
    }

    float accV[25];
    #pragma unroll
    for (int i = 0; i < 25; i++) accV[i] = 0.f;
    float den[5] = {0, 0, 0, 0, 0}, sA[5] = {0, 0, 0, 0, 0}, sG[5] = {0, 0, 0, 0, 0};

    int beg = rowptr[n], end = rowptr[n + 1];
    for (int p = beg; p < end; p++) {
        int e = col[p];
        int s = ei[e];
        float a_ = attr[e], gl = eval_[e];
        const float* kr = kk + (size_t)s * STR;
        const float* vr = v + (size_t)s * STR;
        #pragma unroll
        for (int h = 0; h < 5; h++) {
            float al = qW0[h] * a_ + qW1[h] * gl + qbe[h];
            #pragma unroll
            for (int c = 0; c < 5; c++) { int i = h * 5 + c; al += qr[i] * kr[i]; }
            float ex = expf(al * scale);
            den[h] += ex;
            sA[h] += ex * a_;
            sG[h] += ex * gl;
            #pragma unroll
            for (int c = 0; c < 5; c++) { int i = h * 5 + c; accV[i] += ex * vr[i]; }
        }
    }

    #pragma unroll
    for (int h = 0; h < 5; h++) {
        float inv = 1.f / (den[h] + 1e-16f);
        #pragma unroll
        for (int c = 0; c < 5; c++) {
            int i = h * 5 + c;
            float agg = (accV[i] + sA[h] * We[i] + sG[h] * We[25 + i] + den[h] * be[i]) * inv;
            hnext[(size_t)n * STR + i] += agg;
        }
    }
}

// ---------------- output ----------------
__global__ void k_out(const float* __restrict__ hn, const float* __restrict__ W,
                      const float* __restrict__ b, float* __restrict__ out, int N) {
    int n = blockIdx.x * blockDim.x + threadIdx.x;
    if (n >= N) return;
    float acc = b[0];
    #pragma unroll
    for (int i = 0; i < 25; i++) acc += hn[(size_t)n * STR + i] * W[i];
    out[n] = 1.f / (1.f + expf(-acc));
}

extern "C" void kernel_launch(void* const* d_in, const int* in_sizes, int n_in,
                              void* d_out, int out_size, void* d_ws, size_t ws_size,
                              hipStream_t stream) {
    const float* x      = (const float*)d_in[0];
    const float* token  = (const float*)d_in[1];
    const float* attr   = (const float*)d_in[2];
    const float* gumbel = (const float*)d_in[3];
    const int*   ei     = (const int*)d_in[4];
    const float* W0 = (const float*)d_in[5];
    const float* b0 = (const float*)d_in[6];
    const float* W1 = (const float*)d_in[7];
    const float* b1 = (const float*)d_in[8];
    const float* W2 = (const float*)d_in[9];
    const float* b2 = (const float*)d_in[10];
    const float* W3 = (const float*)d_in[11];
    const float* b3 = (const float*)d_in[12];
    const float* ilW = (const float*)d_in[13];
    const float* ilb = (const float*)d_in[14];
    const float* Wq = (const float*)d_in[15];
    const float* bq = (const float*)d_in[16];
    const float* Wk = (const float*)d_in[17];
    const float* bk = (const float*)d_in[18];
    const float* Wv = (const float*)d_in[19];
    const float* bv = (const float*)d_in[20];
    const float* We = (const float*)d_in[21];
    const float* be = (const float*)d_in[22];
    const float* Ws = (const float*)d_in[23];
    const float* bs = (const float*)d_in[24];
    const float* oW = (const float*)d_in[25];
    const float* ob = (const float*)d_in[26];

    const int N = in_sizes[0];
    const int E = in_sizes[2];
    const int nb_chunk = (N + CHUNK - 1) / CHUNK;

    char* ws = (char*)d_ws;
    size_t off = 0;
    auto alloc = [&](size_t nb) -> void* {
        void* p = ws + off;
        off += (nb + 255) & ~(size_t)255;
        return p;
    };
    float* hnA    = (float*)alloc((size_t)N * STR * 4);
    float* hnB    = (float*)alloc((size_t)N * STR * 4);
    float* q      = (float*)alloc((size_t)N * STR * 4);
    float* k      = (float*)alloc((size_t)N * STR * 4);
    float* v      = (float*)alloc((size_t)N * STR * 4);
    float* evalv  = (float*)alloc((size_t)E * 4);
    int*   cnt    = (int*)alloc((size_t)N * 4);
    int*   rowptr = (int*)alloc((size_t)(N + 1) * 4);
    int*   wpos   = (int*)alloc((size_t)N * 4);
    int*   bsum   = (int*)alloc((size_t)(nb_chunk + 1) * 4);
    int*   boff   = (int*)alloc((size_t)(nb_chunk + 1) * 4);
    int*   col    = (int*)alloc((size_t)E * 4);
    int*   flcnt  = (int*)alloc(256);
    int*   fllist = (int*)alloc((size_t)E * 4);

    int nb_n32 = (N * STR + 255) / 256;
    int nb_e   = (E + 255) / 256;
    int nb_n   = (N + 255) / 256;

    const int mlp_blocks = 2048;
    const int mlp_waves  = mlp_blocks * 4;
    const int ntiles     = (E + 15) / 16;
    const int fb_blocks  = 512;

    hipMemsetAsync(cnt, 0, (size_t)N * 4, stream);
    hipMemsetAsync(flcnt, 0, 4, stream);
    k_node_in<<<nb_n32, 256, 0, stream>>>(x, token, ilW, ilb, hnA, N);
    k_edge_mlp_mfma<<<mlp_blocks, 256, 0, stream>>>(ei, x, token, attr, gumbel,
                                                    W0, b0, W1, b1, W2, b2, W3, b3,
                                                    evalv, flcnt, fllist, E, ntiles, mlp_waves);
    k_edge_fb<<<fb_blocks, 256, 0, stream>>>(ei, x, token, attr, gumbel,
                                             W0, b0, W1, b1, W2, b2, W3, b3,
                                             fllist, flcnt, evalv, E, fb_blocks * 256);
    k_hist<<<nb_e, 256, 0, stream>>>(ei, cnt, E);
    k_scan_partial<<<nb_chunk, 256, 0, stream>>>(cnt, bsum, N);
    k_scan_top<<<1, 64, 0, stream>>>(bsum, boff, rowptr, nb_chunk, N, E);
    k_scan_final<<<nb_chunk, 256, 0, stream>>>(cnt, boff, rowptr, wpos, N);
    k_scatter<<<nb_e, 256, 0, stream>>>(ei, wpos, col, E);

    float* cur = hnA;
    float* nxt = hnB;
    for (int l = 0; l < 3; l++) {
        k_qkvs<<<nb_n32, 256, 0, stream>>>(cur, Wq + l * 625, bq + l * 25,
                                           Wk + l * 625, bk + l * 25,
                                           Wv + l * 625, bv + l * 25,
                                           Ws + l * 625, bs + l * 25,
                                           q, k, v, nxt, N);
        k_attn_node<<<nb_n, 256, 0, stream>>>(rowptr, col, ei, q, k, v, attr, evalv,
                                              We + l * 50, be + l * 25, nxt, N, E);
        float* t = cur; cur = nxt; nxt = t;
    }
    k_out<<<nb_n, 256, 0, stream>>>(cur, oW, ob, (float*)d_out, N);
}

// Round 9
// 3066.077 us; speedup vs baseline: 1.2205x; 1.2205x over previous
//
#include <hip/hip_runtime.h>
#include <math.h>

#define HID 25
#define STR 32   // padded node-feature row stride (128B rows)
#define CHUNK 1024
#define FBTHR 0.1f

typedef __attribute__((ext_vector_type(8))) short short8;
typedef __attribute__((ext_vector_type(4))) short short4v;
typedef __attribute__((ext_vector_type(4))) float f32x4;

__device__ __forceinline__ float gelu_f(float x) {
    return 0.5f * x * (1.0f + erff(x * 0.70710678118654752f));
}

// Branchless gelu: A&S 7.1.26 erf approx, |err| <= 1.5e-7 (<< FBTHR; gate-safe,
// fallback recomputes with true erff). One basic block -> scheduler freedom.
__device__ __forceinline__ float gelu_fast(float x) {
    float y = fabsf(x) * 0.70710678118654752f;
    float t = 1.0f / fmaf(0.3275911f, y, 1.0f);
    float p = fmaf(1.061405429f, t, -1.453152027f);
    p = fmaf(p, t, 1.421413741f);
    p = fmaf(p, t, -0.284496736f);
    p = fmaf(p, t, 0.254829592f);
    p = p * t;
    float e = __expf(-y * y);
    float erfv = fmaf(-p, e, 1.0f);
    float r = copysignf(erfv, x);
    return 0.5f * x * (1.0f + r);
}

__device__ __forceinline__ short f2bf(float f) {
    unsigned u = __float_as_uint(f);
    u = (u + 0x7fffu + ((u >> 16) & 1u)) >> 16;
    return (short)u;
}

// gather 4 consecutive MLP-input slots (k = grp*4 .. grp*4+3) for edge e
__device__ __forceinline__ void gather4(int e, int E, const int* __restrict__ ei,
                                        const float* __restrict__ xt6,
                                        const float* __restrict__ attr, int grp,
                                        float& v0, float& v1, float& v2, float& v3) {
    v0 = v1 = v2 = v3 = 0.f;
    if (e < E) {
        if (grp == 0) {
            const float4 f = *(const float4*)&xt6[(size_t)ei[e] * 8];
            v0 = f.x; v1 = f.y; v2 = f.z; v3 = f.w;
        } else if (grp == 1) {
            int s = ei[e], d = ei[E + e];
            const float2 lo = *(const float2*)&xt6[(size_t)s * 8 + 4];
            const float2 hi = *(const float2*)&xt6[(size_t)d * 8];
            v0 = lo.x; v1 = lo.y; v2 = hi.x; v3 = hi.y;
        } else if (grp == 2) {
            int d = ei[E + e];
            const float2 lo = *(const float2*)&xt6[(size_t)d * 8 + 2];
            const float2 hi = *(const float2*)&xt6[(size_t)d * 8 + 4];
            v0 = lo.x; v1 = lo.y; v2 = hi.x; v3 = hi.y;
        } else {
            v0 = attr[e];
        }
    }
}

// ---------------- node input linear + packed xt6 ----------------
__global__ void k_node_in(const float* __restrict__ x, const float* __restrict__ token,
                          const float* __restrict__ W, const float* __restrict__ b,
                          float* __restrict__ hn, float* __restrict__ xt6, int N) {
    int gid = blockIdx.x * blockDim.x + threadIdx.x;
    int n = gid >> 5, j = gid & 31;
    if (n >= N) return;
    if (j < 8) xt6[(size_t)n * 8 + j] = (j == 0) ? x[n] : ((j < 6) ? token[n * 5 + j - 1] : 0.f);
    if (j >= HID) return;
    float acc = b[j];
    acc += x[n] * W[j];
    #pragma unroll
    for (int i = 0; i < 5; i++) acc += token[n * 5 + i] * W[(i + 1) * HID + j];
    hn[(size_t)n * STR + j] = acc;
}

// ---------------- edge MLP via MFMA (bf16), TWO 16-edge tiles per wave-iter ----------------
__global__ __launch_bounds__(256) void k_edge_mlp_mfma(
    const int* __restrict__ ei, const float* __restrict__ xt6,
    const float* __restrict__ attr, const float* __restrict__ gumbel,
    const float* __restrict__ W0, const float* __restrict__ b0,
    const float* __restrict__ W1, const float* __restrict__ b1,
    const float* __restrict__ W2, const float* __restrict__ b2,
    const float* __restrict__ W3, const float* __restrict__ b3,
    float* __restrict__ eval_, int* __restrict__ flcnt, int* __restrict__ fllist,
    int E, int ntiles, int nwaves) {
    __shared__ short hbuf[4][2][1024];   // [wave][tile][16x64 bf16 swizzled]
    const int lane = threadIdx.x & 63;
    const int wv = threadIdx.x >> 6;
    const int wid = blockIdx.x * 4 + wv;
    const int grp = lane >> 4, r2 = lane & 15;

    // ---- weight fragments (registers, loaded once) ----
    short8 w0f[4], w1f[2][4], w2f[2][4];
    #pragma unroll
    for (int nt = 0; nt < 4; nt++) {
        int col = r2 + 16 * nt;
        #pragma unroll
        for (int j = 0; j < 8; j++) {
            int k = grp * 4 + (j & 3) + 16 * (j >> 2);
            w0f[nt][j] = (k < 13 && col < 50) ? f2bf(W0[k * 50 + col]) : (short)0;
        }
    }
    #pragma unroll
    for (int kt = 0; kt < 2; kt++) {
        #pragma unroll
        for (int nt = 0; nt < 4; nt++) {
            int col = r2 + 16 * nt;
            #pragma unroll
            for (int j = 0; j < 8; j++) {
                int k = kt * 32 + grp * 4 + (j & 3) + 16 * (j >> 2);
                w1f[kt][nt][j] = (k < 50 && col < 50) ? f2bf(W1[k * 50 + col]) : (short)0;
                w2f[kt][nt][j] = (k < 50 && col < 50) ? f2bf(W2[k * 50 + col]) : (short)0;
            }
        }
    }
    float b0v[4], b1v[4], b2v[4], w3dv[4];
    #pragma unroll
    for (int nt = 0; nt < 4; nt++) {
        int col = r2 + 16 * nt;
        b0v[nt] = (col < 50) ? b0[col] : 0.f;
        b1v[nt] = (col < 50) ? b1[col] : 0.f;
        b2v[nt] = (col < 50) ? b2[col] : 0.f;
        w3dv[nt] = (col < 50) ? (W3[col * 2 + 1] - W3[col * 2]) : 0.f;
    }
    const float b3d = b3[1] - b3[0];
    const f32x4 z4 = {0.f, 0.f, 0.f, 0.f};

    short* hbA = &hbuf[wv][0][0];
    short* hbB = &hbuf[wv][1][0];

    auto store_layer = [&](short* hb, const f32x4& c0, const f32x4& c1,
                           const f32x4& c2, const f32x4& c3, const float* bv) {
        #pragma unroll
        for (int i = 0; i < 4; i++) {
            int row = grp * 4 + i;
            int sw = (row & 7) << 3;
            hb[(row * 64 + r2)      ^ sw] = f2bf(gelu_fast(c0[i] + bv[0]));
            hb[(row * 64 + r2 + 16) ^ sw] = f2bf(gelu_fast(c1[i] + bv[1]));
            hb[(row * 64 + r2 + 32) ^ sw] = f2bf(gelu_fast(c2[i] + bv[2]));
            hb[(row * 64 + r2 + 48) ^ sw] = f2bf(gelu_fast(c3[i] + bv[3]));
        }
    };
    auto load_frags = [&](const short* hb, short8& k0, short8& k1) {
        int row = r2, sw = (row & 7) << 3;
        short4v lo0 = *(const short4v*)&hb[(row * 64 + 0  + grp * 4) ^ sw];
        short4v hi0 = *(const short4v*)&hb[(row * 64 + 16 + grp * 4) ^ sw];
        short4v lo1 = *(const short4v*)&hb[(row * 64 + 32 + grp * 4) ^ sw];
        short4v hi1 = *(const short4v*)&hb[(row * 64 + 48 + grp * 4) ^ sw];
        k0 = short8{lo0[0], lo0[1], lo0[2], lo0[3], hi0[0], hi0[1], hi0[2], hi0[3]};
        k1 = short8{lo1[0], lo1[1], lo1[2], lo1[3], hi1[0], hi1[1], hi1[2], hi1[3]};
    };

    for (int t0 = wid * 2; t0 < ntiles; t0 += nwaves * 2) {
        const int baseA = t0 * 16, baseB = baseA + 16;

        // ---- gather both tiles ----
        float gA0, gA1, gA2, gA3, gB0, gB1, gB2, gB3;
        gather4(baseA + r2, E, ei, xt6, attr, grp, gA0, gA1, gA2, gA3);
        gather4(baseB + r2, E, ei, xt6, attr, grp, gB0, gB1, gB2, gB3);
        short8 aA = {f2bf(gA0), f2bf(gA1), f2bf(gA2), f2bf(gA3), 0, 0, 0, 0};
        short8 aB = {f2bf(gB0), f2bf(gB1), f2bf(gB2), f2bf(gB3), 0, 0, 0, 0};

        // ---- layer 0 ----
        f32x4 cA0 = __builtin_amdgcn_mfma_f32_16x16x32_bf16(aA, w0f[0], z4, 0, 0, 0);
        f32x4 cA1 = __builtin_amdgcn_mfma_f32_16x16x32_bf16(aA, w0f[1], z4, 0, 0, 0);
        f32x4 cA2 = __builtin_amdgcn_mfma_f32_16x16x32_bf16(aA, w0f[2], z4, 0, 0, 0);
        f32x4 cA3 = __builtin_amdgcn_mfma_f32_16x16x32_bf16(aA, w0f[3], z4, 0, 0, 0);
        f32x4 cB0 = __builtin_amdgcn_mfma_f32_16x16x32_bf16(aB, w0f[0], z4, 0, 0, 0);
        f32x4 cB1 = __builtin_amdgcn_mfma_f32_16x16x32_bf16(aB, w0f[1], z4, 0, 0, 0);
        f32x4 cB2 = __builtin_amdgcn_mfma_f32_16x16x32_bf16(aB, w0f[2], z4, 0, 0, 0);
        f32x4 cB3 = __builtin_amdgcn_mfma_f32_16x16x32_bf16(aB, w0f[3], z4, 0, 0, 0);
        store_layer(hbA, cA0, cA1, cA2, cA3, b0v);
        store_layer(hbB, cB0, cB1, cB2, cB3, b0v);

        // ---- layer 1 ----
        short8 kA0, kA1, kB0, kB1;
        load_frags(hbA, kA0, kA1);
        load_frags(hbB, kB0, kB1);
        cA0 = __builtin_amdgcn_mfma_f32_16x16x32_bf16(kA1, w1f[1][0],
              __builtin_amdgcn_mfma_f32_16x16x32_bf16(kA0, w1f[0][0], z4, 0, 0, 0), 0, 0, 0);
        cA1 = __builtin_amdgcn_mfma_f32_16x16x32_bf16(kA1, w1f[1][1],
              __builtin_amdgcn_mfma_f32_16x16x32_bf16(kA0, w1f[0][1], z4, 0, 0, 0), 0, 0, 0);
        cA2 = __builtin_amdgcn_mfma_f32_16x16x32_bf16(kA1, w1f[1][2],
              __builtin_amdgcn_mfma_f32_16x16x32_bf16(kA0, w1f[0][2], z4, 0, 0, 0), 0, 0, 0);
        cA3 = __builtin_amdgcn_mfma_f32_16x16x32_bf16(kA1, w1f[1][3],
              __builtin_amdgcn_mfma_f32_16x16x32_bf16(kA0, w1f[0][3], z4, 0, 0, 0), 0, 0, 0);
        cB0 = __builtin_amdgcn_mfma_f32_16x16x32_bf16(kB1, w1f[1][0],
              __builtin_amdgcn_mfma_f32_16x16x32_bf16(kB0, w1f[0][0], z4, 0, 0, 0), 0, 0, 0);
        cB1 = __builtin_amdgcn_mfma_f32_16x16x32_bf16(kB1, w1f[1][1],
              __builtin_amdgcn_mfma_f32_16x16x32_bf16(kB0, w1f[0][1], z4, 0, 0, 0), 0, 0, 0);
        cB2 = __builtin_amdgcn_mfma_f32_16x16x32_bf16(kB1, w1f[1][2],
              __builtin_amdgcn_mfma_f32_16x16x32_bf16(kB0, w1f[0][2], z4, 0, 0, 0), 0, 0, 0);
        cB3 = __builtin_amdgcn_mfma_f32_16x16x32_bf16(kB1, w1f[1][3],
              __builtin_amdgcn_mfma_f32_16x16x32_bf16(kB0, w1f[0][3], z4, 0, 0, 0), 0, 0, 0);
        store_layer(hbA, cA0, cA1, cA2, cA3, b1v);
        store_layer(hbB, cB0, cB1, cB2, cB3, b1v);

        // ---- layer 2 ----
        load_frags(hbA, kA0, kA1);
        load_frags(hbB, kB0, kB1);
        cA0 = __builtin_amdgcn_mfma_f32_16x16x32_bf16(kA1, w2f[1][0],
              __builtin_amdgcn_mfma_f32_16x16x32_bf16(kA0, w2f[0][0], z4, 0, 0, 0), 0, 0, 0);
        cA1 = __builtin_amdgcn_mfma_f32_16x16x32_bf16(kA1, w2f[1][1],
              __builtin_amdgcn_mfma_f32_16x16x32_bf16(kA0, w2f[0][1], z4, 0, 0, 0), 0, 0, 0);
        cA2 = __builtin_amdgcn_mfma_f32_16x16x32_bf16(kA1, w2f[1][2],
              __builtin_amdgcn_mfma_f32_16x16x32_bf16(kA0, w2f[0][2], z4, 0, 0, 0), 0, 0, 0);
        cA3 = __builtin_amdgcn_mfma_f32_16x16x32_bf16(kA1, w2f[1][3],
              __builtin_amdgcn_mfma_f32_16x16x32_bf16(kA0, w2f[0][3], z4, 0, 0, 0), 0, 0, 0);
        cB0 = __builtin_amdgcn_mfma_f32_16x16x32_bf16(kB1, w2f[1][0],
              __builtin_amdgcn_mfma_f32_16x16x32_bf16(kB0, w2f[0][0], z4, 0, 0, 0), 0, 0, 0);
        cB1 = __builtin_amdgcn_mfma_f32_16x16x32_bf16(kB1, w2f[1][1],
              __builtin_amdgcn_mfma_f32_16x16x32_bf16(kB0, w2f[0][1], z4, 0, 0, 0), 0, 0, 0);
        cB2 = __builtin_amdgcn_mfma_f32_16x16x32_bf16(kB1, w2f[1][2],
              __builtin_amdgcn_mfma_f32_16x16x32_bf16(kB0, w2f[0][2], z4, 0, 0, 0), 0, 0, 0);
        cB3 = __builtin_amdgcn_mfma_f32_16x16x32_bf16(kB1, w2f[1][3],
              __builtin_amdgcn_mfma_f32_16x16x32_bf16(kB0, w2f[0][3], z4, 0, 0, 0), 0, 0, 0);

        // ---- h3 gelu + z-diff + 16-lane group reduce, both tiles ----
        float zA0 = 0.f, zA1 = 0.f, zA2 = 0.f, zA3 = 0.f;
        float zB0 = 0.f, zB1 = 0.f, zB2 = 0.f, zB3 = 0.f;
        #pragma unroll
        for (int i = 0; i < 4; i++) {
            float hA0 = gelu_fast(cA0[i] + b2v[0]), hA1 = gelu_fast(cA1[i] + b2v[1]);
            float hA2 = gelu_fast(cA2[i] + b2v[2]), hA3 = gelu_fast(cA3[i] + b2v[3]);
            float hB0 = gelu_fast(cB0[i] + b2v[0]), hB1 = gelu_fast(cB1[i] + b2v[1]);
            float hB2 = gelu_fast(cB2[i] + b2v[2]), hB3 = gelu_fast(cB3[i] + b2v[3]);
            float zA = hA0 * w3dv[0] + hA1 * w3dv[1] + hA2 * w3dv[2] + hA3 * w3dv[3];
            float zB = hB0 * w3dv[0] + hB1 * w3dv[1] + hB2 * w3dv[2] + hB3 * w3dv[3];
            if (i == 0) { zA0 = zA; zB0 = zB; }
            else if (i == 1) { zA1 = zA; zB1 = zB; }
            else if (i == 2) { zA2 = zA; zB2 = zB; }
            else { zA3 = zA; zB3 = zB; }
        }
        #pragma unroll
        for (int off = 1; off < 16; off <<= 1) {
            zA0 += __shfl_xor(zA0, off); zA1 += __shfl_xor(zA1, off);
            zA2 += __shfl_xor(zA2, off); zA3 += __shfl_xor(zA3, off);
            zB0 += __shfl_xor(zB0, off); zB1 += __shfl_xor(zB1, off);
            zB2 += __shfl_xor(zB2, off); zB3 += __shfl_xor(zB3, off);
        }
        if (r2 < 4) {
            int eA = baseA + grp * 4 + r2;
            if (eA < E) {
                float zsel = (r2 == 0) ? zA0 : (r2 == 1) ? zA1 : (r2 == 2) ? zA2 : zA3;
                float g0v = gumbel[2 * (long long)eA], g1v = gumbel[2 * (long long)eA + 1];
                float m = zsel + b3d + g1v - g0v;
                eval_[eA] = (m > 0.f) ? 1.f : 0.f;
                if (fabsf(m) < FBTHR) { int p = atomicAdd(flcnt, 1); fllist[p] = eA; }
            }
            int eB = baseB + grp * 4 + r2;
            if (eB < E) {
                float zsel = (r2 == 0) ? zB0 : (r2 == 1) ? zB1 : (r2 == 2) ? zB2 : zB3;
                float g0v = gumbel[2 * (long long)eB], g1v = gumbel[2 * (long long)eB + 1];
                float m = zsel + b3d + g1v - g0v;
                eval_[eB] = (m > 0.f) ? 1.f : 0.f;
                if (fabsf(m) < FBTHR) { int p = atomicAdd(flcnt, 1); fllist[p] = eB; }
            }
        }
    }
}

// ---------------- wave-cooperative exact-fp32 fallback (R7 version-B structure) ----------------
__global__ __launch_bounds__(256) void k_edge_fb(
    const int* __restrict__ ei, const float* __restrict__ xt6,
    const float* __restrict__ attr, const float* __restrict__ gumbel,
    const float* __restrict__ W0, const float* __restrict__ b0,
    const float* __restrict__ W1, const float* __restrict__ b1,
    const float* __restrict__ W2, const float* __restrict__ b2,
    const float* __restrict__ W3, const float* __restrict__ b3,
    const int* __restrict__ fllist, const int* __restrict__ flcnt,
    float* __restrict__ eval_, int E, int nwaves) {
    __shared__ float buf[4][2][2][64];
    const int lane = threadIdx.x & 63;
    const int wv = threadIdx.x >> 6;
    const int wid = blockIdx.x * 4 + wv;
    const int jw = (lane < 50) ? lane : 49;

    float w0r[16], w1r[52], w2r[52];
    #pragma unroll
    for (int k = 0; k < 13; k++) w0r[k] = W0[k * 50 + jw];
    w0r[13] = 0.f; w0r[14] = 0.f; w0r[15] = 0.f;
    #pragma unroll
    for (int k = 0; k < 50; k++) w1r[k] = W1[k * 50 + jw];
    w1r[50] = 0.f; w1r[51] = 0.f;
    #pragma unroll
    for (int k = 0; k < 50; k++) w2r[k] = W2[k * 50 + jw];
    w2r[50] = 0.f; w2r[51] = 0.f;
    const float b0r = b0[jw], b1r = b1[jw], b2r = b2[jw];
    const float b3_0 = b3[0], b3_1 = b3[1];
    const float w3d = (lane < 50) ? (W3[lane * 2 + 1] - W3[lane * 2]) : 0.f;

    const int g = lane >> 4, r = lane & 15;
    const int cnt = *flcnt;

    for (int base = wid * 2; base < cnt; base += nwaves * 2) {
        if (g < 2) {
            int idx = base + g;
            float val = 0.f;
            if (idx < cnt && r < 13) {
                int e = fllist[idx];
                if (r == 12) val = attr[e];
                else if (r < 6) val = xt6[(size_t)ei[e] * 8 + r];
                else val = xt6[(size_t)ei[E + e] * 8 + (r - 6)];
            }
            buf[wv][0][g][r] = val;
        }

        const float4* a4 = (const float4*)(&buf[wv][0][0][0]);
        const float4* c4 = (const float4*)(&buf[wv][0][1][0]);
        float tA = b0r, tB = b0r;
        #pragma unroll
        for (int c = 0; c < 4; c++) {
            float4 a = a4[c], b = c4[c];
            tA += a.x * w0r[4 * c];     tB += b.x * w0r[4 * c];
            tA += a.y * w0r[4 * c + 1]; tB += b.y * w0r[4 * c + 1];
            tA += a.z * w0r[4 * c + 2]; tB += b.z * w0r[4 * c + 2];
            tA += a.w * w0r[4 * c + 3]; tB += b.w * w0r[4 * c + 3];
        }
        buf[wv][1][0][lane] = gelu_f(tA);
        buf[wv][1][1][lane] = gelu_f(tB);

        const float4* p4 = (const float4*)(&buf[wv][1][0][0]);
        const float4* q4 = (const float4*)(&buf[wv][1][1][0]);
        tA = b1r; tB = b1r;
        #pragma unroll
        for (int c = 0; c < 13; c++) {
            float4 a = p4[c], b = q4[c];
            tA += a.x * w1r[4 * c];     tB += b.x * w1r[4 * c];
            tA += a.y * w1r[4 * c + 1]; tB += b.y * w1r[4 * c + 1];
            tA += a.z * w1r[4 * c + 2]; tB += b.z * w1r[4 * c + 2];
            tA += a.w * w1r[4 * c + 3]; tB += b.w * w1r[4 * c + 3];
        }
        buf[wv][0][0][lane] = gelu_f(tA);
        buf[wv][0][1][lane] = gelu_f(tB);

        tA = b2r; tB = b2r;
        #pragma unroll
        for (int c = 0; c < 13; c++) {
            float4 a = a4[c], b = c4[c];
            tA += a.x * w2r[4 * c];     tB += b.x * w2r[4 * c];
            tA += a.y * w2r[4 * c + 1]; tB += b.y * w2r[4 * c + 1];
            tA += a.z * w2r[4 * c + 2]; tB += b.z * w2r[4 * c + 2];
            tA += a.w * w2r[4 * c + 3]; tB += b.w * w2r[4 * c + 3];
        }
        float h3A = gelu_f(tA), h3B = gelu_f(tB);
        buf[wv][1][0][lane] = h3A;
        buf[wv][1][1][lane] = h3B;

        float zA = h3A * w3d, zB = h3B * w3d;
        #pragma unroll
        for (int off = 32; off > 0; off >>= 1) {
            zA += __shfl_xor(zA, off);
            zB += __shfl_xor(zB, off);
        }

        if (lane < 2) {
            int idx = base + lane;
            if (idx < cnt) {
                int e = fllist[idx];
                float z = (lane == 0) ? zA : zB;
                float g0v = gumbel[2 * (long long)e], g1v = gumbel[2 * (long long)e + 1];
                float m = z + (b3_1 - b3_0) + g1v - g0v;
                float dec;
                if (fabsf(m) < 1e-4f) {
                    float z0 = 0.f, z1 = 0.f;
                    for (int j = 0; j < 50; j++) {
                        float h = buf[wv][1][lane][j];
                        z0 += h * W3[2 * j];
                        z1 += h * W3[2 * j + 1];
                    }
                    z0 += b3_0; z1 += b3_1;
                    dec = (z1 + g1v > z0 + g0v) ? 1.f : 0.f;
                } else {
                    dec = (m > 0.f) ? 1.f : 0.f;
                }
                eval_[e] = dec;
            }
        }
    }
}

// ---------------- CSR build: histogram + scan + scatter ----------------
__global__ void k_hist(const int* __restrict__ ei, int* __restrict__ cnt, int E) {
    int e = blockIdx.x * blockDim.x + threadIdx.x;
    if (e >= E) return;
    atomicAdd(&cnt[ei[E + e]], 1);
}

__global__ void k_scan_partial(const int* __restrict__ cnt, int* __restrict__ bsum, int N) {
    __shared__ int s[256];
    int b = blockIdx.x, t = threadIdx.x;
    int base = b * CHUNK + t * 4;
    int sum = 0;
    #pragma unroll
    for (int u = 0; u < 4; u++) { int idx = base + u; if (idx < N) sum += cnt[idx]; }
    s[t] = sum; __syncthreads();
    for (int off = 128; off > 0; off >>= 1) {
        if (t < off) s[t] += s[t + off];
        __syncthreads();
    }
    if (t == 0) bsum[b] = s[0];
}

__global__ void k_scan_top(const int* __restrict__ bsum, int* __restrict__ boff,
                           int* __restrict__ rowptr, int nb, int N, int E) {
    if (threadIdx.x == 0 && blockIdx.x == 0) {
        int run = 0;
        for (int i = 0; i < nb; i++) { boff[i] = run; run += bsum[i]; }
        rowptr[N] = E;
    }
}

__global__ void k_scan_final(const int* __restrict__ cnt, const int* __restrict__ boff,
                             int* __restrict__ rowptr, int* __restrict__ wpos, int N) {
    __shared__ int s[256];
    int b = blockIdx.x, t = threadIdx.x;
    int base = b * CHUNK + t * 4;
    int v0 = 0, v1 = 0, v2 = 0, v3 = 0;
    if (base     < N) v0 = cnt[base];
    if (base + 1 < N) v1 = cnt[base + 1];
    if (base + 2 < N) v2 = cnt[base + 2];
    if (base + 3 < N) v3 = cnt[base + 3];
    int ts = v0 + v1 + v2 + v3;
    s[t] = ts; __syncthreads();
    for (int off = 1; off < 256; off <<= 1) {
        int xv = (t >= off) ? s[t - off] : 0;
        __syncthreads();
        s[t] += xv;
        __syncthreads();
    }
    int excl = s[t] - ts + boff[b];
    if (base     < N) { rowptr[base]     = excl;                 wpos[base]     = excl; }
    if (base + 1 < N) { int p = excl + v0;           rowptr[base + 1] = p; wpos[base + 1] = p; }
    if (base + 2 < N) { int p = excl + v0 + v1;      rowptr[base + 2] = p; wpos[base + 2] = p; }
    if (base + 3 < N) { int p = excl + v0 + v1 + v2; rowptr[base + 3] = p; wpos[base + 3] = p; }
}

__global__ void k_scatter(const int* __restrict__ ei, int* __restrict__ wpos,
                          int* __restrict__ col, int E) {
    int e = blockIdx.x * blockDim.x + threadIdx.x;
    if (e >= E) return;
    int d = ei[E + e];
    int p = atomicAdd(&wpos[d], 1);
    col[p] = e;
}

// ---------------- per-layer node transform ----------------
__global__ void k_qkvs(const float* __restrict__ hn,
                       const float* __restrict__ Wq, const float* __restrict__ bq,
                       const float* __restrict__ Wk, const float* __restrict__ bk,
                       const float* __restrict__ Wv, const float* __restrict__ bv,
                       const float* __restrict__ Ws, const float* __restrict__ bs,
                       float* __restrict__ q, float* __restrict__ k, float* __restrict__ v,
                       float* __restrict__ hnext, int N) {
    __shared__ float sWq[625], sWk[625], sWv[625], sWs[625], sbq[25], sbk[25], sbv[25], sbs[25];
    for (int i = threadIdx.x; i < 625; i += blockDim.x) {
        sWq[i] = Wq[i]; sWk[i] = Wk[i]; sWv[i] = Wv[i]; sWs[i] = Ws[i];
    }
    if (threadIdx.x < 25) {
        sbq[threadIdx.x] = bq[threadIdx.x]; sbk[threadIdx.x] = bk[threadIdx.x];
        sbv[threadIdx.x] = bv[threadIdx.x]; sbs[threadIdx.x] = bs[threadIdx.x];
    }
    __syncthreads();
    int gid = blockIdx.x * blockDim.x + threadIdx.x;
    int n = gid >> 5, j = gid & 31;
    if (n >= N || j >= HID) return;
    float h[25];
    #pragma unroll
    for (int i = 0; i < 25; i++) h[i] = hn[(size_t)n * STR + i];
    float aq = sbq[j], ak = sbk[j], av = sbv[j], as = sbs[j];
    #pragma unroll
    for (int i = 0; i < 25; i++) {
        float hi = h[i];
        aq += hi * sWq[i * 25 + j];
        ak += hi * sWk[i * 25 + j];
        av += hi * sWv[i * 25 + j];
        as += hi * sWs[i * 25 + j];
    }
    size_t o = (size_t)n * STR + j;
    q[o] = aq; k[o] = ak; v[o] = av; hnext[o] = as;
}

// ---------------- fused node-centric attention ----------------
__global__ void k_attn_node(const int* __restrict__ rowptr, const int* __restrict__ col,
                            const int* __restrict__ ei,
                            const float* __restrict__ q, const float* __restrict__ kk,
                            const float* __restrict__ v, const float* __restrict__ attr,
                            const float* __restrict__ eval_,
                            const float* __restrict__ We, const float* __restrict__ be,
                            float* __restrict__ hnext, int N, int E) {
    int n = blockIdx.x * blockDim.x + threadIdx.x;
    if (n >= N) return;
    const float scale = 0.44721359549995793f;

    float qr[25];
    #pragma unroll
    for (int i = 0; i < 25; i++) qr[i] = q[(size_t)n * STR + i];

    float qW0[5], qW1[5], qbe[5];
    #pragma unroll
    for (int h = 0; h < 5; h++) {
        float a0 = 0.f, a1 = 0.f, ab = 0.f;
        #pragma unroll
        for (int c = 0; c < 5; c++) {
            int i = h * 5 + c;
            a0 += qr[i] * We[i];
            a1 += qr[i] * We[25 + i];
            ab += qr[i] * be[i];
        }
        qW0[h] = a0; qW1[h] = a1; qbe[h] = ab;
    }

    float accV[25];
    #pragma unroll
    for (int i = 0; i < 25; i++) accV[i] = 0.f;
    float den[5] = {0, 0, 0, 0, 0}, sA[5] = {0, 0, 0, 0, 0}, sG[5] = {0, 0, 0, 0, 0};

    int beg = rowptr[n], end = rowptr[n + 1];
    for (int p = beg; p < end; p++) {
        int e = col[p];
        int s = ei[e];
        float a_ = attr[e], gl = eval_[e];
        const float* kr = kk + (size_t)s * STR;
        const float* vr = v + (size_t)s * STR;
        #pragma unroll
        for (int h = 0; h < 5; h++) {
            float al = qW0[h] * a_ + qW1[h] * gl + qbe[h];
            #pragma unroll
            for (int c = 0; c < 5; c++) { int i = h * 5 + c; al += qr[i] * kr[i]; }
            float ex = expf(al * scale);
            den[h] += ex;
            sA[h] += ex * a_;
            sG[h] += ex * gl;
            #pragma unroll
            for (int c = 0; c < 5; c++) { int i = h * 5 + c; accV[i] += ex * vr[i]; }
        }
    }

    #pragma unroll
    for (int h = 0; h < 5; h++) {
        float inv = 1.f / (den[h] + 1e-16f);
        #pragma unroll
        for (int c = 0; c < 5; c++) {
            int i = h * 5 + c;
            float agg = (accV[i] + sA[h] * We[i] + sG[h] * We[25 + i] + den[h] * be[i]) * inv;
            hnext[(size_t)n * STR + i] += agg;
        }
    }
}

// ---------------- output ----------------
__global__ void k_out(const float* __restrict__ hn, const float* __restrict__ W,
                      const float* __restrict__ b, float* __restrict__ out, int N) {
    int n = blockIdx.x * blockDim.x + threadIdx.x;
    if (n >= N) return;
    float acc = b[0];
    #pragma unroll
    for (int i = 0; i < 25; i++) acc += hn[(size_t)n * STR + i] * W[i];
    out[n] = 1.f / (1.f + expf(-acc));
}

extern "C" void kernel_launch(void* const* d_in, const int* in_sizes, int n_in,
                              void* d_out, int out_size, void* d_ws, size_t ws_size,
                              hipStream_t stream) {
    const float* x      = (const float*)d_in[0];
    const float* token  = (const float*)d_in[1];
    const float* attr   = (const float*)d_in[2];
    const float* gumbel = (const float*)d_in[3];
    const int*   ei     = (const int*)d_in[4];
    const float* W0 = (const float*)d_in[5];
    const float* b0 = (const float*)d_in[6];
    const float* W1 = (const float*)d_in[7];
    const float* b1 = (const float*)d_in[8];
    const float* W2 = (const float*)d_in[9];
    const float* b2 = (const float*)d_in[10];
    const float* W3 = (const float*)d_in[11];
    const float* b3 = (const float*)d_in[12];
    const float* ilW = (const float*)d_in[13];
    const float* ilb = (const float*)d_in[14];
    const float* Wq = (const float*)d_in[15];
    const float* bq = (const float*)d_in[16];
    const float* Wk = (const float*)d_in[17];
    const float* bk = (const float*)d_in[18];
    const float* Wv = (const float*)d_in[19];
    const float* bv = (const float*)d_in[20];
    const float* We = (const float*)d_in[21];
    const float* be = (const float*)d_in[22];
    const float* Ws = (const float*)d_in[23];
    const float* bs = (const float*)d_in[24];
    const float* oW = (const float*)d_in[25];
    const float* ob = (const float*)d_in[26];

    const int N = in_sizes[0];
    const int E = in_sizes[2];
    const int nb_chunk = (N + CHUNK - 1) / CHUNK;

    char* ws = (char*)d_ws;
    size_t off = 0;
    auto alloc = [&](size_t nb) -> void* {
        void* p = ws + off;
        off += (nb + 255) & ~(size_t)255;
        return p;
    };
    float* hnA    = (float*)alloc((size_t)N * STR * 4);
    float* hnB    = (float*)alloc((size_t)N * STR * 4);
    float* q      = (float*)alloc((size_t)N * STR * 4);
    float* k      = (float*)alloc((size_t)N * STR * 4);
    float* v      = (float*)alloc((size_t)N * STR * 4);
    float* evalv  = (float*)alloc((size_t)E * 4);
    float* xt6    = (float*)alloc((size_t)N * 8 * 4);
    int*   cnt    = (int*)alloc((size_t)N * 4);
    int*   rowptr = (int*)alloc((size_t)(N + 1) * 4);
    int*   wpos   = (int*)alloc((size_t)N * 4);
    int*   bsum   = (int*)alloc((size_t)(nb_chunk + 1) * 4);
    int*   boff   = (int*)alloc((size_t)(nb_chunk + 1) * 4);
    int*   col    = (int*)alloc((size_t)E * 4);
    int*   flcnt  = (int*)alloc(256);
    int*   fllist = (int*)alloc((size_t)E * 4);

    int nb_n32 = (N * STR + 255) / 256;
    int nb_e   = (E + 255) / 256;
    int nb_n   = (N + 255) / 256;

    const int mlp_blocks = 2048;
    const int mlp_waves  = mlp_blocks * 4;
    const int ntiles     = (E + 15) / 16;

    hipMemsetAsync(cnt, 0, (size_t)N * 4, stream);
    hipMemsetAsync(flcnt, 0, 4, stream);
    k_node_in<<<nb_n32, 256, 0, stream>>>(x, token, ilW, ilb, hnA, xt6, N);
    k_edge_mlp_mfma<<<mlp_blocks, 256, 0, stream>>>(ei, xt6, attr, gumbel,
                                                    W0, b0, W1, b1, W2, b2, W3, b3,
                                                    evalv, flcnt, fllist, E, ntiles, mlp_waves);
    k_edge_fb<<<mlp_blocks, 256, 0, stream>>>(ei, xt6, attr, gumbel,
                                              W0, b0, W1, b1, W2, b2, W3, b3,
                                              fllist, flcnt, evalv, E, mlp_waves);
    k_hist<<<nb_e, 256, 0, stream>>>(ei, cnt, E);
    k_scan_partial<<<nb_chunk, 256, 0, stream>>>(cnt, bsum, N);
    k_scan_top<<<1, 64, 0, stream>>>(bsum, boff, rowptr, nb_chunk, N, E);
    k_scan_final<<<nb_chunk, 256, 0, stream>>>(cnt, boff, rowptr, wpos, N);
    k_scatter<<<nb_e, 256, 0, stream>>>(ei, wpos, col, E);

    float* cur = hnA;
    float* nxt = hnB;
    for (int l = 0; l < 3; l++) {
        k_qkvs<<<nb_n32, 256, 0, stream>>>(cur, Wq + l * 625, bq + l * 25,
                                           Wk + l * 625, bk + l * 25,
                                           Wv + l * 625, bv + l * 25,
                                           Ws + l * 625, bs + l * 25,
                                           q, k, v, nxt, N);
        k_attn_node<<<nb_n, 256, 0, stream>>>(rowptr, col, ei, q, k, v, attr, evalv,
                                              We + l * 50, be + l * 25, nxt, N, E);
        float* t = cur; cur = nxt; nxt = t;
    }
    k_out<<<nb_n, 256, 0, stream>>>(cur, oW, ob, (float*)d_out, N);
}

// Round 10
// 2981.167 us; speedup vs baseline: 1.2553x; 1.0285x over previous
//
#include <hip/hip_runtime.h>
#include <math.h>

#define HID 25
#define STR 32   // padded node-feature row stride (128B rows)
#define CHUNK 1024
#define FBTHR 0.1f

typedef __attribute__((ext_vector_type(8))) short short8;
typedef __attribute__((ext_vector_type(4))) short short4v;
typedef __attribute__((ext_vector_type(4))) float f32x4;

__device__ __forceinline__ float gelu_f(float x) {
    return 0.5f * x * (1.0f + erff(x * 0.70710678118654752f));
}

// Branchless gelu: A&S 7.1.26 erf approx, |err| <= 1.5e-7 (<< FBTHR; gate-safe,
// fallback recomputes with true erff).
__device__ __forceinline__ float gelu_fast(float x) {
    float y = fabsf(x) * 0.70710678118654752f;
    float t = 1.0f / fmaf(0.3275911f, y, 1.0f);
    float p = fmaf(1.061405429f, t, -1.453152027f);
    p = fmaf(p, t, 1.421413741f);
    p = fmaf(p, t, -0.284496736f);
    p = fmaf(p, t, 0.254829592f);
    p = p * t;
    float e = __expf(-y * y);
    float erfv = fmaf(-p, e, 1.0f);
    float r = copysignf(erfv, x);
    return 0.5f * x * (1.0f + r);
}

__device__ __forceinline__ short f2bf(float f) {
    unsigned u = __float_as_uint(f);
    u = (u + 0x7fffu + ((u >> 16) & 1u)) >> 16;
    return (short)u;
}

// gather 4 consecutive MLP-input slots (k = grp*4 .. grp*4+3) for edge e
__device__ __forceinline__ void gather4(int e, int E, const int* __restrict__ ei,
                                        const float* __restrict__ xt6,
                                        const float* __restrict__ attr, int grp,
                                        float& v0, float& v1, float& v2, float& v3) {
    v0 = v1 = v2 = v3 = 0.f;
    if (e < E) {
        if (grp == 0) {
            const float4 f = *(const float4*)&xt6[(size_t)ei[e] * 8];
            v0 = f.x; v1 = f.y; v2 = f.z; v3 = f.w;
        } else if (grp == 1) {
            int s = ei[e], d = ei[E + e];
            const float2 lo = *(const float2*)&xt6[(size_t)s * 8 + 4];
            const float2 hi = *(const float2*)&xt6[(size_t)d * 8];
            v0 = lo.x; v1 = lo.y; v2 = hi.x; v3 = hi.y;
        } else if (grp == 2) {
            int d = ei[E + e];
            const float2 lo = *(const float2*)&xt6[(size_t)d * 8 + 2];
            const float2 hi = *(const float2*)&xt6[(size_t)d * 8 + 4];
            v0 = lo.x; v1 = lo.y; v2 = hi.x; v3 = hi.y;
        } else {
            v0 = attr[e];
        }
    }
}

// ---------------- node input linear + packed xt6 ----------------
__global__ void k_node_in(const float* __restrict__ x, const float* __restrict__ token,
                          const float* __restrict__ W, const float* __restrict__ b,
                          float* __restrict__ hn, float* __restrict__ xt6, int N) {
    int gid = blockIdx.x * blockDim.x + threadIdx.x;
    int n = gid >> 5, j = gid & 31;
    if (n >= N) return;
    if (j < 8) xt6[(size_t)n * 8 + j] = (j == 0) ? x[n] : ((j < 6) ? token[n * 5 + j - 1] : 0.f);
    if (j >= HID) return;
    float acc = b[j];
    acc += x[n] * W[j];
    #pragma unroll
    for (int i = 0; i < 5; i++) acc += token[n * 5 + i] * W[(i + 1) * HID + j];
    hn[(size_t)n * STR + j] = acc;
}

// ---------------- edge MLP via MFMA (bf16), 16 edges/wave-tile, NO atomics ----------------
__global__ __launch_bounds__(256) void k_edge_mlp_mfma(
    const int* __restrict__ ei, const float* __restrict__ xt6,
    const float* __restrict__ attr, const float* __restrict__ gumbel,
    const float* __restrict__ W0, const float* __restrict__ b0,
    const float* __restrict__ W1, const float* __restrict__ b1,
    const float* __restrict__ W2, const float* __restrict__ b2,
    const float* __restrict__ W3, const float* __restrict__ b3,
    float* __restrict__ eval_, unsigned char* __restrict__ flagv,
    int E, int ntiles, int nwaves) {
    __shared__ short hbuf[4][1024];   // [wave][16x64 bf16 swizzled]
    const int lane = threadIdx.x & 63;
    const int wv = threadIdx.x >> 6;
    const int wid = blockIdx.x * 4 + wv;
    const int grp = lane >> 4, r2 = lane & 15;

    short8 w0f[4], w1f[2][4], w2f[2][4];
    #pragma unroll
    for (int nt = 0; nt < 4; nt++) {
        int col = r2 + 16 * nt;
        #pragma unroll
        for (int j = 0; j < 8; j++) {
            int k = grp * 4 + (j & 3) + 16 * (j >> 2);
            w0f[nt][j] = (k < 13 && col < 50) ? f2bf(W0[k * 50 + col]) : (short)0;
        }
    }
    #pragma unroll
    for (int kt = 0; kt < 2; kt++) {
        #pragma unroll
        for (int nt = 0; nt < 4; nt++) {
            int col = r2 + 16 * nt;
            #pragma unroll
            for (int j = 0; j < 8; j++) {
                int k = kt * 32 + grp * 4 + (j & 3) + 16 * (j >> 2);
                w1f[kt][nt][j] = (k < 50 && col < 50) ? f2bf(W1[k * 50 + col]) : (short)0;
                w2f[kt][nt][j] = (k < 50 && col < 50) ? f2bf(W2[k * 50 + col]) : (short)0;
            }
        }
    }
    float b0v[4], b1v[4], b2v[4], w3dv[4];
    #pragma unroll
    for (int nt = 0; nt < 4; nt++) {
        int col = r2 + 16 * nt;
        b0v[nt] = (col < 50) ? b0[col] : 0.f;
        b1v[nt] = (col < 50) ? b1[col] : 0.f;
        b2v[nt] = (col < 50) ? b2[col] : 0.f;
        w3dv[nt] = (col < 50) ? (W3[col * 2 + 1] - W3[col * 2]) : 0.f;
    }
    const float b3d = b3[1] - b3[0];
    const f32x4 z4 = {0.f, 0.f, 0.f, 0.f};
    short* hb = &hbuf[wv][0];

    for (int t = wid; t < ntiles; t += nwaves) {
        const int base = t * 16;
        float g0, g1, g2, g3;
        gather4(base + r2, E, ei, xt6, attr, grp, g0, g1, g2, g3);
        short8 a0 = {f2bf(g0), f2bf(g1), f2bf(g2), f2bf(g3), 0, 0, 0, 0};

        // ---- layer 0 ----
        f32x4 c0 = __builtin_amdgcn_mfma_f32_16x16x32_bf16(a0, w0f[0], z4, 0, 0, 0);
        f32x4 c1 = __builtin_amdgcn_mfma_f32_16x16x32_bf16(a0, w0f[1], z4, 0, 0, 0);
        f32x4 c2 = __builtin_amdgcn_mfma_f32_16x16x32_bf16(a0, w0f[2], z4, 0, 0, 0);
        f32x4 c3 = __builtin_amdgcn_mfma_f32_16x16x32_bf16(a0, w0f[3], z4, 0, 0, 0);
        #pragma unroll
        for (int i = 0; i < 4; i++) {
            int row = grp * 4 + i, sw = (row & 7) << 3;
            hb[(row * 64 + r2)      ^ sw] = f2bf(gelu_fast(c0[i] + b0v[0]));
            hb[(row * 64 + r2 + 16) ^ sw] = f2bf(gelu_fast(c1[i] + b0v[1]));
            hb[(row * 64 + r2 + 32) ^ sw] = f2bf(gelu_fast(c2[i] + b0v[2]));
            hb[(row * 64 + r2 + 48) ^ sw] = f2bf(gelu_fast(c3[i] + b0v[3]));
        }

        // ---- layer 1 ----
        {
            int row = r2, sw = (row & 7) << 3;
            short4v lo0 = *(const short4v*)&hb[(row * 64 + 0  + grp * 4) ^ sw];
            short4v hi0 = *(const short4v*)&hb[(row * 64 + 16 + grp * 4) ^ sw];
            short4v lo1 = *(const short4v*)&hb[(row * 64 + 32 + grp * 4) ^ sw];
            short4v hi1 = *(const short4v*)&hb[(row * 64 + 48 + grp * 4) ^ sw];
            short8 k0 = {lo0[0], lo0[1], lo0[2], lo0[3], hi0[0], hi0[1], hi0[2], hi0[3]};
            short8 k1 = {lo1[0], lo1[1], lo1[2], lo1[3], hi1[0], hi1[1], hi1[2], hi1[3]};
            c0 = __builtin_amdgcn_mfma_f32_16x16x32_bf16(k1, w1f[1][0],
                 __builtin_amdgcn_mfma_f32_16x16x32_bf16(k0, w1f[0][0], z4, 0, 0, 0), 0, 0, 0);
            c1 = __builtin_amdgcn_mfma_f32_16x16x32_bf16(k1, w1f[1][1],
                 __builtin_amdgcn_mfma_f32_16x16x32_bf16(k0, w1f[0][1], z4, 0, 0, 0), 0, 0, 0);
            c2 = __builtin_amdgcn_mfma_f32_16x16x32_bf16(k1, w1f[1][2],
                 __builtin_amdgcn_mfma_f32_16x16x32_bf16(k0, w1f[0][2], z4, 0, 0, 0), 0, 0, 0);
            c3 = __builtin_amdgcn_mfma_f32_16x16x32_bf16(k1, w1f[1][3],
                 __builtin_amdgcn_mfma_f32_16x16x32_bf16(k0, w1f[0][3], z4, 0, 0, 0), 0, 0, 0);
        }
        #pragma unroll
        for (int i = 0; i < 4; i++) {
            int row = grp * 4 + i, sw = (row & 7) << 3;
            hb[(row * 64 + r2)      ^ sw] = f2bf(gelu_fast(c0[i] + b1v[0]));
            hb[(row * 64 + r2 + 16) ^ sw] = f2bf(gelu_fast(c1[i] + b1v[1]));
            hb[(row * 64 + r2 + 32) ^ sw] = f2bf(gelu_fast(c2[i] + b1v[2]));
            hb[(row * 64 + r2 + 48) ^ sw] = f2bf(gelu_fast(c3[i] + b1v[3]));
        }

        // ---- layer 2 ----
        {
            int row = r2, sw = (row & 7) << 3;
            short4v lo0 = *(const short4v*)&hb[(row * 64 + 0  + grp * 4) ^ sw];
            short4v hi0 = *(const short4v*)&hb[(row * 64 + 16 + grp * 4) ^ sw];
            short4v lo1 = *(const short4v*)&hb[(row * 64 + 32 + grp * 4) ^ sw];
            short4v hi1 = *(const short4v*)&hb[(row * 64 + 48 + grp * 4) ^ sw];
            short8 k0 = {lo0[0], lo0[1], lo0[2], lo0[3], hi0[0], hi0[1], hi0[2], hi0[3]};
            short8 k1 = {lo1[0], lo1[1], lo1[2], lo1[3], hi1[0], hi1[1], hi1[2], hi1[3]};
            c0 = __builtin_amdgcn_mfma_f32_16x16x32_bf16(k1, w2f[1][0],
                 __builtin_amdgcn_mfma_f32_16x16x32_bf16(k0, w2f[0][0], z4, 0, 0, 0), 0, 0, 0);
            c1 = __builtin_amdgcn_mfma_f32_16x16x32_bf16(k1, w2f[1][1],
                 __builtin_amdgcn_mfma_f32_16x16x32_bf16(k0, w2f[0][1], z4, 0, 0, 0), 0, 0, 0);
            c2 = __builtin_amdgcn_mfma_f32_16x16x32_bf16(k1, w2f[1][2],
                 __builtin_amdgcn_mfma_f32_16x16x32_bf16(k0, w2f[0][2], z4, 0, 0, 0), 0, 0, 0);
            c3 = __builtin_amdgcn_mfma_f32_16x16x32_bf16(k1, w2f[1][3],
                 __builtin_amdgcn_mfma_f32_16x16x32_bf16(k0, w2f[0][3], z4, 0, 0, 0), 0, 0, 0);
        }

        float z0 = 0.f, z1 = 0.f, z2 = 0.f, z3 = 0.f;
        #pragma unroll
        for (int i = 0; i < 4; i++) {
            float h0 = gelu_fast(c0[i] + b2v[0]), h1 = gelu_fast(c1[i] + b2v[1]);
            float h2 = gelu_fast(c2[i] + b2v[2]), h3 = gelu_fast(c3[i] + b2v[3]);
            float z = h0 * w3dv[0] + h1 * w3dv[1] + h2 * w3dv[2] + h3 * w3dv[3];
            if (i == 0) z0 = z; else if (i == 1) z1 = z; else if (i == 2) z2 = z; else z3 = z;
        }
        #pragma unroll
        for (int off = 1; off < 16; off <<= 1) {
            z0 += __shfl_xor(z0, off); z1 += __shfl_xor(z1, off);
            z2 += __shfl_xor(z2, off); z3 += __shfl_xor(z3, off);
        }
        if (r2 < 4) {
            int e2 = base + grp * 4 + r2;
            if (e2 < E) {
                float zsel = (r2 == 0) ? z0 : (r2 == 1) ? z1 : (r2 == 2) ? z2 : z3;
                float g0v = gumbel[2 * (long long)e2], g1v = gumbel[2 * (long long)e2 + 1];
                float m = zsel + b3d + g1v - g0v;
                eval_[e2] = (m > 0.f) ? 1.f : 0.f;
                flagv[e2] = (fabsf(m) < FBTHR) ? 1 : 0;
            }
        }
    }
}

// ---------------- flag -> list compaction (one atomic per wave) ----------------
__global__ void k_compact(const unsigned char* __restrict__ flagv,
                          int* __restrict__ flcnt, int* __restrict__ fllist, int E) {
    int e = blockIdx.x * blockDim.x + threadIdx.x;
    bool f = (e < E) && (flagv[e] != 0);
    unsigned long long mask = __ballot(f);
    int lane = threadIdx.x & 63;
    int cnt = __popcll(mask);
    if (cnt == 0) return;
    int leader = __ffsll((long long)mask) - 1;
    int basep = 0;
    if (lane == leader) basep = atomicAdd(flcnt, cnt);
    basep = __shfl(basep, leader);
    if (f) {
        int idx = basep + __popcll(mask & ((1ull << lane) - 1ull));
        fllist[idx] = e;
    }
}

// ---------------- wave-cooperative exact-fp32 fallback ----------------
__global__ __launch_bounds__(256) void k_edge_fb(
    const int* __restrict__ ei, const float* __restrict__ xt6,
    const float* __restrict__ attr, const float* __restrict__ gumbel,
    const float* __restrict__ W0, const float* __restrict__ b0,
    const float* __restrict__ W1, const float* __restrict__ b1,
    const float* __restrict__ W2, const float* __restrict__ b2,
    const float* __restrict__ W3, const float* __restrict__ b3,
    const int* __restrict__ fllist, const int* __restrict__ flcnt,
    float* __restrict__ eval_, int E, int nwaves) {
    __shared__ float buf[4][2][2][64];
    const int lane = threadIdx.x & 63;
    const int wv = threadIdx.x >> 6;
    const int wid = blockIdx.x * 4 + wv;
    const int jw = (lane < 50) ? lane : 49;

    float w0r[16], w1r[52], w2r[52];
    #pragma unroll
    for (int k = 0; k < 13; k++) w0r[k] = W0[k * 50 + jw];
    w0r[13] = 0.f; w0r[14] = 0.f; w0r[15] = 0.f;
    #pragma unroll
    for (int k = 0; k < 50; k++) w1r[k] = W1[k * 50 + jw];
    w1r[50] = 0.f; w1r[51] = 0.f;
    #pragma unroll
    for (int k = 0; k < 50; k++) w2r[k] = W2[k * 50 + jw];
    w2r[50] = 0.f; w2r[51] = 0.f;
    const float b0r = b0[jw], b1r = b1[jw], b2r = b2[jw];
    const float b3_0 = b3[0], b3_1 = b3[1];
    const float w3d = (lane < 50) ? (W3[lane * 2 + 1] - W3[lane * 2]) : 0.f;

    const int g = lane >> 4, r = lane & 15;
    const int cnt = *flcnt;

    for (int base = wid * 2; base < cnt; base += nwaves * 2) {
        if (g < 2) {
            int idx = base + g;
            float val = 0.f;
            if (idx < cnt && r < 13) {
                int e = fllist[idx];
                if (r == 12) val = attr[e];
                else if (r < 6) val = xt6[(size_t)ei[e] * 8 + r];
                else val = xt6[(size_t)ei[E + e] * 8 + (r - 6)];
            }
            buf[wv][0][g][r] = val;
        }

        const float4* a4 = (const float4*)(&buf[wv][0][0][0]);
        const float4* c4 = (const float4*)(&buf[wv][0][1][0]);
        float tA = b0r, tB = b0r;
        #pragma unroll
        for (int c = 0; c < 4; c++) {
            float4 a = a4[c], b = c4[c];
            tA += a.x * w0r[4 * c];     tB += b.x * w0r[4 * c];
            tA += a.y * w0r[4 * c + 1]; tB += b.y * w0r[4 * c + 1];
            tA += a.z * w0r[4 * c + 2]; tB += b.z * w0r[4 * c + 2];
            tA += a.w * w0r[4 * c + 3]; tB += b.w * w0r[4 * c + 3];
        }
        buf[wv][1][0][lane] = gelu_f(tA);
        buf[wv][1][1][lane] = gelu_f(tB);

        const float4* p4 = (const float4*)(&buf[wv][1][0][0]);
        const float4* q4 = (const float4*)(&buf[wv][1][1][0]);
        tA = b1r; tB = b1r;
        #pragma unroll
        for (int c = 0; c < 13; c++) {
            float4 a = p4[c], b = q4[c];
            tA += a.x * w1r[4 * c];     tB += b.x * w1r[4 * c];
            tA += a.y * w1r[4 * c + 1]; tB += b.y * w1r[4 * c + 1];
            tA += a.z * w1r[4 * c + 2]; tB += b.z * w1r[4 * c + 2];
            tA += a.w * w1r[4 * c + 3]; tB += b.w * w1r[4 * c + 3];
        }
        buf[wv][0][0][lane] = gelu_f(tA);
        buf[wv][0][1][lane] = gelu_f(tB);

        tA = b2r; tB = b2r;
        #pragma unroll
        for (int c = 0; c < 13; c++) {
            float4 a = a4[c], b = c4[c];
            tA += a.x * w2r[4 * c];     tB += b.x * w2r[4 * c];
            tA += a.y * w2r[4 * c + 1]; tB += b.y * w2r[4 * c + 1];
            tA += a.z * w2r[4 * c + 2]; tB += b.z * w2r[4 * c + 2];
            tA += a.w * w2r[4 * c + 3]; tB += b.w * w2r[4 * c + 3];
        }
        float h3A = gelu_f(tA), h3B = gelu_f(tB);
        buf[wv][1][0][lane] = h3A;
        buf[wv][1][1][lane] = h3B;

        float zA = h3A * w3d, zB = h3B * w3d;
        #pragma unroll
        for (int off = 32; off > 0; off >>= 1) {
            zA += __shfl_xor(zA, off);
            zB += __shfl_xor(zB, off);
        }

        if (lane < 2) {
            int idx = base + lane;
            if (idx < cnt) {
                int e = fllist[idx];
                float z = (lane == 0) ? zA : zB;
                float g0v = gumbel[2 * (long long)e], g1v = gumbel[2 * (long long)e + 1];
                float m = z + (b3_1 - b3_0) + g1v - g0v;
                float dec;
                if (fabsf(m) < 1e-4f) {
                    float z0 = 0.f, z1 = 0.f;
                    for (int j = 0; j < 50; j++) {
                        float h = buf[wv][1][lane][j];
                        z0 += h * W3[2 * j];
                        z1 += h * W3[2 * j + 1];
                    }
                    z0 += b3_0; z1 += b3_1;
                    dec = (z1 + g1v > z0 + g0v) ? 1.f : 0.f;
                } else {
                    dec = (m > 0.f) ? 1.f : 0.f;
                }
                eval_[e] = dec;
            }
        }
    }
}

// ---------------- CSR build: histogram + scan + scatter ----------------
__global__ void k_hist(const int* __restrict__ ei, int* __restrict__ cnt, int E) {
    int e = blockIdx.x * blockDim.x + threadIdx.x;
    if (e >= E) return;
    atomicAdd(&cnt[ei[E + e]], 1);
}

__global__ void k_scan_partial(const int* __restrict__ cnt, int* __restrict__ bsum, int N) {
    __shared__ int s[256];
    int b = blockIdx.x, t = threadIdx.x;
    int base = b * CHUNK + t * 4;
    int sum = 0;
    #pragma unroll
    for (int u = 0; u < 4; u++) { int idx = base + u; if (idx < N) sum += cnt[idx]; }
    s[t] = sum; __syncthreads();
    for (int off = 128; off > 0; off >>= 1) {
        if (t < off) s[t] += s[t + off];
        __syncthreads();
    }
    if (t == 0) bsum[b] = s[0];
}

__global__ void k_scan_top(const int* __restrict__ bsum, int* __restrict__ boff,
                           int* __restrict__ rowptr, int nb, int N, int E) {
    if (threadIdx.x == 0 && blockIdx.x == 0) {
        int run = 0;
        for (int i = 0; i < nb; i++) { boff[i] = run; run += bsum[i]; }
        rowptr[N] = E;
    }
}

__global__ void k_scan_final(const int* __restrict__ cnt, const int* __restrict__ boff,
                             int* __restrict__ rowptr, int* __restrict__ wpos, int N) {
    __shared__ int s[256];
    int b = blockIdx.x, t = threadIdx.x;
    int base = b * CHUNK + t * 4;
    int v0 = 0, v1 = 0, v2 = 0, v3 = 0;
    if (base     < N) v0 = cnt[base];
    if (base + 1 < N) v1 = cnt[base + 1];
    if (base + 2 < N) v2 = cnt[base + 2];
    if (base + 3 < N) v3 = cnt[base + 3];
    int ts = v0 + v1 + v2 + v3;
    s[t] = ts; __syncthreads();
    for (int off = 1; off < 256; off <<= 1) {
        int xv = (t >= off) ? s[t - off] : 0;
        __syncthreads();
        s[t] += xv;
        __syncthreads();
    }
    int excl = s[t] - ts + boff[b];
    if (base     < N) { rowptr[base]     = excl;                 wpos[base]     = excl; }
    if (base + 1 < N) { int p = excl + v0;           rowptr[base + 1] = p; wpos[base + 1] = p; }
    if (base + 2 < N) { int p = excl + v0 + v1;      rowptr[base + 2] = p; wpos[base + 2] = p; }
    if (base + 3 < N) { int p = excl + v0 + v1 + v2; rowptr[base + 3] = p; wpos[base + 3] = p; }
}

__global__ void k_scatter(const int* __restrict__ ei, int* __restrict__ wpos,
                          int* __restrict__ col, int E) {
    int e = blockIdx.x * blockDim.x + threadIdx.x;
    if (e >= E) return;
    int d = ei[E + e];
    int p = atomicAdd(&wpos[d], 1);
    col[p] = e;
}

// ---------------- per-layer node transform ----------------
__global__ void k_qkvs(const float* __restrict__ hn,
                       const float* __restrict__ Wq, const float* __restrict__ bq,
                       const float* __restrict__ Wk, const float* __restrict__ bk,
                       const float* __restrict__ Wv, const float* __restrict__ bv,
                       const float* __restrict__ Ws, const float* __restrict__ bs,
                       float* __restrict__ q, float* __restrict__ k, float* __restrict__ v,
                       float* __restrict__ hnext, int N) {
    __shared__ float sWq[625], sWk[625], sWv[625], sWs[625], sbq[25], sbk[25], sbv[25], sbs[25];
    for (int i = threadIdx.x; i < 625; i += blockDim.x) {
        sWq[i] = Wq[i]; sWk[i] = Wk[i]; sWv[i] = Wv[i]; sWs[i] = Ws[i];
    }
    if (threadIdx.x < 25) {
        sbq[threadIdx.x] = bq[threadIdx.x]; sbk[threadIdx.x] = bk[threadIdx.x];
        sbv[threadIdx.x] = bv[threadIdx.x]; sbs[threadIdx.x] = bs[threadIdx.x];
    }
    __syncthreads();
    int gid = blockIdx.x * blockDim.x + threadIdx.x;
    int n = gid >> 5, j = gid & 31;
    if (n >= N || j >= HID) return;
    float h[25];
    #pragma unroll
    for (int i = 0; i < 25; i++) h[i] = hn[(size_t)n * STR + i];
    float aq = sbq[j], ak = sbk[j], av = sbv[j], as = sbs[j];
    #pragma unroll
    for (int i = 0; i < 25; i++) {
        float hi = h[i];
        aq += hi * sWq[i * 25 + j];
        ak += hi * sWk[i * 25 + j];
        av += hi * sWv[i * 25 + j];
        as += hi * sWs[i * 25 + j];
    }
    size_t o = (size_t)n * STR + j;
    q[o] = aq; k[o] = ak; v[o] = av; hnext[o] = as;
}

// ---------------- fused node-centric attention (prefetched, __expf) ----------------
__global__ void k_attn_node(const int* __restrict__ rowptr, const int* __restrict__ col,
                            const int* __restrict__ ei,
                            const float* __restrict__ q, const float* __restrict__ kk,
                            const float* __restrict__ v, const float* __restrict__ attr,
                            const float* __restrict__ eval_,
                            const float* __restrict__ We, const float* __restrict__ be,
                            float* __restrict__ hnext, int N, int E) {
    int n = blockIdx.x * blockDim.x + threadIdx.x;
    if (n >= N) return;
    const float scale = 0.44721359549995793f;

    float qr[25];
    #pragma unroll
    for (int i = 0; i < 25; i++) qr[i] = q[(size_t)n * STR + i];

    float qW0[5], qW1[5], qbe[5];
    #pragma unroll
    for (int h = 0; h < 5; h++) {
        float a0 = 0.f, a1 = 0.f, ab = 0.f;
        #pragma unroll
        for (int c = 0; c < 5; c++) {
            int i = h * 5 + c;
            a0 += qr[i] * We[i];
            a1 += qr[i] * We[25 + i];
            ab += qr[i] * be[i];
        }
        qW0[h] = a0; qW1[h] = a1; qbe[h] = ab;
    }

    float accV[25];
    #pragma unroll
    for (int i = 0; i < 25; i++) accV[i] = 0.f;
    float den[5] = {0, 0, 0, 0, 0}, sA[5] = {0, 0, 0, 0, 0}, sG[5] = {0, 0, 0, 0, 0};

    int beg = rowptr[n], end = rowptr[n + 1];
    int e = 0, s = 0; float a_ = 0.f, gl = 0.f;
    if (beg < end) { e = col[beg]; s = ei[e]; a_ = attr[e]; gl = eval_[e]; }
    for (int p = beg; p < end; p++) {
        // prefetch next edge's scalars to hide the index chain
        int en = 0, sn = 0; float an = 0.f, gln = 0.f;
        if (p + 1 < end) { en = col[p + 1]; sn = ei[en]; an = attr[en]; gln = eval_[en]; }
        const float* kr = kk + (size_t)s * STR;
        const float* vr = v + (size_t)s * STR;
        #pragma unroll
        for (int h = 0; h < 5; h++) {
            float al = qW0[h] * a_ + qW1[h] * gl + qbe[h];
            #pragma unroll
            for (int c = 0; c < 5; c++) { int i = h * 5 + c; al += qr[i] * kr[i]; }
            float ex = __expf(al * scale);
            den[h] += ex;
            sA[h] += ex * a_;
            sG[h] += ex * gl;
            #pragma unroll
            for (int c = 0; c < 5; c++) { int i = h * 5 + c; accV[i] += ex * vr[i]; }
        }
        e = en; s = sn; a_ = an; gl = gln;
    }

    #pragma unroll
    for (int h = 0; h < 5; h++) {
        float inv = 1.f / (den[h] + 1e-16f);
        #pragma unroll
        for (int c = 0; c < 5; c++) {
            int i = h * 5 + c;
            float agg = (accV[i] + sA[h] * We[i] + sG[h] * We[25 + i] + den[h] * be[i]) * inv;
            hnext[(size_t)n * STR + i] += agg;
        }
    }
}

// ---------------- output ----------------
__global__ void k_out(const float* __restrict__ hn, const float* __restrict__ W,
                      const float* __restrict__ b, float* __restrict__ out, int N) {
    int n = blockIdx.x * blockDim.x + threadIdx.x;
    if (n >= N) return;
    float acc = b[0];
    #pragma unroll
    for (int i = 0; i < 25; i++) acc += hn[(size_t)n * STR + i] * W[i];
    out[n] = 1.f / (1.f + expf(-acc));
}

extern "C" void kernel_launch(void* const* d_in, const int* in_sizes, int n_in,
                              void* d_out, int out_size, void* d_ws, size_t ws_size,
                              hipStream_t stream) {
    const float* x      = (const float*)d_in[0];
    const float* token  = (const float*)d_in[1];
    const float* attr   = (const float*)d_in[2];
    const float* gumbel = (const float*)d_in[3];
    const int*   ei     = (const int*)d_in[4];
    const float* W0 = (const float*)d_in[5];
    const float* b0 = (const float*)d_in[6];
    const float* W1 = (const float*)d_in[7];
    const float* b1 = (const float*)d_in[8];
    const float* W2 = (const float*)d_in[9];
    const float* b2 = (const float*)d_in[10];
    const float* W3 = (const float*)d_in[11];
    const float* b3 = (const float*)d_in[12];
    const float* ilW = (const float*)d_in[13];
    const float* ilb = (const float*)d_in[14];
    const float* Wq = (const float*)d_in[15];
    const float* bq = (const float*)d_in[16];
    const float* Wk = (const float*)d_in[17];
    const float* bk = (const float*)d_in[18];
    const float* Wv = (const float*)d_in[19];
    const float* bv = (const float*)d_in[20];
    const float* We = (const float*)d_in[21];
    const float* be = (const float*)d_in[22];
    const float* Ws = (const float*)d_in[23];
    const float* bs = (const float*)d_in[24];
    const float* oW = (const float*)d_in[25];
    const float* ob = (const float*)d_in[26];

    const int N = in_sizes[0];
    const int E = in_sizes[2];
    const int nb_chunk = (N + CHUNK - 1) / CHUNK;

    char* ws = (char*)d_ws;
    size_t off = 0;
    auto alloc = [&](size_t nb) -> void* {
        void* p = ws + off;
        off += (nb + 255) & ~(size_t)255;
        return p;
    };
    float* hnA    = (float*)alloc((size_t)N * STR * 4);
    float* hnB    = (float*)alloc((size_t)N * STR * 4);
    float* q      = (float*)alloc((size_t)N * STR * 4);
    float* k      = (float*)alloc((size_t)N * STR * 4);
    float* v      = (float*)alloc((size_t)N * STR * 4);
    float* evalv  = (float*)alloc((size_t)E * 4);
    float* xt6    = (float*)alloc((size_t)N * 8 * 4);
    int*   cnt    = (int*)alloc((size_t)N * 4);
    int*   rowptr = (int*)alloc((size_t)(N + 1) * 4);
    int*   wpos   = (int*)alloc((size_t)N * 4);
    int*   bsum   = (int*)alloc((size_t)(nb_chunk + 1) * 4);
    int*   boff   = (int*)alloc((size_t)(nb_chunk + 1) * 4);
    int*   col    = (int*)alloc((size_t)E * 4);
    int*   flcnt  = (int*)alloc(256);
    int*   fllist = (int*)alloc((size_t)E * 4);
    unsigned char* flagv = (unsigned char*)alloc((size_t)E);

    int nb_n32 = (N * STR + 255) / 256;
    int nb_e   = (E + 255) / 256;
    int nb_n   = (N + 255) / 256;

    const int mlp_blocks = 4096;
    const int mlp_waves  = mlp_blocks * 4;
    const int ntiles     = (E + 15) / 16;

    hipMemsetAsync(cnt, 0, (size_t)N * 4, stream);
    hipMemsetAsync(flcnt, 0, 4, stream);
    k_node_in<<<nb_n32, 256, 0, stream>>>(x, token, ilW, ilb, hnA, xt6, N);
    k_edge_mlp_mfma<<<mlp_blocks, 256, 0, stream>>>(ei, xt6, attr, gumbel,
                                                    W0, b0, W1, b1, W2, b2, W3, b3,
                                                    evalv, flagv, E, ntiles, mlp_waves);
    k_compact<<<nb_e, 256, 0, stream>>>(flagv, flcnt, fllist, E);
    k_edge_fb<<<2048, 256, 0, stream>>>(ei, xt6, attr, gumbel,
                                        W0, b0, W1, b1, W2, b2, W3, b3,
                                        fllist, flcnt, evalv, E, 2048 * 4);
    k_hist<<<nb_e, 256, 0, stream>>>(ei, cnt, E);
    k_scan_partial<<<nb_chunk, 256, 0, stream>>>(cnt, bsum, N);
    k_scan_top<<<1, 64, 0, stream>>>(bsum, boff, rowptr, nb_chunk, N, E);
    k_scan_final<<<nb_chunk, 256, 0, stream>>>(cnt, boff, rowptr, wpos, N);
    k_scatter<<<nb_e, 256, 0, stream>>>(ei, wpos, col, E);

    float* cur = hnA;
    float* nxt = hnB;
    for (int l = 0; l < 3; l++) {
        k_qkvs<<<nb_n32, 256, 0, stream>>>(cur, Wq + l * 625, bq + l * 25,
                                           Wk + l * 625, bk + l * 25,
                                           Wv + l * 625, bv + l * 25,
                                           Ws + l * 625, bs + l * 25,
                                           q, k, v, nxt, N);
        k_attn_node<<<nb_n, 256, 0, stream>>>(rowptr, col, ei, q, k, v, attr, evalv,
                                              We + l * 50, be + l * 25, nxt, N, E);
        float* t = cur; cur = nxt; nxt = t;
    }
    k_out<<<nb_n, 256, 0, stream>>>(cur, oW, ob, (float*)d_out, N);
}

// Round 11
// 2840.271 us; speedup vs baseline: 1.3176x; 1.0496x over previous
//
#include <hip/hip_runtime.h>
#include <math.h>

#define HID 25
#define STR 32   // padded node-feature row stride (128B rows)
#define CHUNK 1024
#define FBTHR 0.1f

typedef __attribute__((ext_vector_type(8))) short short8;
typedef __attribute__((ext_vector_type(4))) short short4v;
typedef __attribute__((ext_vector_type(4))) float f32x4;

__device__ __forceinline__ float gelu_f(float x) {
    return 0.5f * x * (1.0f + erff(x * 0.70710678118654752f));
}

// Branchless gelu: A&S 7.1.26 erf approx, |err| <= 1.5e-7 (<< FBTHR; gate-safe,
// fallback recomputes with true erff).
__device__ __forceinline__ float gelu_fast(float x) {
    float y = fabsf(x) * 0.70710678118654752f;
    float t = 1.0f / fmaf(0.3275911f, y, 1.0f);
    float p = fmaf(1.061405429f, t, -1.453152027f);
    p = fmaf(p, t, 1.421413741f);
    p = fmaf(p, t, -0.284496736f);
    p = fmaf(p, t, 0.254829592f);
    p = p * t;
    float e = __expf(-y * y);
    float erfv = fmaf(-p, e, 1.0f);
    float r = copysignf(erfv, x);
    return 0.5f * x * (1.0f + r);
}

__device__ __forceinline__ short f2bf(float f) {
    unsigned u = __float_as_uint(f);
    u = (u + 0x7fffu + ((u >> 16) & 1u)) >> 16;
    return (short)u;
}

// gather 4 consecutive MLP-input slots (k = grp*4 .. grp*4+3) for edge e
__device__ __forceinline__ void gather4(int e, int E, const int* __restrict__ ei,
                                        const float* __restrict__ xt6,
                                        const float* __restrict__ attr, int grp,
                                        float& v0, float& v1, float& v2, float& v3) {
    v0 = v1 = v2 = v3 = 0.f;
    if (e < E) {
        if (grp == 0) {
            const float4 f = *(const float4*)&xt6[(size_t)ei[e] * 8];
            v0 = f.x; v1 = f.y; v2 = f.z; v3 = f.w;
        } else if (grp == 1) {
            int s = ei[e], d = ei[E + e];
            const float2 lo = *(const float2*)&xt6[(size_t)s * 8 + 4];
            const float2 hi = *(const float2*)&xt6[(size_t)d * 8];
            v0 = lo.x; v1 = lo.y; v2 = hi.x; v3 = hi.y;
        } else if (grp == 2) {
            int d = ei[E + e];
            const float2 lo = *(const float2*)&xt6[(size_t)d * 8 + 2];
            const float2 hi = *(const float2*)&xt6[(size_t)d * 8 + 4];
            v0 = lo.x; v1 = lo.y; v2 = hi.x; v3 = hi.y;
        } else {
            v0 = attr[e];
        }
    }
}

// ---------------- node input linear + packed xt6 ----------------
__global__ void k_node_in(const float* __restrict__ x, const float* __restrict__ token,
                          const float* __restrict__ W, const float* __restrict__ b,
                          float* __restrict__ hn, float* __restrict__ xt6, int N) {
    int gid = blockIdx.x * blockDim.x + threadIdx.x;
    int n = gid >> 5, j = gid & 31;
    if (n >= N) return;
    if (j < 8) xt6[(size_t)n * 8 + j] = (j == 0) ? x[n] : ((j < 6) ? token[n * 5 + j - 1] : 0.f);
    if (j >= HID) return;
    float acc = b[j];
    acc += x[n] * W[j];
    #pragma unroll
    for (int i = 0; i < 5; i++) acc += token[n * 5 + i] * W[(i + 1) * HID + j];
    hn[(size_t)n * STR + j] = acc;
}

// ---------------- edge MLP via MFMA (bf16), 16 edges/wave-tile, NO atomics ----------------
__global__ __launch_bounds__(256) void k_edge_mlp_mfma(
    const int* __restrict__ ei, const float* __restrict__ xt6,
    const float* __restrict__ attr, const float* __restrict__ gumbel,
    const float* __restrict__ W0, const float* __restrict__ b0,
    const float* __restrict__ W1, const float* __restrict__ b1,
    const float* __restrict__ W2, const float* __restrict__ b2,
    const float* __restrict__ W3, const float* __restrict__ b3,
    float* __restrict__ eval_, unsigned char* __restrict__ flagv,
    int E, int ntiles, int nwaves) {
    __shared__ short hbuf[4][1024];   // [wave][16x64 bf16 swizzled]
    const int lane = threadIdx.x & 63;
    const int wv = threadIdx.x >> 6;
    const int wid = blockIdx.x * 4 + wv;
    const int grp = lane >> 4, r2 = lane & 15;

    short8 w0f[4], w1f[2][4], w2f[2][4];
    #pragma unroll
    for (int nt = 0; nt < 4; nt++) {
        int col = r2 + 16 * nt;
        #pragma unroll
        for (int j = 0; j < 8; j++) {
            int k = grp * 4 + (j & 3) + 16 * (j >> 2);
            w0f[nt][j] = (k < 13 && col < 50) ? f2bf(W0[k * 50 + col]) : (short)0;
        }
    }
    #pragma unroll
    for (int kt = 0; kt < 2; kt++) {
        #pragma unroll
        for (int nt = 0; nt < 4; nt++) {
            int col = r2 + 16 * nt;
            #pragma unroll
            for (int j = 0; j < 8; j++) {
                int k = kt * 32 + grp * 4 + (j & 3) + 16 * (j >> 2);
                w1f[kt][nt][j] = (k < 50 && col < 50) ? f2bf(W1[k * 50 + col]) : (short)0;
                w2f[kt][nt][j] = (k < 50 && col < 50) ? f2bf(W2[k * 50 + col]) : (short)0;
            }
        }
    }
    float b0v[4], b1v[4], b2v[4], w3dv[4];
    #pragma unroll
    for (int nt = 0; nt < 4; nt++) {
        int col = r2 + 16 * nt;
        b0v[nt] = (col < 50) ? b0[col] : 0.f;
        b1v[nt] = (col < 50) ? b1[col] : 0.f;
        b2v[nt] = (col < 50) ? b2[col] : 0.f;
        w3dv[nt] = (col < 50) ? (W3[col * 2 + 1] - W3[col * 2]) : 0.f;
    }
    const float b3d = b3[1] - b3[0];
    const f32x4 z4 = {0.f, 0.f, 0.f, 0.f};
    short* hb = &hbuf[wv][0];

    for (int t = wid; t < ntiles; t += nwaves) {
        const int base = t * 16;
        float g0, g1, g2, g3;
        gather4(base + r2, E, ei, xt6, attr, grp, g0, g1, g2, g3);
        short8 a0 = {f2bf(g0), f2bf(g1), f2bf(g2), f2bf(g3), 0, 0, 0, 0};

        // ---- layer 0 ----
        f32x4 c0 = __builtin_amdgcn_mfma_f32_16x16x32_bf16(a0, w0f[0], z4, 0, 0, 0);
        f32x4 c1 = __builtin_amdgcn_mfma_f32_16x16x32_bf16(a0, w0f[1], z4, 0, 0, 0);
        f32x4 c2 = __builtin_amdgcn_mfma_f32_16x16x32_bf16(a0, w0f[2], z4, 0, 0, 0);
        f32x4 c3 = __builtin_amdgcn_mfma_f32_16x16x32_bf16(a0, w0f[3], z4, 0, 0, 0);
        #pragma unroll
        for (int i = 0; i < 4; i++) {
            int row = grp * 4 + i, sw = (row & 7) << 3;
            hb[(row * 64 + r2)      ^ sw] = f2bf(gelu_fast(c0[i] + b0v[0]));
            hb[(row * 64 + r2 + 16) ^ sw] = f2bf(gelu_fast(c1[i] + b0v[1]));
            hb[(row * 64 + r2 + 32) ^ sw] = f2bf(gelu_fast(c2[i] + b0v[2]));
            hb[(row * 64 + r2 + 48) ^ sw] = f2bf(gelu_fast(c3[i] + b0v[3]));
        }

        // ---- layer 1 ----
        {
            int row = r2, sw = (row & 7) << 3;
            short4v lo0 = *(const short4v*)&hb[(row * 64 + 0  + grp * 4) ^ sw];
            short4v hi0 = *(const short4v*)&hb[(row * 64 + 16 + grp * 4) ^ sw];
            short4v lo1 = *(const short4v*)&hb[(row * 64 + 32 + grp * 4) ^ sw];
            short4v hi1 = *(const short4v*)&hb[(row * 64 + 48 + grp * 4) ^ sw];
            short8 k0 = {lo0[0], lo0[1], lo0[2], lo0[3], hi0[0], hi0[1], hi0[2], hi0[3]};
            short8 k1 = {lo1[0], lo1[1], lo1[2], lo1[3], hi1[0], hi1[1], hi1[2], hi1[3]};
            c0 = __builtin_amdgcn_mfma_f32_16x16x32_bf16(k1, w1f[1][0],
                 __builtin_amdgcn_mfma_f32_16x16x32_bf16(k0, w1f[0][0], z4, 0, 0, 0), 0, 0, 0);
            c1 = __builtin_amdgcn_mfma_f32_16x16x32_bf16(k1, w1f[1][1],
                 __builtin_amdgcn_mfma_f32_16x16x32_bf16(k0, w1f[0][1], z4, 0, 0, 0), 0, 0, 0);
            c2 = __builtin_amdgcn_mfma_f32_16x16x32_bf16(k1, w1f[1][2],
                 __builtin_amdgcn_mfma_f32_16x16x32_bf16(k0, w1f[0][2], z4, 0, 0, 0), 0, 0, 0);
            c3 = __builtin_amdgcn_mfma_f32_16x16x32_bf16(k1, w1f[1][3],
                 __builtin_amdgcn_mfma_f32_16x16x32_bf16(k0, w1f[0][3], z4, 0, 0, 0), 0, 0, 0);
        }
        #pragma unroll
        for (int i = 0; i < 4; i++) {
            int row = grp * 4 + i, sw = (row & 7) << 3;
            hb[(row * 64 + r2)      ^ sw] = f2bf(gelu_fast(c0[i] + b1v[0]));
            hb[(row * 64 + r2 + 16) ^ sw] = f2bf(gelu_fast(c1[i] + b1v[1]));
            hb[(row * 64 + r2 + 32) ^ sw] = f2bf(gelu_fast(c2[i] + b1v[2]));
            hb[(row * 64 + r2 + 48) ^ sw] = f2bf(gelu_fast(c3[i] + b1v[3]));
        }

        // ---- layer 2 ----
        {
            int row = r2, sw = (row & 7) << 3;
            short4v lo0 = *(const short4v*)&hb[(row * 64 + 0  + grp * 4) ^ sw];
            short4v hi0 = *(const short4v*)&hb[(row * 64 + 16 + grp * 4) ^ sw];
            short4v lo1 = *(const short4v*)&hb[(row * 64 + 32 + grp * 4) ^ sw];
            short4v hi1 = *(const short4v*)&hb[(row * 64 + 48 + grp * 4) ^ sw];
            short8 k0 = {lo0[0], lo0[1], lo0[2], lo0[3], hi0[0], hi0[1], hi0[2], hi0[3]};
            short8 k1 = {lo1[0], lo1[1], lo1[2], lo1[3], hi1[0], hi1[1], hi1[2], hi1[3]};
            c0 = __builtin_amdgcn_mfma_f32_16x16x32_bf16(k1, w2f[1][0],
                 __builtin_amdgcn_mfma_f32_16x16x32_bf16(k0, w2f[0][0], z4, 0, 0, 0), 0, 0, 0);
            c1 = __builtin_amdgcn_mfma_f32_16x16x32_bf16(k1, w2f[1][1],
                 __builtin_amdgcn_mfma_f32_16x16x32_bf16(k0, w2f[0][1], z4, 0, 0, 0), 0, 0, 0);
            c2 = __builtin_amdgcn_mfma_f32_16x16x32_bf16(k1, w2f[1][2],
                 __builtin_amdgcn_mfma_f32_16x16x32_bf16(k0, w2f[0][2], z4, 0, 0, 0), 0, 0, 0);
            c3 = __builtin_amdgcn_mfma_f32_16x16x32_bf16(k1, w2f[1][3],
                 __builtin_amdgcn_mfma_f32_16x16x32_bf16(k0, w2f[0][3], z4, 0, 0, 0), 0, 0, 0);
        }

        float z0 = 0.f, z1 = 0.f, z2 = 0.f, z3 = 0.f;
        #pragma unroll
        for (int i = 0; i < 4; i++) {
            float h0 = gelu_fast(c0[i] + b2v[0]), h1 = gelu_fast(c1[i] + b2v[1]);
            float h2 = gelu_fast(c2[i] + b2v[2]), h3 = gelu_fast(c3[i] + b2v[3]);
            float z = h0 * w3dv[0] + h1 * w3dv[1] + h2 * w3dv[2] + h3 * w3dv[3];
            if (i == 0) z0 = z; else if (i == 1) z1 = z; else if (i == 2) z2 = z; else z3 = z;
        }
        #pragma unroll
        for (int off = 1; off < 16; off <<= 1) {
            z0 += __shfl_xor(z0, off); z1 += __shfl_xor(z1, off);
            z2 += __shfl_xor(z2, off); z3 += __shfl_xor(z3, off);
        }
        if (r2 < 4) {
            int e2 = base + grp * 4 + r2;
            if (e2 < E) {
                float zsel = (r2 == 0) ? z0 : (r2 == 1) ? z1 : (r2 == 2) ? z2 : z3;
                float g0v = gumbel[2 * (long long)e2], g1v = gumbel[2 * (long long)e2 + 1];
                float m = zsel + b3d + g1v - g0v;
                eval_[e2] = (m > 0.f) ? 1.f : 0.f;
                flagv[e2] = (fabsf(m) < FBTHR) ? 1 : 0;
            }
        }
    }
}

// ---------------- flag -> list compaction (one atomic per wave) ----------------
__global__ void k_compact(const unsigned char* __restrict__ flagv,
                          int* __restrict__ flcnt, int* __restrict__ fllist, int E) {
    int e = blockIdx.x * blockDim.x + threadIdx.x;
    bool f = (e < E) && (flagv[e] != 0);
    unsigned long long mask = __ballot(f);
    int lane = threadIdx.x & 63;
    int cnt = __popcll(mask);
    if (cnt == 0) return;
    int leader = __ffsll((long long)mask) - 1;
    int basep = 0;
    if (lane == leader) basep = atomicAdd(flcnt, cnt);
    basep = __shfl(basep, leader);
    if (f) {
        int idx = basep + __popcll(mask & ((1ull << lane) - 1ull));
        fllist[idx] = e;
    }
}

// ---------------- wave-cooperative exact-fp32 fallback ----------------
__global__ __launch_bounds__(256) void k_edge_fb(
    const int* __restrict__ ei, const float* __restrict__ xt6,
    const float* __restrict__ attr, const float* __restrict__ gumbel,
    const float* __restrict__ W0, const float* __restrict__ b0,
    const float* __restrict__ W1, const float* __restrict__ b1,
    const float* __restrict__ W2, const float* __restrict__ b2,
    const float* __restrict__ W3, const float* __restrict__ b3,
    const int* __restrict__ fllist, const int* __restrict__ flcnt,
    float* __restrict__ eval_, int E, int nwaves) {
    __shared__ float buf[4][2][2][64];
    const int lane = threadIdx.x & 63;
    const int wv = threadIdx.x >> 6;
    const int wid = blockIdx.x * 4 + wv;
    const int jw = (lane < 50) ? lane : 49;

    float w0r[16], w1r[52], w2r[52];
    #pragma unroll
    for (int k = 0; k < 13; k++) w0r[k] = W0[k * 50 + jw];
    w0r[13] = 0.f; w0r[14] = 0.f; w0r[15] = 0.f;
    #pragma unroll
    for (int k = 0; k < 50; k++) w1r[k] = W1[k * 50 + jw];
    w1r[50] = 0.f; w1r[51] = 0.f;
    #pragma unroll
    for (int k = 0; k < 50; k++) w2r[k] = W2[k * 50 + jw];
    w2r[50] = 0.f; w2r[51] = 0.f;
    const float b0r = b0[jw], b1r = b1[jw], b2r = b2[jw];
    const float b3_0 = b3[0], b3_1 = b3[1];
    const float w3d = (lane < 50) ? (W3[lane * 2 + 1] - W3[lane * 2]) : 0.f;

    const int g = lane >> 4, r = lane & 15;
    const int cnt = *flcnt;

    for (int base = wid * 2; base < cnt; base += nwaves * 2) {
        if (g < 2) {
            int idx = base + g;
            float val = 0.f;
            if (idx < cnt && r < 13) {
                int e = fllist[idx];
                if (r == 12) val = attr[e];
                else if (r < 6) val = xt6[(size_t)ei[e] * 8 + r];
                else val = xt6[(size_t)ei[E + e] * 8 + (r - 6)];
            }
            buf[wv][0][g][r] = val;
        }

        const float4* a4 = (const float4*)(&buf[wv][0][0][0]);
        const float4* c4 = (const float4*)(&buf[wv][0][1][0]);
        float tA = b0r, tB = b0r;
        #pragma unroll
        for (int c = 0; c < 4; c++) {
            float4 a = a4[c], b = c4[c];
            tA += a.x * w0r[4 * c];     tB += b.x * w0r[4 * c];
            tA += a.y * w0r[4 * c + 1]; tB += b.y * w0r[4 * c + 1];
            tA += a.z * w0r[4 * c + 2]; tB += b.z * w0r[4 * c + 2];
            tA += a.w * w0r[4 * c + 3]; tB += b.w * w0r[4 * c + 3];
        }
        buf[wv][1][0][lane] = gelu_f(tA);
        buf[wv][1][1][lane] = gelu_f(tB);

        const float4* p4 = (const float4*)(&buf[wv][1][0][0]);
        const float4* q4 = (const float4*)(&buf[wv][1][1][0]);
        tA = b1r; tB = b1r;
        #pragma unroll
        for (int c = 0; c < 13; c++) {
            float4 a = p4[c], b = q4[c];
            tA += a.x * w1r[4 * c];     tB += b.x * w1r[4 * c];
            tA += a.y * w1r[4 * c + 1]; tB += b.y * w1r[4 * c + 1];
            tA += a.z * w1r[4 * c + 2]; tB += b.z * w1r[4 * c + 2];
            tA += a.w * w1r[4 * c + 3]; tB += b.w * w1r[4 * c + 3];
        }
        buf[wv][0][0][lane] = gelu_f(tA);
        buf[wv][0][1][lane] = gelu_f(tB);

        tA = b2r; tB = b2r;
        #pragma unroll
        for (int c = 0; c < 13; c++) {
            float4 a = a4[c], b = c4[c];
            tA += a.x * w2r[4 * c];     tB += b.x * w2r[4 * c];
            tA += a.y * w2r[4 * c + 1]; tB += b.y * w2r[4 * c + 1];
            tA += a.z * w2r[4 * c + 2]; tB += b.z * w2r[4 * c + 2];
            tA += a.w * w2r[4 * c + 3]; tB += b.w * w2r[4 * c + 3];
        }
        float h3A = gelu_f(tA), h3B = gelu_f(tB);
        buf[wv][1][0][lane] = h3A;
        buf[wv][1][1][lane] = h3B;

        float zA = h3A * w3d, zB = h3B * w3d;
        #pragma unroll
        for (int off = 32; off > 0; off >>= 1) {
            zA += __shfl_xor(zA, off);
            zB += __shfl_xor(zB, off);
        }

        if (lane < 2) {
            int idx = base + lane;
            if (idx < cnt) {
                int e = fllist[idx];
                float z = (lane == 0) ? zA : zB;
                float g0v = gumbel[2 * (long long)e], g1v = gumbel[2 * (long long)e + 1];
                float m = z + (b3_1 - b3_0) + g1v - g0v;
                float dec;
                if (fabsf(m) < 1e-4f) {
                    float z0 = 0.f, z1 = 0.f;
                    for (int j = 0; j < 50; j++) {
                        float h = buf[wv][1][lane][j];
                        z0 += h * W3[2 * j];
                        z1 += h * W3[2 * j + 1];
                    }
                    z0 += b3_0; z1 += b3_1;
                    dec = (z1 + g1v > z0 + g0v) ? 1.f : 0.f;
                } else {
                    dec = (m > 0.f) ? 1.f : 0.f;
                }
                eval_[e] = dec;
            }
        }
    }
}

// ---------------- CSR build: histogram + scan + scatter ----------------
__global__ void k_hist(const int* __restrict__ ei, int* __restrict__ cnt, int E) {
    int e = blockIdx.x * blockDim.x + threadIdx.x;
    if (e >= E) return;
    atomicAdd(&cnt[ei[E + e]], 1);
}

__global__ void k_scan_partial(const int* __restrict__ cnt, int* __restrict__ bsum, int N) {
    __shared__ int s[256];
    int b = blockIdx.x, t = threadIdx.x;
    int base = b * CHUNK + t * 4;
    int sum = 0;
    #pragma unroll
    for (int u = 0; u < 4; u++) { int idx = base + u; if (idx < N) sum += cnt[idx]; }
    s[t] = sum; __syncthreads();
    for (int off = 128; off > 0; off >>= 1) {
        if (t < off) s[t] += s[t + off];
        __syncthreads();
    }
    if (t == 0) bsum[b] = s[0];
}

__global__ void k_scan_top(const int* __restrict__ bsum, int* __restrict__ boff,
                           int* __restrict__ rowptr, int nb, int N, int E) {
    if (threadIdx.x == 0 && blockIdx.x == 0) {
        int run = 0;
        for (int i = 0; i < nb; i++) { boff[i] = run; run += bsum[i]; }
        rowptr[N] = E;
    }
}

__global__ void k_scan_final(const int* __restrict__ cnt, const int* __restrict__ boff,
                             int* __restrict__ rowptr, int* __restrict__ wpos, int N) {
    __shared__ int s[256];
    int b = blockIdx.x, t = threadIdx.x;
    int base = b * CHUNK + t * 4;
    int v0 = 0, v1 = 0, v2 = 0, v3 = 0;
    if (base     < N) v0 = cnt[base];
    if (base + 1 < N) v1 = cnt[base + 1];
    if (base + 2 < N) v2 = cnt[base + 2];
    if (base + 3 < N) v3 = cnt[base + 3];
    int ts = v0 + v1 + v2 + v3;
    s[t] = ts; __syncthreads();
    for (int off = 1; off < 256; off <<= 1) {
        int xv = (t >= off) ? s[t - off] : 0;
        __syncthreads();
        s[t] += xv;
        __syncthreads();
    }
    int excl = s[t] - ts + boff[b];
    if (base     < N) { rowptr[base]     = excl;                 wpos[base]     = excl; }
    if (base + 1 < N) { int p = excl + v0;           rowptr[base + 1] = p; wpos[base + 1] = p; }
    if (base + 2 < N) { int p = excl + v0 + v1;      rowptr[base + 2] = p; wpos[base + 2] = p; }
    if (base + 3 < N) { int p = excl + v0 + v1 + v2; rowptr[base + 3] = p; wpos[base + 3] = p; }
}

__global__ void k_scatter(const int* __restrict__ ei, int* __restrict__ wpos,
                          int* __restrict__ col, int E) {
    int e = blockIdx.x * blockDim.x + threadIdx.x;
    if (e >= E) return;
    int d = ei[E + e];
    int p = atomicAdd(&wpos[d], 1);
    col[p] = e;
}

// ---------------- per-layer node transform ----------------
__global__ void k_qkvs(const float* __restrict__ hn,
                       const float* __restrict__ Wq, const float* __restrict__ bq,
                       const float* __restrict__ Wk, const float* __restrict__ bk,
                       const float* __restrict__ Wv, const float* __restrict__ bv,
                       const float* __restrict__ Ws, const float* __restrict__ bs,
                       float* __restrict__ q, float* __restrict__ k, float* __restrict__ v,
                       float* __restrict__ hnext, int N) {
    __shared__ float sWq[625], sWk[625], sWv[625], sWs[625], sbq[25], sbk[25], sbv[25], sbs[25];
    for (int i = threadIdx.x; i < 625; i += blockDim.x) {
        sWq[i] = Wq[i]; sWk[i] = Wk[i]; sWv[i] = Wv[i]; sWs[i] = Ws[i];
    }
    if (threadIdx.x < 25) {
        sbq[threadIdx.x] = bq[threadIdx.x]; sbk[threadIdx.x] = bk[threadIdx.x];
        sbv[threadIdx.x] = bv[threadIdx.x]; sbs[threadIdx.x] = bs[threadIdx.x];
    }
    __syncthreads();
    int gid = blockIdx.x * blockDim.x + threadIdx.x;
    int n = gid >> 5, j = gid & 31;
    if (n >= N || j >= HID) return;
    float h[25];
    #pragma unroll
    for (int i = 0; i < 25; i++) h[i] = hn[(size_t)n * STR + i];
    float aq = sbq[j], ak = sbk[j], av = sbv[j], as = sbs[j];
    #pragma unroll
    for (int i = 0; i < 25; i++) {
        float hi = h[i];
        aq += hi * sWq[i * 25 + j];
        ak += hi * sWk[i * 25 + j];
        av += hi * sWv[i * 25 + j];
        as += hi * sWs[i * 25 + j];
    }
    size_t o = (size_t)n * STR + j;
    q[o] = aq; k[o] = ak; v[o] = av; hnext[o] = as;
}

// ---------------- fused node-centric attention, 4 lanes per node ----------------
__global__ void k_attn_node(const int* __restrict__ rowptr, const int* __restrict__ col,
                            const int* __restrict__ ei,
                            const float* __restrict__ q, const float* __restrict__ kk,
                            const float* __restrict__ v, const float* __restrict__ attr,
                            const float* __restrict__ eval_,
                            const float* __restrict__ We, const float* __restrict__ be,
                            float* __restrict__ hnext, int N, int E) {
    int gid = blockIdx.x * blockDim.x + threadIdx.x;
    int n = gid >> 2, sub = gid & 3;
    if (n >= N) return;
    const float scale = 0.44721359549995793f;

    float qr[25];
    #pragma unroll
    for (int i = 0; i < 25; i++) qr[i] = q[(size_t)n * STR + i];

    float qW0[5], qW1[5], qbe[5];
    #pragma unroll
    for (int h = 0; h < 5; h++) {
        float a0 = 0.f, a1 = 0.f, ab = 0.f;
        #pragma unroll
        for (int c = 0; c < 5; c++) {
            int i = h * 5 + c;
            a0 += qr[i] * We[i];
            a1 += qr[i] * We[25 + i];
            ab += qr[i] * be[i];
        }
        qW0[h] = a0; qW1[h] = a1; qbe[h] = ab;
    }

    float accV[25];
    #pragma unroll
    for (int i = 0; i < 25; i++) accV[i] = 0.f;
    float den[5] = {0, 0, 0, 0, 0}, sA[5] = {0, 0, 0, 0, 0}, sG[5] = {0, 0, 0, 0, 0};

    int beg = rowptr[n], end = rowptr[n + 1];
    for (int p = beg + sub; p < end; p += 4) {
        int e = col[p];
        int s = ei[e];
        float a_ = attr[e], gl = eval_[e];
        const float* kr = kk + (size_t)s * STR;
        const float* vr = v + (size_t)s * STR;
        #pragma unroll
        for (int h = 0; h < 5; h++) {
            float al = qW0[h] * a_ + qW1[h] * gl + qbe[h];
            #pragma unroll
            for (int c = 0; c < 5; c++) { int i = h * 5 + c; al += qr[i] * kr[i]; }
            float ex = __expf(al * scale);
            den[h] += ex;
            sA[h] += ex * a_;
            sG[h] += ex * gl;
            #pragma unroll
            for (int c = 0; c < 5; c++) { int i = h * 5 + c; accV[i] += ex * vr[i]; }
        }
    }

    // combine the 4 sub-lanes (consecutive lanes of one wave)
    #pragma unroll
    for (int off = 1; off < 4; off <<= 1) {
        #pragma unroll
        for (int i = 0; i < 25; i++) accV[i] += __shfl_xor(accV[i], off);
        #pragma unroll
        for (int h = 0; h < 5; h++) {
            den[h] += __shfl_xor(den[h], off);
            sA[h] += __shfl_xor(sA[h], off);
            sG[h] += __shfl_xor(sG[h], off);
        }
    }

    if (sub == 0) {
        #pragma unroll
        for (int h = 0; h < 5; h++) {
            float inv = 1.f / (den[h] + 1e-16f);
            #pragma unroll
            for (int c = 0; c < 5; c++) {
                int i = h * 5 + c;
                float agg = (accV[i] + sA[h] * We[i] + sG[h] * We[25 + i] + den[h] * be[i]) * inv;
                hnext[(size_t)n * STR + i] += agg;
            }
        }
    }
}

// ---------------- output ----------------
__global__ void k_out(const float* __restrict__ hn, const float* __restrict__ W,
                      const float* __restrict__ b, float* __restrict__ out, int N) {
    int n = blockIdx.x * blockDim.x + threadIdx.x;
    if (n >= N) return;
    float acc = b[0];
    #pragma unroll
    for (int i = 0; i < 25; i++) acc += hn[(size_t)n * STR + i] * W[i];
    out[n] = 1.f / (1.f + expf(-acc));
}

extern "C" void kernel_launch(void* const* d_in, const int* in_sizes, int n_in,
                              void* d_out, int out_size, void* d_ws, size_t ws_size,
                              hipStream_t stream) {
    const float* x      = (const float*)d_in[0];
    const float* token  = (const float*)d_in[1];
    const float* attr   = (const float*)d_in[2];
    const float* gumbel = (const float*)d_in[3];
    const int*   ei     = (const int*)d_in[4];
    const float* W0 = (const float*)d_in[5];
    const float* b0 = (const float*)d_in[6];
    const float* W1 = (const float*)d_in[7];
    const float* b1 = (const float*)d_in[8];
    const float* W2 = (const float*)d_in[9];
    const float* b2 = (const float*)d_in[10];
    const float* W3 = (const float*)d_in[11];
    const float* b3 = (const float*)d_in[12];
    const float* ilW = (const float*)d_in[13];
    const float* ilb = (const float*)d_in[14];
    const float* Wq = (const float*)d_in[15];
    const float* bq = (const float*)d_in[16];
    const float* Wk = (const float*)d_in[17];
    const float* bk = (const float*)d_in[18];
    const float* Wv = (const float*)d_in[19];
    const float* bv = (const float*)d_in[20];
    const float* We = (const float*)d_in[21];
    const float* be = (const float*)d_in[22];
    const float* Ws = (const float*)d_in[23];
    const float* bs = (const float*)d_in[24];
    const float* oW = (const float*)d_in[25];
    const float* ob = (const float*)d_in[26];

    const int N = in_sizes[0];
    const int E = in_sizes[2];
    const int nb_chunk = (N + CHUNK - 1) / CHUNK;

    char* ws = (char*)d_ws;
    size_t off = 0;
    auto alloc = [&](size_t nb) -> void* {
        void* p = ws + off;
        off += (nb + 255) & ~(size_t)255;
        return p;
    };
    float* hnA    = (float*)alloc((size_t)N * STR * 4);
    float* hnB    = (float*)alloc((size_t)N * STR * 4);
    float* q      = (float*)alloc((size_t)N * STR * 4);
    float* k      = (float*)alloc((size_t)N * STR * 4);
    float* v      = (float*)alloc((size_t)N * STR * 4);
    float* evalv  = (float*)alloc((size_t)E * 4);
    float* xt6    = (float*)alloc((size_t)N * 8 * 4);
    int*   cnt    = (int*)alloc((size_t)N * 4);
    int*   rowptr = (int*)alloc((size_t)(N + 1) * 4);
    int*   wpos   = (int*)alloc((size_t)N * 4);
    int*   bsum   = (int*)alloc((size_t)(nb_chunk + 1) * 4);
    int*   boff   = (int*)alloc((size_t)(nb_chunk + 1) * 4);
    int*   col    = (int*)alloc((size_t)E * 4);
    int*   flcnt  = (int*)alloc(256);
    int*   fllist = (int*)alloc((size_t)E * 4);
    unsigned char* flagv = (unsigned char*)alloc((size_t)E);

    int nb_n32 = (N * STR + 255) / 256;
    int nb_e   = (E + 255) / 256;
    int nb_n4  = (N * 4 + 255) / 256;
    int nb_n   = (N + 255) / 256;

    const int mlp_blocks = 4096;
    const int mlp_waves  = mlp_blocks * 4;
    const int ntiles     = (E + 15) / 16;

    hipMemsetAsync(cnt, 0, (size_t)N * 4, stream);
    hipMemsetAsync(flcnt, 0, 4, stream);
    k_node_in<<<nb_n32, 256, 0, stream>>>(x, token, ilW, ilb, hnA, xt6, N);
    k_edge_mlp_mfma<<<mlp_blocks, 256, 0, stream>>>(ei, xt6, attr, gumbel,
                                                    W0, b0, W1, b1, W2, b2, W3, b3,
                                                    evalv, flagv, E, ntiles, mlp_waves);
    k_compact<<<nb_e, 256, 0, stream>>>(flagv, flcnt, fllist, E);
    k_edge_fb<<<2048, 256, 0, stream>>>(ei, xt6, attr, gumbel,
                                        W0, b0, W1, b1, W2, b2, W3, b3,
                                        fllist, flcnt, evalv, E, 2048 * 4);
    k_hist<<<nb_e, 256, 0, stream>>>(ei, cnt, E);
    k_scan_partial<<<nb_chunk, 256, 0, stream>>>(cnt, bsum, N);
    k_scan_top<<<1, 64, 0, stream>>>(bsum, boff, rowptr, nb_chunk, N, E);
    k_scan_final<<<nb_chunk, 256, 0, stream>>>(cnt, boff, rowptr, wpos, N);
    k_scatter<<<nb_e, 256, 0, stream>>>(ei, wpos, col, E);

    float* cur = hnA;
    float* nxt = hnB;
    for (int l = 0; l < 3; l++) {
        k_qkvs<<<nb_n32, 256, 0, stream>>>(cur, Wq + l * 625, bq + l * 25,
                                           Wk + l * 625, bk + l * 25,
                                           Wv + l * 625, bv + l * 25,
                                           Ws + l * 625, bs + l * 25,
                                           q, k, v, nxt, N);
        k_attn_node<<<nb_n4, 256, 0, stream>>>(rowptr, col, ei, q, k, v, attr, evalv,
                                               We + l * 50, be + l * 25, nxt, N, E);
        float* t = cur; cur = nxt; nxt = t;
    }
    k_out<<<nb_n, 256, 0, stream>>>(cur, oW, ob, (float*)d_out, N);
}

// Round 12
// 2163.117 us; speedup vs baseline: 1.7300x; 1.3130x over previous
//
#include <hip/hip_runtime.h>
#include <math.h>

#define HID 25
#define STR 32   // padded node-feature row stride (128B rows)
#define CHUNK 1024
#define FBTHR 0.1f
#define RST 72   // LDS activation row stride in bf16 (144B; conflict-managed)

typedef __attribute__((ext_vector_type(8))) short short8;
typedef __attribute__((ext_vector_type(4))) float f32x4;

__device__ __forceinline__ float gelu_f(float x) {
    return 0.5f * x * (1.0f + erff(x * 0.70710678118654752f));
}

// Branchless gelu: A&S 7.1.26 erf approx, |err| <= 1.5e-7 (<< FBTHR; gate-safe,
// fallback recomputes with true erff).
__device__ __forceinline__ float gelu_fast(float x) {
    float y = fabsf(x) * 0.70710678118654752f;
    float t = __builtin_amdgcn_rcpf(fmaf(0.3275911f, y, 1.0f));
    float p = fmaf(1.061405429f, t, -1.453152027f);
    p = fmaf(p, t, 1.421413741f);
    p = fmaf(p, t, -0.284496736f);
    p = fmaf(p, t, 0.254829592f);
    p = p * t;
    float e = __expf(-y * y);
    float erfv = fmaf(-p, e, 1.0f);
    float r = copysignf(erfv, x);
    return 0.5f * x * (1.0f + r);
}

__device__ __forceinline__ short f2bf(float f) {
    unsigned u = __float_as_uint(f);
    u = (u + 0x7fffu + ((u >> 16) & 1u)) >> 16;
    return (short)u;
}

// gather 4 consecutive MLP-input slots (k = grp*4 .. grp*4+3) for edge e
__device__ __forceinline__ void gather4(int e, int E, const int* __restrict__ ei,
                                        const float* __restrict__ xt6,
                                        const float* __restrict__ attr, int grp,
                                        float& v0, float& v1, float& v2, float& v3) {
    v0 = v1 = v2 = v3 = 0.f;
    if (e < E) {
        if (grp == 0) {
            const float4 f = *(const float4*)&xt6[(size_t)ei[e] * 8];
            v0 = f.x; v1 = f.y; v2 = f.z; v3 = f.w;
        } else if (grp == 1) {
            int s = ei[e], d = ei[E + e];
            const float2 lo = *(const float2*)&xt6[(size_t)s * 8 + 4];
            const float2 hi = *(const float2*)&xt6[(size_t)d * 8];
            v0 = lo.x; v1 = lo.y; v2 = hi.x; v3 = hi.y;
        } else if (grp == 2) {
            int d = ei[E + e];
            const float2 lo = *(const float2*)&xt6[(size_t)d * 8 + 2];
            const float2 hi = *(const float2*)&xt6[(size_t)d * 8 + 4];
            v0 = lo.x; v1 = lo.y; v2 = hi.x; v3 = hi.y;
        } else {
            v0 = attr[e];
        }
    }
}

// ---------------- node input linear + packed xt6 ----------------
__global__ void k_node_in(const float* __restrict__ x, const float* __restrict__ token,
                          const float* __restrict__ W, const float* __restrict__ b,
                          float* __restrict__ hn, float* __restrict__ xt6, int N) {
    int gid = blockIdx.x * blockDim.x + threadIdx.x;
    int n = gid >> 5, j = gid & 31;
    if (n >= N) return;
    if (j < 8) xt6[(size_t)n * 8 + j] = (j == 0) ? x[n] : ((j < 6) ? token[n * 5 + j - 1] : 0.f);
    if (j >= HID) return;
    float acc = b[j];
    acc += x[n] * W[j];
    #pragma unroll
    for (int i = 0; i < 5; i++) acc += token[n * 5 + i] * W[(i + 1) * HID + j];
    hn[(size_t)n * STR + j] = acc;
}

// ---------------- edge MLP via MFMA (bf16), col'-layout LDS ----------------
// Neuron c stored at LDS col' = (c&15)*4 + (c>>4): stores = contiguous 4×bf16
// (2 cvt_pk + 1 ds_write_b64), loads = one aligned ds_read_b128 per k-fragment.
// B-fragments use matching neuron map cW = (j&3)*16 + kt*8 + grp*2 + (j>>2)
// (common k-permutation cancels between A and B).
__global__ __launch_bounds__(256) void k_edge_mlp_mfma(
    const int* __restrict__ ei, const float* __restrict__ xt6,
    const float* __restrict__ attr, const float* __restrict__ gumbel,
    const float* __restrict__ W0, const float* __restrict__ b0,
    const float* __restrict__ W1, const float* __restrict__ b1,
    const float* __restrict__ W2, const float* __restrict__ b2,
    const float* __restrict__ W3, const float* __restrict__ b3,
    float* __restrict__ eval_, unsigned char* __restrict__ flagv,
    int E, int ntiles, int nwaves) {
    __shared__ short hbuf[4][16 * RST];
    const int lane = threadIdx.x & 63;
    const int wv = threadIdx.x >> 6;
    const int wid = blockIdx.x * 4 + wv;
    const int grp = lane >> 4, r2 = lane & 15;

    // layer0 B-frags: input k = grp*4 + (j&3) + 16*(j>>2) (13 inputs, zero-pad)
    short8 w0f[4], w1f[2][4], w2f[2][4];
    #pragma unroll
    for (int nt = 0; nt < 4; nt++) {
        int col = r2 + 16 * nt;
        #pragma unroll
        for (int j = 0; j < 8; j++) {
            int k = grp * 4 + (j & 3) + 16 * (j >> 2);
            w0f[nt][j] = (k < 13 && col < 50) ? f2bf(W0[k * 50 + col]) : (short)0;
        }
    }
    // layer1/2 B-frags with col'-layout input-neuron map
    #pragma unroll
    for (int kt = 0; kt < 2; kt++) {
        #pragma unroll
        for (int nt = 0; nt < 4; nt++) {
            int col = r2 + 16 * nt;
            #pragma unroll
            for (int j = 0; j < 8; j++) {
                int cW = (j & 3) * 16 + kt * 8 + grp * 2 + (j >> 2);
                w1f[kt][nt][j] = (cW < 50 && col < 50) ? f2bf(W1[cW * 50 + col]) : (short)0;
                w2f[kt][nt][j] = (cW < 50 && col < 50) ? f2bf(W2[cW * 50 + col]) : (short)0;
            }
        }
    }
    float b0v[4], b1v[4], b2v[4], w3dv[4];
    #pragma unroll
    for (int nt = 0; nt < 4; nt++) {
        int col = r2 + 16 * nt;
        b0v[nt] = (col < 50) ? b0[col] : 0.f;
        b1v[nt] = (col < 50) ? b1[col] : 0.f;
        b2v[nt] = (col < 50) ? b2[col] : 0.f;
        w3dv[nt] = (col < 50) ? (W3[col * 2 + 1] - W3[col * 2]) : 0.f;
    }
    const float b3d = b3[1] - b3[0];
    const f32x4 z4 = {0.f, 0.f, 0.f, 0.f};
    short* hb = &hbuf[wv][0];

    for (int t = wid; t < ntiles; t += nwaves) {
        const int base = t * 16;
        float g0, g1, g2, g3;
        gather4(base + r2, E, ei, xt6, attr, grp, g0, g1, g2, g3);
        short8 a0 = {f2bf(g0), f2bf(g1), f2bf(g2), f2bf(g3), 0, 0, 0, 0};

        // ---- layer 0 ----
        f32x4 c0 = __builtin_amdgcn_mfma_f32_16x16x32_bf16(a0, w0f[0], z4, 0, 0, 0);
        f32x4 c1 = __builtin_amdgcn_mfma_f32_16x16x32_bf16(a0, w0f[1], z4, 0, 0, 0);
        f32x4 c2 = __builtin_amdgcn_mfma_f32_16x16x32_bf16(a0, w0f[2], z4, 0, 0, 0);
        f32x4 c3 = __builtin_amdgcn_mfma_f32_16x16x32_bf16(a0, w0f[3], z4, 0, 0, 0);
        #pragma unroll
        for (int i = 0; i < 4; i++) {
            int row = grp * 4 + i;
            float v0 = gelu_fast(c0[i] + b0v[0]);
            float v1 = gelu_fast(c1[i] + b0v[1]);
            float v2 = gelu_fast(c2[i] + b0v[2]);
            float v3 = gelu_fast(c3[i] + b0v[3]);
            unsigned lo, hi;
            asm("v_cvt_pk_bf16_f32 %0, %1, %2" : "=v"(lo) : "v"(v0), "v"(v1));
            asm("v_cvt_pk_bf16_f32 %0, %1, %2" : "=v"(hi) : "v"(v2), "v"(v3));
            *(int2*)&hb[row * RST + r2 * 4] = make_int2((int)lo, (int)hi);
        }

        // ---- layer 1 ----
        {
            short8 k0 = *(const short8*)&hb[r2 * RST + 0 * 32 + grp * 8];
            short8 k1 = *(const short8*)&hb[r2 * RST + 1 * 32 + grp * 8];
            c0 = __builtin_amdgcn_mfma_f32_16x16x32_bf16(k1, w1f[1][0],
                 __builtin_amdgcn_mfma_f32_16x16x32_bf16(k0, w1f[0][0], z4, 0, 0, 0), 0, 0, 0);
            c1 = __builtin_amdgcn_mfma_f32_16x16x32_bf16(k1, w1f[1][1],
                 __builtin_amdgcn_mfma_f32_16x16x32_bf16(k0, w1f[0][1], z4, 0, 0, 0), 0, 0, 0);
            c2 = __builtin_amdgcn_mfma_f32_16x16x32_bf16(k1, w1f[1][2],
                 __builtin_amdgcn_mfma_f32_16x16x32_bf16(k0, w1f[0][2], z4, 0, 0, 0), 0, 0, 0);
            c3 = __builtin_amdgcn_mfma_f32_16x16x32_bf16(k1, w1f[1][3],
                 __builtin_amdgcn_mfma_f32_16x16x32_bf16(k0, w1f[0][3], z4, 0, 0, 0), 0, 0, 0);
        }
        #pragma unroll
        for (int i = 0; i < 4; i++) {
            int row = grp * 4 + i;
            float v0 = gelu_fast(c0[i] + b1v[0]);
            float v1 = gelu_fast(c1[i] + b1v[1]);
            float v2 = gelu_fast(c2[i] + b1v[2]);
            float v3 = gelu_fast(c3[i] + b1v[3]);
            unsigned lo, hi;
            asm("v_cvt_pk_bf16_f32 %0, %1, %2" : "=v"(lo) : "v"(v0), "v"(v1));
            asm("v_cvt_pk_bf16_f32 %0, %1, %2" : "=v"(hi) : "v"(v2), "v"(v3));
            *(int2*)&hb[row * RST + r2 * 4] = make_int2((int)lo, (int)hi);
        }

        // ---- layer 2 ----
        {
            short8 k0 = *(const short8*)&hb[r2 * RST + 0 * 32 + grp * 8];
            short8 k1 = *(const short8*)&hb[r2 * RST + 1 * 32 + grp * 8];
            c0 = __builtin_amdgcn_mfma_f32_16x16x32_bf16(k1, w2f[1][0],
                 __builtin_amdgcn_mfma_f32_16x16x32_bf16(k0, w2f[0][0], z4, 0, 0, 0), 0, 0, 0);
            c1 = __builtin_amdgcn_mfma_f32_16x16x32_bf16(k1, w2f[1][1],
                 __builtin_amdgcn_mfma_f32_16x16x32_bf16(k0, w2f[0][1], z4, 0, 0, 0), 0, 0, 0);
            c2 = __builtin_amdgcn_mfma_f32_16x16x32_bf16(k1, w2f[1][2],
                 __builtin_amdgcn_mfma_f32_16x16x32_bf16(k0, w2f[0][2], z4, 0, 0, 0), 0, 0, 0);
            c3 = __builtin_amdgcn_mfma_f32_16x16x32_bf16(k1, w2f[1][3],
                 __builtin_amdgcn_mfma_f32_16x16x32_bf16(k0, w2f[0][3], z4, 0, 0, 0), 0, 0, 0);
        }

        float z0 = 0.f, z1 = 0.f, z2 = 0.f, z3 = 0.f;
        #pragma unroll
        for (int i = 0; i < 4; i++) {
            float h0 = gelu_fast(c0[i] + b2v[0]), h1 = gelu_fast(c1[i] + b2v[1]);
            float h2 = gelu_fast(c2[i] + b2v[2]), h3 = gelu_fast(c3[i] + b2v[3]);
            float z = h0 * w3dv[0] + h1 * w3dv[1] + h2 * w3dv[2] + h3 * w3dv[3];
            if (i == 0) z0 = z; else if (i == 1) z1 = z; else if (i == 2) z2 = z; else z3 = z;
        }
        #pragma unroll
        for (int off = 1; off < 16; off <<= 1) {
            z0 += __shfl_xor(z0, off); z1 += __shfl_xor(z1, off);
            z2 += __shfl_xor(z2, off); z3 += __shfl_xor(z3, off);
        }
        if (r2 < 4) {
            int e2 = base + grp * 4 + r2;
            if (e2 < E) {
                float zsel = (r2 == 0) ? z0 : (r2 == 1) ? z1 : (r2 == 2) ? z2 : z3;
                float g0v = gumbel[2 * (long long)e2], g1v = gumbel[2 * (long long)e2 + 1];
                float m = zsel + b3d + g1v - g0v;
                eval_[e2] = (m > 0.f) ? 1.f : 0.f;
                flagv[e2] = (fabsf(m) < FBTHR) ? 1 : 0;
            }
        }
    }
}

// ---------------- flag -> list compaction (one atomic per wave) ----------------
__global__ void k_compact(const unsigned char* __restrict__ flagv,
                          int* __restrict__ flcnt, int* __restrict__ fllist, int E) {
    int e = blockIdx.x * blockDim.x + threadIdx.x;
    bool f = (e < E) && (flagv[e] != 0);
    unsigned long long mask = __ballot(f);
    int lane = threadIdx.x & 63;
    int cnt = __popcll(mask);
    if (cnt == 0) return;
    int leader = __ffsll((long long)mask) - 1;
    int basep = 0;
    if (lane == leader) basep = atomicAdd(flcnt, cnt);
    basep = __shfl(basep, leader);
    if (f) {
        int idx = basep + __popcll(mask & ((1ull << lane) - 1ull));
        fllist[idx] = e;
    }
}

// ---------------- wave-cooperative exact-fp32 fallback ----------------
__global__ __launch_bounds__(256) void k_edge_fb(
    const int* __restrict__ ei, const float* __restrict__ xt6,
    const float* __restrict__ attr, const float* __restrict__ gumbel,
    const float* __restrict__ W0, const float* __restrict__ b0,
    const float* __restrict__ W1, const float* __restrict__ b1,
    const float* __restrict__ W2, const float* __restrict__ b2,
    const float* __restrict__ W3, const float* __restrict__ b3,
    const int* __restrict__ fllist, const int* __restrict__ flcnt,
    float* __restrict__ eval_, int E, int nwaves) {
    __shared__ float buf[4][2][2][64];
    const int lane = threadIdx.x & 63;
    const int wv = threadIdx.x >> 6;
    const int wid = blockIdx.x * 4 + wv;
    const int jw = (lane < 50) ? lane : 49;

    float w0r[16], w1r[52], w2r[52];
    #pragma unroll
    for (int k = 0; k < 13; k++) w0r[k] = W0[k * 50 + jw];
    w0r[13] = 0.f; w0r[14] = 0.f; w0r[15] = 0.f;
    #pragma unroll
    for (int k = 0; k < 50; k++) w1r[k] = W1[k * 50 + jw];
    w1r[50] = 0.f; w1r[51] = 0.f;
    #pragma unroll
    for (int k = 0; k < 50; k++) w2r[k] = W2[k * 50 + jw];
    w2r[50] = 0.f; w2r[51] = 0.f;
    const float b0r = b0[jw], b1r = b1[jw], b2r = b2[jw];
    const float b3_0 = b3[0], b3_1 = b3[1];
    const float w3d = (lane < 50) ? (W3[lane * 2 + 1] - W3[lane * 2]) : 0.f;

    const int g = lane >> 4, r = lane & 15;
    const int cnt = *flcnt;

    for (int base = wid * 2; base < cnt; base += nwaves * 2) {
        if (g < 2) {
            int idx = base + g;
            float val = 0.f;
            if (idx < cnt && r < 13) {
                int e = fllist[idx];
                if (r == 12) val = attr[e];
                else if (r < 6) val = xt6[(size_t)ei[e] * 8 + r];
                else val = xt6[(size_t)ei[E + e] * 8 + (r - 6)];
            }
            buf[wv][0][g][r] = val;
        }

        const float4* a4 = (const float4*)(&buf[wv][0][0][0]);
        const float4* c4 = (const float4*)(&buf[wv][0][1][0]);
        float tA = b0r, tB = b0r;
        #pragma unroll
        for (int c = 0; c < 4; c++) {
            float4 a = a4[c], b = c4[c];
            tA += a.x * w0r[4 * c];     tB += b.x * w0r[4 * c];
            tA += a.y * w0r[4 * c + 1]; tB += b.y * w0r[4 * c + 1];
            tA += a.z * w0r[4 * c + 2]; tB += b.z * w0r[4 * c + 2];
            tA += a.w * w0r[4 * c + 3]; tB += b.w * w0r[4 * c + 3];
        }
        buf[wv][1][0][lane] = gelu_f(tA);
        buf[wv][1][1][lane] = gelu_f(tB);

        const float4* p4 = (const float4*)(&buf[wv][1][0][0]);
        const float4* q4 = (const float4*)(&buf[wv][1][1][0]);
        tA = b1r; tB = b1r;
        #pragma unroll
        for (int c = 0; c < 13; c++) {
            float4 a = p4[c], b = q4[c];
            tA += a.x * w1r[4 * c];     tB += b.x * w1r[4 * c];
            tA += a.y * w1r[4 * c + 1]; tB += b.y * w1r[4 * c + 1];
            tA += a.z * w1r[4 * c + 2]; tB += b.z * w1r[4 * c + 2];
            tA += a.w * w1r[4 * c + 3]; tB += b.w * w1r[4 * c + 3];
        }
        buf[wv][0][0][lane] = gelu_f(tA);
        buf[wv][0][1][lane] = gelu_f(tB);

        tA = b2r; tB = b2r;
        #pragma unroll
        for (int c = 0; c < 13; c++) {
            float4 a = a4[c], b = c4[c];
            tA += a.x * w2r[4 * c];     tB += b.x * w2r[4 * c];
            tA += a.y * w2r[4 * c + 1]; tB += b.y * w2r[4 * c + 1];
            tA += a.z * w2r[4 * c + 2]; tB += b.z * w2r[4 * c + 2];
            tA += a.w * w2r[4 * c + 3]; tB += b.w * w2r[4 * c + 3];
        }
        float h3A = gelu_f(tA), h3B = gelu_f(tB);
        buf[wv][1][0][lane] = h3A;
        buf[wv][1][1][lane] = h3B;

        float zA = h3A * w3d, zB = h3B * w3d;
        #pragma unroll
        for (int off = 32; off > 0; off >>= 1) {
            zA += __shfl_xor(zA, off);
            zB += __shfl_xor(zB, off);
        }

        if (lane < 2) {
            int idx = base + lane;
            if (idx < cnt) {
                int e = fllist[idx];
                float z = (lane == 0) ? zA : zB;
                float g0v = gumbel[2 * (long long)e], g1v = gumbel[2 * (long long)e + 1];
                float m = z + (b3_1 - b3_0) + g1v - g0v;
                float dec;
                if (fabsf(m) < 1e-4f) {
                    float z0 = 0.f, z1 = 0.f;
                    for (int j = 0; j < 50; j++) {
                        float h = buf[wv][1][lane][j];
                        z0 += h * W3[2 * j];
                        z1 += h * W3[2 * j + 1];
                    }
                    z0 += b3_0; z1 += b3_1;
                    dec = (z1 + g1v > z0 + g0v) ? 1.f : 0.f;
                } else {
                    dec = (m > 0.f) ? 1.f : 0.f;
                }
                eval_[e] = dec;
            }
        }
    }
}

// ---------------- CSR build: histogram (x4) + scan + scatter(+pack) ----------------
__global__ void k_hist(const int* __restrict__ ei, int* __restrict__ cnt, int E) {
    int i = blockIdx.x * blockDim.x + threadIdx.x;
    int e = i * 4;
    if (e + 3 < E) {
        int4 d = *(const int4*)&ei[E + e];
        atomicAdd(&cnt[d.x], 1); atomicAdd(&cnt[d.y], 1);
        atomicAdd(&cnt[d.z], 1); atomicAdd(&cnt[d.w], 1);
    } else {
        for (int u = e; u < E; u++) atomicAdd(&cnt[ei[E + u]], 1);
    }
}

__global__ void k_scan_partial(const int* __restrict__ cnt, int* __restrict__ bsum, int N) {
    __shared__ int s[256];
    int b = blockIdx.x, t = threadIdx.x;
    int base = b * CHUNK + t * 4;
    int sum = 0;
    #pragma unroll
    for (int u = 0; u < 4; u++) { int idx = base + u; if (idx < N) sum += cnt[idx]; }
    s[t] = sum; __syncthreads();
    for (int off = 128; off > 0; off >>= 1) {
        if (t < off) s[t] += s[t + off];
        __syncthreads();
    }
    if (t == 0) bsum[b] = s[0];
}

__global__ void k_scan_top(const int* __restrict__ bsum, int* __restrict__ boff,
                           int* __restrict__ rowptr, int nb, int N, int E) {
    if (threadIdx.x == 0 && blockIdx.x == 0) {
        int run = 0;
        for (int i = 0; i < nb; i++) { boff[i] = run; run += bsum[i]; }
        rowptr[N] = E;
    }
}

__global__ void k_scan_final(const int* __restrict__ cnt, const int* __restrict__ boff,
                             int* __restrict__ rowptr, int* __restrict__ wpos, int N) {
    __shared__ int s[256];
    int b = blockIdx.x, t = threadIdx.x;
    int base = b * CHUNK + t * 4;
    int v0 = 0, v1 = 0, v2 = 0, v3 = 0;
    if (base     < N) v0 = cnt[base];
    if (base + 1 < N) v1 = cnt[base + 1];
    if (base + 2 < N) v2 = cnt[base + 2];
    if (base + 3 < N) v3 = cnt[base + 3];
    int ts = v0 + v1 + v2 + v3;
    s[t] = ts; __syncthreads();
    for (int off = 1; off < 256; off <<= 1) {
        int xv = (t >= off) ? s[t - off] : 0;
        __syncthreads();
        s[t] += xv;
        __syncthreads();
    }
    int excl = s[t] - ts + boff[b];
    if (base     < N) { rowptr[base]     = excl;                 wpos[base]     = excl; }
    if (base + 1 < N) { int p = excl + v0;           rowptr[base + 1] = p; wpos[base + 1] = p; }
    if (base + 2 < N) { int p = excl + v0 + v1;      rowptr[base + 2] = p; wpos[base + 2] = p; }
    if (base + 3 < N) { int p = excl + v0 + v1 + v2; rowptr[base + 3] = p; wpos[base + 3] = p; }
}

// scatter + pack per-edge record {src, attr, eval} at CSR position
__global__ void k_scatter(const int* __restrict__ ei, const float* __restrict__ attr,
                          const float* __restrict__ eval_, int* __restrict__ wpos,
                          int4* __restrict__ epack, int E) {
    int e = blockIdx.x * blockDim.x + threadIdx.x;
    if (e >= E) return;
    int d = ei[E + e];
    int p = atomicAdd(&wpos[d], 1);
    int4 rec;
    rec.x = ei[e];
    rec.y = __float_as_int(attr[e]);
    rec.z = __float_as_int(eval_[e]);
    rec.w = 0;
    epack[p] = rec;
}

// ---------------- per-layer node transform ----------------
__global__ void k_qkvs(const float* __restrict__ hn,
                       const float* __restrict__ Wq, const float* __restrict__ bq,
                       const float* __restrict__ Wk, const float* __restrict__ bk,
                       const float* __restrict__ Wv, const float* __restrict__ bv,
                       const float* __restrict__ Ws, const float* __restrict__ bs,
                       float* __restrict__ q, float* __restrict__ k, float* __restrict__ v,
                       float* __restrict__ hnext, int N) {
    __shared__ float sWq[625], sWk[625], sWv[625], sWs[625], sbq[25], sbk[25], sbv[25], sbs[25];
    for (int i = threadIdx.x; i < 625; i += blockDim.x) {
        sWq[i] = Wq[i]; sWk[i] = Wk[i]; sWv[i] = Wv[i]; sWs[i] = Ws[i];
    }
    if (threadIdx.x < 25) {
        sbq[threadIdx.x] = bq[threadIdx.x]; sbk[threadIdx.x] = bk[threadIdx.x];
        sbv[threadIdx.x] = bv[threadIdx.x]; sbs[threadIdx.x] = bs[threadIdx.x];
    }
    __syncthreads();
    int gid = blockIdx.x * blockDim.x + threadIdx.x;
    int n = gid >> 5, j = gid & 31;
    if (n >= N || j >= HID) return;
    float h[25];
    #pragma unroll
    for (int i = 0; i < 25; i++) h[i] = hn[(size_t)n * STR + i];
    float aq = sbq[j], ak = sbk[j], av = sbv[j], as = sbs[j];
    #pragma unroll
    for (int i = 0; i < 25; i++) {
        float hi = h[i];
        aq += hi * sWq[i * 25 + j];
        ak += hi * sWk[i * 25 + j];
        av += hi * sWv[i * 25 + j];
        as += hi * sWs[i * 25 + j];
    }
    size_t o = (size_t)n * STR + j;
    q[o] = aq; k[o] = ak; v[o] = av; hnext[o] = as;
}

// ---------------- fused node-centric attention, 4 lanes/node, packed edges ----------------
__global__ void k_attn_node(const int* __restrict__ rowptr, const int4* __restrict__ epack,
                            const float* __restrict__ q, const float* __restrict__ kk,
                            const float* __restrict__ v,
                            const float* __restrict__ We, const float* __restrict__ be,
                            float* __restrict__ hnext, int N) {
    int gid = blockIdx.x * blockDim.x + threadIdx.x;
    int n = gid >> 2, sub = gid & 3;
    if (n >= N) return;
    const float scale = 0.44721359549995793f;

    float qr[25];
    #pragma unroll
    for (int i = 0; i < 25; i++) qr[i] = q[(size_t)n * STR + i];

    float qW0[5], qW1[5], qbe[5];
    #pragma unroll
    for (int h = 0; h < 5; h++) {
        float a0 = 0.f, a1 = 0.f, ab = 0.f;
        #pragma unroll
        for (int c = 0; c < 5; c++) {
            int i = h * 5 + c;
            a0 += qr[i] * We[i];
            a1 += qr[i] * We[25 + i];
            ab += qr[i] * be[i];
        }
        qW0[h] = a0; qW1[h] = a1; qbe[h] = ab;
    }

    float accV[25];
    #pragma unroll
    for (int i = 0; i < 25; i++) accV[i] = 0.f;
    float den[5] = {0, 0, 0, 0, 0}, sA[5] = {0, 0, 0, 0, 0}, sG[5] = {0, 0, 0, 0, 0};

    int beg = rowptr[n], end = rowptr[n + 1];
    for (int p = beg + sub; p < end; p += 4) {
        int4 ep = epack[p];
        int s = ep.x;
        float a_ = __int_as_float(ep.y), gl = __int_as_float(ep.z);
        const float* kr = kk + (size_t)s * STR;
        const float* vr = v + (size_t)s * STR;
        #pragma unroll
        for (int h = 0; h < 5; h++) {
            float al = qW0[h] * a_ + qW1[h] * gl + qbe[h];
            #pragma unroll
            for (int c = 0; c < 5; c++) { int i = h * 5 + c; al += qr[i] * kr[i]; }
            float ex = __expf(al * scale);
            den[h] += ex;
            sA[h] += ex * a_;
            sG[h] += ex * gl;
            #pragma unroll
            for (int c = 0; c < 5; c++) { int i = h * 5 + c; accV[i] += ex * vr[i]; }
        }
    }

    #pragma unroll
    for (int off = 1; off < 4; off <<= 1) {
        #pragma unroll
        for (int i = 0; i < 25; i++) accV[i] += __shfl_xor(accV[i], off);
        #pragma unroll
        for (int h = 0; h < 5; h++) {
            den[h] += __shfl_xor(den[h], off);
            sA[h] += __shfl_xor(sA[h], off);
            sG[h] += __shfl_xor(sG[h], off);
        }
    }

    if (sub == 0) {
        #pragma unroll
        for (int h = 0; h < 5; h++) {
            float inv = 1.f / (den[h] + 1e-16f);
            #pragma unroll
            for (int c = 0; c < 5; c++) {
                int i = h * 5 + c;
                float agg = (accV[i] + sA[h] * We[i] + sG[h] * We[25 + i] + den[h] * be[i]) * inv;
                hnext[(size_t)n * STR + i] += agg;
            }
        }
    }
}

// ---------------- output ----------------
__global__ void k_out(const float* __restrict__ hn, const float* __restrict__ W,
                      const float* __restrict__ b, float* __restrict__ out, int N) {
    int n = blockIdx.x * blockDim.x + threadIdx.x;
    if (n >= N) return;
    float acc = b[0];
    #pragma unroll
    for (int i = 0; i < 25; i++) acc += hn[(size_t)n * STR + i] * W[i];
    out[n] = 1.f / (1.f + expf(-acc));
}

extern "C" void kernel_launch(void* const* d_in, const int* in_sizes, int n_in,
                              void* d_out, int out_size, void* d_ws, size_t ws_size,
                              hipStream_t stream) {
    const float* x      = (const float*)d_in[0];
    const float* token  = (const float*)d_in[1];
    const float* attr   = (const float*)d_in[2];
    const float* gumbel = (const float*)d_in[3];
    const int*   ei     = (const int*)d_in[4];
    const float* W0 = (const float*)d_in[5];
    const float* b0 = (const float*)d_in[6];
    const float* W1 = (const float*)d_in[7];
    const float* b1 = (const float*)d_in[8];
    const float* W2 = (const float*)d_in[9];
    const float* b2 = (const float*)d_in[10];
    const float* W3 = (const float*)d_in[11];
    const float* b3 = (const float*)d_in[12];
    const float* ilW = (const float*)d_in[13];
    const float* ilb = (const float*)d_in[14];
    const float* Wq = (const float*)d_in[15];
    const float* bq = (const float*)d_in[16];
    const float* Wk = (const float*)d_in[17];
    const float* bk = (const float*)d_in[18];
    const float* Wv = (const float*)d_in[19];
    const float* bv = (const float*)d_in[20];
    const float* We = (const float*)d_in[21];
    const float* be = (const float*)d_in[22];
    const float* Ws = (const float*)d_in[23];
    const float* bs = (const float*)d_in[24];
    const float* oW = (const float*)d_in[25];
    const float* ob = (const float*)d_in[26];

    const int N = in_sizes[0];
    const int E = in_sizes[2];
    const int nb_chunk = (N + CHUNK - 1) / CHUNK;

    char* ws = (char*)d_ws;
    size_t off = 0;
    auto alloc = [&](size_t nb) -> void* {
        void* p = ws + off;
        off += (nb + 255) & ~(size_t)255;
        return p;
    };
    float* hnA    = (float*)alloc((size_t)N * STR * 4);
    float* hnB    = (float*)alloc((size_t)N * STR * 4);
    float* q      = (float*)alloc((size_t)N * STR * 4);
    float* k      = (float*)alloc((size_t)N * STR * 4);
    float* v      = (float*)alloc((size_t)N * STR * 4);
    float* evalv  = (float*)alloc((size_t)E * 4);
    float* xt6    = (float*)alloc((size_t)N * 8 * 4);
    int*   cnt    = (int*)alloc((size_t)N * 4);
    int*   rowptr = (int*)alloc((size_t)(N + 1) * 4);
    int*   wpos   = (int*)alloc((size_t)N * 4);
    int*   bsum   = (int*)alloc((size_t)(nb_chunk + 1) * 4);
    int*   boff   = (int*)alloc((size_t)(nb_chunk + 1) * 4);
    int4*  epack  = (int4*)alloc((size_t)E * 16);
    int*   flcnt  = (int*)alloc(256);
    int*   fllist = (int*)alloc((size_t)E * 4);
    unsigned char* flagv = (unsigned char*)alloc((size_t)E);

    int nb_n32  = (N * STR + 255) / 256;
    int nb_n32b = (N * STR + 511) / 512;
    int nb_e    = (E + 255) / 256;
    int nb_e4   = ((E + 3) / 4 + 255) / 256;
    int nb_n4   = (N * 4 + 255) / 256;
    int nb_n    = (N + 255) / 256;

    const int mlp_blocks = 4096;
    const int mlp_waves  = mlp_blocks * 4;
    const int ntiles     = (E + 15) / 16;

    hipMemsetAsync(cnt, 0, (size_t)N * 4, stream);
    hipMemsetAsync(flcnt, 0, 4, stream);
    k_node_in<<<nb_n32, 256, 0, stream>>>(x, token, ilW, ilb, hnA, xt6, N);
    k_edge_mlp_mfma<<<mlp_blocks, 256, 0, stream>>>(ei, xt6, attr, gumbel,
                                                    W0, b0, W1, b1, W2, b2, W3, b3,
                                                    evalv, flagv, E, ntiles, mlp_waves);
    k_compact<<<nb_e, 256, 0, stream>>>(flagv, flcnt, fllist, E);
    k_edge_fb<<<2048, 256, 0, stream>>>(ei, xt6, attr, gumbel,
                                        W0, b0, W1, b1, W2, b2, W3, b3,
                                        fllist, flcnt, evalv, E, 2048 * 4);
    k_hist<<<nb_e4, 256, 0, stream>>>(ei, cnt, E);
    k_scan_partial<<<nb_chunk, 256, 0, stream>>>(cnt, bsum, N);
    k_scan_top<<<1, 64, 0, stream>>>(bsum, boff, rowptr, nb_chunk, N, E);
    k_scan_final<<<nb_chunk, 256, 0, stream>>>(cnt, boff, rowptr, wpos, N);
    k_scatter<<<nb_e, 256, 0, stream>>>(ei, attr, evalv, wpos, epack, E);

    float* cur = hnA;
    float* nxt = hnB;
    for (int l = 0; l < 3; l++) {
        k_qkvs<<<nb_n32b, 512, 0, stream>>>(cur, Wq + l * 625, bq + l * 25,
                                            Wk + l * 625, bk + l * 25,
                                            Wv + l * 625, bv + l * 25,
                                            Ws + l * 625, bs + l * 25,
                                            q, k, v, nxt, N);
        k_attn_node<<<nb_n4, 256, 0, stream>>>(rowptr, epack, q, k, v,
                                               We + l * 50, be + l * 25, nxt, N);
        float* t = cur; cur = nxt; nxt = t;
    }
    k_out<<<nb_n, 256, 0, stream>>>(cur, oW, ob, (float*)d_out, N);
}

// Round 13
// 1621.960 us; speedup vs baseline: 2.3073x; 1.3336x over previous
//
#include <hip/hip_runtime.h>
#include <math.h>

#define HID 25
#define STR 32   // padded node-feature row stride (128B rows)
#define CHUNK 1024
#define FBTHR 0.1f
#define RST 72   // LDS activation row stride in bf16 (144B; conflict-managed)
#define CEPT 32  // edges per thread in k_compact (8192/block)

typedef __attribute__((ext_vector_type(8))) short short8;
typedef __attribute__((ext_vector_type(4))) float f32x4;

__device__ __forceinline__ float gelu_f(float x) {
    return 0.5f * x * (1.0f + erff(x * 0.70710678118654752f));
}

// Branchless gelu: A&S 7.1.26 erf approx, |err| <= 1.5e-7 (<< FBTHR; gate-safe,
// fallback recomputes with true erff).
__device__ __forceinline__ float gelu_fast(float x) {
    float y = fabsf(x) * 0.70710678118654752f;
    float t = __builtin_amdgcn_rcpf(fmaf(0.3275911f, y, 1.0f));
    float p = fmaf(1.061405429f, t, -1.453152027f);
    p = fmaf(p, t, 1.421413741f);
    p = fmaf(p, t, -0.284496736f);
    p = fmaf(p, t, 0.254829592f);
    p = p * t;
    float e = __expf(-y * y);
    float erfv = fmaf(-p, e, 1.0f);
    float r = copysignf(erfv, x);
    return 0.5f * x * (1.0f + r);
}

__device__ __forceinline__ short f2bf(float f) {
    unsigned u = __float_as_uint(f);
    u = (u + 0x7fffu + ((u >> 16) & 1u)) >> 16;
    return (short)u;
}

// gather 4 consecutive MLP-input slots (k = grp*4 .. grp*4+3) for edge e
__device__ __forceinline__ void gather4(int e, int E, const int* __restrict__ ei,
                                        const float* __restrict__ xt6,
                                        const float* __restrict__ attr, int grp,
                                        float& v0, float& v1, float& v2, float& v3) {
    v0 = v1 = v2 = v3 = 0.f;
    if (e < E) {
        if (grp == 0) {
            const float4 f = *(const float4*)&xt6[(size_t)ei[e] * 8];
            v0 = f.x; v1 = f.y; v2 = f.z; v3 = f.w;
        } else if (grp == 1) {
            int s = ei[e], d = ei[E + e];
            const float2 lo = *(const float2*)&xt6[(size_t)s * 8 + 4];
            const float2 hi = *(const float2*)&xt6[(size_t)d * 8];
            v0 = lo.x; v1 = lo.y; v2 = hi.x; v3 = hi.y;
        } else if (grp == 2) {
            int d = ei[E + e];
            const float2 lo = *(const float2*)&xt6[(size_t)d * 8 + 2];
            const float2 hi = *(const float2*)&xt6[(size_t)d * 8 + 4];
            v0 = lo.x; v1 = lo.y; v2 = hi.x; v3 = hi.y;
        } else {
            v0 = attr[e];
        }
    }
}

// ---------------- node input linear + packed xt6 ----------------
__global__ void k_node_in(const float* __restrict__ x, const float* __restrict__ token,
                          const float* __restrict__ W, const float* __restrict__ b,
                          float* __restrict__ hn, float* __restrict__ xt6, int N) {
    int gid = blockIdx.x * blockDim.x + threadIdx.x;
    int n = gid >> 5, j = gid & 31;
    if (n >= N) return;
    if (j < 8) xt6[(size_t)n * 8 + j] = (j == 0) ? x[n] : ((j < 6) ? token[n * 5 + j - 1] : 0.f);
    if (j >= HID) return;
    float acc = b[j];
    acc += x[n] * W[j];
    #pragma unroll
    for (int i = 0; i < 5; i++) acc += token[n * 5 + i] * W[(i + 1) * HID + j];
    hn[(size_t)n * STR + j] = acc;
}

// ---------------- edge MLP via MFMA (bf16), col'-layout LDS ----------------
__global__ __launch_bounds__(256) void k_edge_mlp_mfma(
    const int* __restrict__ ei, const float* __restrict__ xt6,
    const float* __restrict__ attr, const float* __restrict__ gumbel,
    const float* __restrict__ W0, const float* __restrict__ b0,
    const float* __restrict__ W1, const float* __restrict__ b1,
    const float* __restrict__ W2, const float* __restrict__ b2,
    const float* __restrict__ W3, const float* __restrict__ b3,
    float* __restrict__ eval_, unsigned char* __restrict__ flagv,
    int E, int ntiles, int nwaves) {
    __shared__ short hbuf[4][16 * RST];
    const int lane = threadIdx.x & 63;
    const int wv = threadIdx.x >> 6;
    const int wid = blockIdx.x * 4 + wv;
    const int grp = lane >> 4, r2 = lane & 15;

    short8 w0f[4], w1f[2][4], w2f[2][4];
    #pragma unroll
    for (int nt = 0; nt < 4; nt++) {
        int col = r2 + 16 * nt;
        #pragma unroll
        for (int j = 0; j < 8; j++) {
            int k = grp * 4 + (j & 3) + 16 * (j >> 2);
            w0f[nt][j] = (k < 13 && col < 50) ? f2bf(W0[k * 50 + col]) : (short)0;
        }
    }
    #pragma unroll
    for (int kt = 0; kt < 2; kt++) {
        #pragma unroll
        for (int nt = 0; nt < 4; nt++) {
            int col = r2 + 16 * nt;
            #pragma unroll
            for (int j = 0; j < 8; j++) {
                int cW = (j & 3) * 16 + kt * 8 + grp * 2 + (j >> 2);
                w1f[kt][nt][j] = (cW < 50 && col < 50) ? f2bf(W1[cW * 50 + col]) : (short)0;
                w2f[kt][nt][j] = (cW < 50 && col < 50) ? f2bf(W2[cW * 50 + col]) : (short)0;
            }
        }
    }
    float b0v[4], b1v[4], b2v[4], w3dv[4];
    #pragma unroll
    for (int nt = 0; nt < 4; nt++) {
        int col = r2 + 16 * nt;
        b0v[nt] = (col < 50) ? b0[col] : 0.f;
        b1v[nt] = (col < 50) ? b1[col] : 0.f;
        b2v[nt] = (col < 50) ? b2[col] : 0.f;
        w3dv[nt] = (col < 50) ? (W3[col * 2 + 1] - W3[col * 2]) : 0.f;
    }
    const float b3d = b3[1] - b3[0];
    const f32x4 z4 = {0.f, 0.f, 0.f, 0.f};
    short* hb = &hbuf[wv][0];

    for (int t = wid; t < ntiles; t += nwaves) {
        const int base = t * 16;
        float g0, g1, g2, g3;
        gather4(base + r2, E, ei, xt6, attr, grp, g0, g1, g2, g3);
        short8 a0 = {f2bf(g0), f2bf(g1), f2bf(g2), f2bf(g3), 0, 0, 0, 0};

        // ---- layer 0 ----
        f32x4 c0 = __builtin_amdgcn_mfma_f32_16x16x32_bf16(a0, w0f[0], z4, 0, 0, 0);
        f32x4 c1 = __builtin_amdgcn_mfma_f32_16x16x32_bf16(a0, w0f[1], z4, 0, 0, 0);
        f32x4 c2 = __builtin_amdgcn_mfma_f32_16x16x32_bf16(a0, w0f[2], z4, 0, 0, 0);
        f32x4 c3 = __builtin_amdgcn_mfma_f32_16x16x32_bf16(a0, w0f[3], z4, 0, 0, 0);
        #pragma unroll
        for (int i = 0; i < 4; i++) {
            int row = grp * 4 + i;
            float v0 = gelu_fast(c0[i] + b0v[0]);
            float v1 = gelu_fast(c1[i] + b0v[1]);
            float v2 = gelu_fast(c2[i] + b0v[2]);
            float v3 = gelu_fast(c3[i] + b0v[3]);
            unsigned lo, hi;
            asm("v_cvt_pk_bf16_f32 %0, %1, %2" : "=v"(lo) : "v"(v0), "v"(v1));
            asm("v_cvt_pk_bf16_f32 %0, %1, %2" : "=v"(hi) : "v"(v2), "v"(v3));
            *(int2*)&hb[row * RST + r2 * 4] = make_int2((int)lo, (int)hi);
        }

        // ---- layer 1 ----
        {
            short8 k0 = *(const short8*)&hb[r2 * RST + 0 * 32 + grp * 8];
            short8 k1 = *(const short8*)&hb[r2 * RST + 1 * 32 + grp * 8];
            c0 = __builtin_amdgcn_mfma_f32_16x16x32_bf16(k1, w1f[1][0],
                 __builtin_amdgcn_mfma_f32_16x16x32_bf16(k0, w1f[0][0], z4, 0, 0, 0), 0, 0, 0);
            c1 = __builtin_amdgcn_mfma_f32_16x16x32_bf16(k1, w1f[1][1],
                 __builtin_amdgcn_mfma_f32_16x16x32_bf16(k0, w1f[0][1], z4, 0, 0, 0), 0, 0, 0);
            c2 = __builtin_amdgcn_mfma_f32_16x16x32_bf16(k1, w1f[1][2],
                 __builtin_amdgcn_mfma_f32_16x16x32_bf16(k0, w1f[0][2], z4, 0, 0, 0), 0, 0, 0);
            c3 = __builtin_amdgcn_mfma_f32_16x16x32_bf16(k1, w1f[1][3],
                 __builtin_amdgcn_mfma_f32_16x16x32_bf16(k0, w1f[0][3], z4, 0, 0, 0), 0, 0, 0);
        }
        #pragma unroll
        for (int i = 0; i < 4; i++) {
            int row = grp * 4 + i;
            float v0 = gelu_fast(c0[i] + b1v[0]);
            float v1 = gelu_fast(c1[i] + b1v[1]);
            float v2 = gelu_fast(c2[i] + b1v[2]);
            float v3 = gelu_fast(c3[i] + b1v[3]);
            unsigned lo, hi;
            asm("v_cvt_pk_bf16_f32 %0, %1, %2" : "=v"(lo) : "v"(v0), "v"(v1));
            asm("v_cvt_pk_bf16_f32 %0, %1, %2" : "=v"(hi) : "v"(v2), "v"(v3));
            *(int2*)&hb[row * RST + r2 * 4] = make_int2((int)lo, (int)hi);
        }

        // ---- layer 2 ----
        {
            short8 k0 = *(const short8*)&hb[r2 * RST + 0 * 32 + grp * 8];
            short8 k1 = *(const short8*)&hb[r2 * RST + 1 * 32 + grp * 8];
            c0 = __builtin_amdgcn_mfma_f32_16x16x32_bf16(k1, w2f[1][0],
                 __builtin_amdgcn_mfma_f32_16x16x32_bf16(k0, w2f[0][0], z4, 0, 0, 0), 0, 0, 0);
            c1 = __builtin_amdgcn_mfma_f32_16x16x32_bf16(k1, w2f[1][1],
                 __builtin_amdgcn_mfma_f32_16x16x32_bf16(k0, w2f[0][1], z4, 0, 0, 0), 0, 0, 0);
            c2 = __builtin_amdgcn_mfma_f32_16x16x32_bf16(k1, w2f[1][2],
                 __builtin_amdgcn_mfma_f32_16x16x32_bf16(k0, w2f[0][2], z4, 0, 0, 0), 0, 0, 0);
            c3 = __builtin_amdgcn_mfma_f32_16x16x32_bf16(k1, w2f[1][3],
                 __builtin_amdgcn_mfma_f32_16x16x32_bf16(k0, w2f[0][3], z4, 0, 0, 0), 0, 0, 0);
        }

        float z0 = 0.f, z1 = 0.f, z2 = 0.f, z3 = 0.f;
        #pragma unroll
        for (int i = 0; i < 4; i++) {
            float h0 = gelu_fast(c0[i] + b2v[0]), h1 = gelu_fast(c1[i] + b2v[1]);
            float h2 = gelu_fast(c2[i] + b2v[2]), h3 = gelu_fast(c3[i] + b2v[3]);
            float z = h0 * w3dv[0] + h1 * w3dv[1] + h2 * w3dv[2] + h3 * w3dv[3];
            if (i == 0) z0 = z; else if (i == 1) z1 = z; else if (i == 2) z2 = z; else z3 = z;
        }
        #pragma unroll
        for (int off = 1; off < 16; off <<= 1) {
            z0 += __shfl_xor(z0, off); z1 += __shfl_xor(z1, off);
            z2 += __shfl_xor(z2, off); z3 += __shfl_xor(z3, off);
        }
        if (r2 < 4) {
            int e2 = base + grp * 4 + r2;
            if (e2 < E) {
                float zsel = (r2 == 0) ? z0 : (r2 == 1) ? z1 : (r2 == 2) ? z2 : z3;
                float g0v = gumbel[2 * (long long)e2], g1v = gumbel[2 * (long long)e2 + 1];
                float m = zsel + b3d + g1v - g0v;
                eval_[e2] = (m > 0.f) ? 1.f : 0.f;
                flagv[e2] = (fabsf(m) < FBTHR) ? 1 : 0;
            }
        }
    }
}

// ---------------- block-aggregated flag -> list compaction (1 atomic / 8192 edges) ----------------
__global__ __launch_bounds__(256) void k_compact(const unsigned char* __restrict__ flagv,
                                                 int* __restrict__ flcnt,
                                                 int* __restrict__ fllist, int E) {
    __shared__ int s[256];
    __shared__ int sbase;
    const int t = threadIdx.x;
    const long long base = (long long)blockIdx.x * (256 * CEPT) + (long long)t * CEPT;

    unsigned char fl[CEPT];
    #pragma unroll
    for (int u = 0; u < CEPT; u += 16) {
        int4 w = make_int4(0, 0, 0, 0);
        if (base + u + 15 < (long long)E) {
            w = *(const int4*)&flagv[base + u];
        } else {
            #pragma unroll
            for (int b2 = 0; b2 < 16; b2++) {
                long long idx = base + u + b2;
                ((unsigned char*)&w)[b2] = (idx < (long long)E) ? flagv[idx] : 0;
            }
        }
        *(int4*)&fl[u] = w;
    }
    int cnt = 0;
    #pragma unroll
    for (int u = 0; u < CEPT; u++) cnt += fl[u];

    s[t] = cnt;
    __syncthreads();
    for (int off = 1; off < 256; off <<= 1) {
        int xv = (t >= off) ? s[t - off] : 0;
        __syncthreads();
        s[t] += xv;
        __syncthreads();
    }
    if (t == 255) sbase = (s[255] > 0) ? atomicAdd(flcnt, s[255]) : 0;
    __syncthreads();

    int pos = sbase + s[t] - cnt;
    #pragma unroll
    for (int u = 0; u < CEPT; u++) {
        if (fl[u]) fllist[pos++] = (int)(base + u);
    }
}

// ---------------- wave-cooperative exact-fp32 fallback ----------------
__global__ __launch_bounds__(256) void k_edge_fb(
    const int* __restrict__ ei, const float* __restrict__ xt6,
    const float* __restrict__ attr, const float* __restrict__ gumbel,
    const float* __restrict__ W0, const float* __restrict__ b0,
    const float* __restrict__ W1, const float* __restrict__ b1,
    const float* __restrict__ W2, const float* __restrict__ b2,
    const float* __restrict__ W3, const float* __restrict__ b3,
    const int* __restrict__ fllist, const int* __restrict__ flcnt,
    float* __restrict__ eval_, int E, int nwaves) {
    __shared__ float buf[4][2][2][64];
    const int lane = threadIdx.x & 63;
    const int wv = threadIdx.x >> 6;
    const int wid = blockIdx.x * 4 + wv;
    const int jw = (lane < 50) ? lane : 49;

    float w0r[16], w1r[52], w2r[52];
    #pragma unroll
    for (int k = 0; k < 13; k++) w0r[k] = W0[k * 50 + jw];
    w0r[13] = 0.f; w0r[14] = 0.f; w0r[15] = 0.f;
    #pragma unroll
    for (int k = 0; k < 50; k++) w1r[k] = W1[k * 50 + jw];
    w1r[50] = 0.f; w1r[51] = 0.f;
    #pragma unroll
    for (int k = 0; k < 50; k++) w2r[k] = W2[k * 50 + jw];
    w2r[50] = 0.f; w2r[51] = 0.f;
    const float b0r = b0[jw], b1r = b1[jw], b2r = b2[jw];
    const float b3_0 = b3[0], b3_1 = b3[1];
    const float w3d = (lane < 50) ? (W3[lane * 2 + 1] - W3[lane * 2]) : 0.f;

    const int g = lane >> 4, r = lane & 15;
    const int cnt = *flcnt;

    for (int base = wid * 2; base < cnt; base += nwaves * 2) {
        if (g < 2) {
            int idx = base + g;
            float val = 0.f;
            if (idx < cnt && r < 13) {
                int e = fllist[idx];
                if (r == 12) val = attr[e];
                else if (r < 6) val = xt6[(size_t)ei[e] * 8 + r];
                else val = xt6[(size_t)ei[E + e] * 8 + (r - 6)];
            }
            buf[wv][0][g][r] = val;
        }

        const float4* a4 = (const float4*)(&buf[wv][0][0][0]);
        const float4* c4 = (const float4*)(&buf[wv][0][1][0]);
        float tA = b0r, tB = b0r;
        #pragma unroll
        for (int c = 0; c < 4; c++) {
            float4 a = a4[c], b = c4[c];
            tA += a.x * w0r[4 * c];     tB += b.x * w0r[4 * c];
            tA += a.y * w0r[4 * c + 1]; tB += b.y * w0r[4 * c + 1];
            tA += a.z * w0r[4 * c + 2]; tB += b.z * w0r[4 * c + 2];
            tA += a.w * w0r[4 * c + 3]; tB += b.w * w0r[4 * c + 3];
        }
        buf[wv][1][0][lane] = gelu_f(tA);
        buf[wv][1][1][lane] = gelu_f(tB);

        const float4* p4 = (const float4*)(&buf[wv][1][0][0]);
        const float4* q4 = (const float4*)(&buf[wv][1][1][0]);
        tA = b1r; tB = b1r;
        #pragma unroll
        for (int c = 0; c < 13; c++) {
            float4 a = p4[c], b = q4[c];
            tA += a.x * w1r[4 * c];     tB += b.x * w1r[4 * c];
            tA += a.y * w1r[4 * c + 1]; tB += b.y * w1r[4 * c + 1];
            tA += a.z * w1r[4 * c + 2]; tB += b.z * w1r[4 * c + 2];
            tA += a.w * w1r[4 * c + 3]; tB += b.w * w1r[4 * c + 3];
        }
        buf[wv][0][0][lane] = gelu_f(tA);
        buf[wv][0][1][lane] = gelu_f(tB);

        tA = b2r; tB = b2r;
        #pragma unroll
        for (int c = 0; c < 13; c++) {
            float4 a = a4[c], b = c4[c];
            tA += a.x * w2r[4 * c];     tB += b.x * w2r[4 * c];
            tA += a.y * w2r[4 * c + 1]; tB += b.y * w2r[4 * c + 1];
            tA += a.z * w2r[4 * c + 2]; tB += b.z * w2r[4 * c + 2];
            tA += a.w * w2r[4 * c + 3]; tB += b.w * w2r[4 * c + 3];
        }
        float h3A = gelu_f(tA), h3B = gelu_f(tB);
        buf[wv][1][0][lane] = h3A;
        buf[wv][1][1][lane] = h3B;

        float zA = h3A * w3d, zB = h3B * w3d;
        #pragma unroll
        for (int off = 32; off > 0; off >>= 1) {
            zA += __shfl_xor(zA, off);
            zB += __shfl_xor(zB, off);
        }

        if (lane < 2) {
            int idx = base + lane;
            if (idx < cnt) {
                int e = fllist[idx];
                float z = (lane == 0) ? zA : zB;
                float g0v = gumbel[2 * (long long)e], g1v = gumbel[2 * (long long)e + 1];
                float m = z + (b3_1 - b3_0) + g1v - g0v;
                float dec;
                if (fabsf(m) < 1e-4f) {
                    float z0 = 0.f, z1 = 0.f;
                    for (int j = 0; j < 50; j++) {
                        float h = buf[wv][1][lane][j];
                        z0 += h * W3[2 * j];
                        z1 += h * W3[2 * j + 1];
                    }
                    z0 += b3_0; z1 += b3_1;
                    dec = (z1 + g1v > z0 + g0v) ? 1.f : 0.f;
                } else {
                    dec = (m > 0.f) ? 1.f : 0.f;
                }
                eval_[e] = dec;
            }
        }
    }
}

// ---------------- CSR build: histogram (x4) + scan + scatter(+pack) ----------------
__global__ void k_hist(const int* __restrict__ ei, int* __restrict__ cnt, int E) {
    int i = blockIdx.x * blockDim.x + threadIdx.x;
    int e = i * 4;
    if (e + 3 < E) {
        int4 d = *(const int4*)&ei[E + e];
        atomicAdd(&cnt[d.x], 1); atomicAdd(&cnt[d.y], 1);
        atomicAdd(&cnt[d.z], 1); atomicAdd(&cnt[d.w], 1);
    } else {
        for (int u = e; u < E; u++) atomicAdd(&cnt[ei[E + u]], 1);
    }
}

__global__ void k_scan_partial(const int* __restrict__ cnt, int* __restrict__ bsum, int N) {
    __shared__ int s[256];
    int b = blockIdx.x, t = threadIdx.x;
    int base = b * CHUNK + t * 4;
    int sum = 0;
    #pragma unroll
    for (int u = 0; u < 4; u++) { int idx = base + u; if (idx < N) sum += cnt[idx]; }
    s[t] = sum; __syncthreads();
    for (int off = 128; off > 0; off >>= 1) {
        if (t < off) s[t] += s[t + off];
        __syncthreads();
    }
    if (t == 0) bsum[b] = s[0];
}

__global__ void k_scan_top(const int* __restrict__ bsum, int* __restrict__ boff,
                           int* __restrict__ rowptr, int nb, int N, int E) {
    if (threadIdx.x == 0 && blockIdx.x == 0) {
        int run = 0;
        for (int i = 0; i < nb; i++) { boff[i] = run; run += bsum[i]; }
        rowptr[N] = E;
    }
}

__global__ void k_scan_final(const int* __restrict__ cnt, const int* __restrict__ boff,
                             int* __restrict__ rowptr, int* __restrict__ wpos, int N) {
    __shared__ int s[256];
    int b = blockIdx.x, t = threadIdx.x;
    int base = b * CHUNK + t * 4;
    int v0 = 0, v1 = 0, v2 = 0, v3 = 0;
    if (base     < N) v0 = cnt[base];
    if (base + 1 < N) v1 = cnt[base + 1];
    if (base + 2 < N) v2 = cnt[base + 2];
    if (base + 3 < N) v3 = cnt[base + 3];
    int ts = v0 + v1 + v2 + v3;
    s[t] = ts; __syncthreads();
    for (int off = 1; off < 256; off <<= 1) {
        int xv = (t >= off) ? s[t - off] : 0;
        __syncthreads();
        s[t] += xv;
        __syncthreads();
    }
    int excl = s[t] - ts + boff[b];
    if (base     < N) { rowptr[base]     = excl;                 wpos[base]     = excl; }
    if (base + 1 < N) { int p = excl + v0;           rowptr[base + 1] = p; wpos[base + 1] = p; }
    if (base + 2 < N) { int p = excl + v0 + v1;      rowptr[base + 2] = p; wpos[base + 2] = p; }
    if (base + 3 < N) { int p = excl + v0 + v1 + v2; rowptr[base + 3] = p; wpos[base + 3] = p; }
}

// scatter + pack per-edge record {src, attr, eval} at CSR position
__global__ void k_scatter(const int* __restrict__ ei, const float* __restrict__ attr,
                          const float* __restrict__ eval_, int* __restrict__ wpos,
                          int4* __restrict__ epack, int E) {
    int e = blockIdx.x * blockDim.x + threadIdx.x;
    if (e >= E) return;
    int d = ei[E + e];
    int p = atomicAdd(&wpos[d], 1);
    int4 rec;
    rec.x = ei[e];
    rec.y = __float_as_int(attr[e]);
    rec.z = __float_as_int(eval_[e]);
    rec.w = 0;
    epack[p] = rec;
}

// ---------------- per-layer node transform ----------------
__global__ void k_qkvs(const float* __restrict__ hn,
                       const float* __restrict__ Wq, const float* __restrict__ bq,
                       const float* __restrict__ Wk, const float* __restrict__ bk,
                       const float* __restrict__ Wv, const float* __restrict__ bv,
                       const float* __restrict__ Ws, const float* __restrict__ bs,
                       float* __restrict__ q, float* __restrict__ k, float* __restrict__ v,
                       float* __restrict__ hnext, int N) {
    __shared__ float sWq[625], sWk[625], sWv[625], sWs[625], sbq[25], sbk[25], sbv[25], sbs[25];
    for (int i = threadIdx.x; i < 625; i += blockDim.x) {
        sWq[i] = Wq[i]; sWk[i] = Wk[i]; sWv[i] = Wv[i]; sWs[i] = Ws[i];
    }
    if (threadIdx.x < 25) {
        sbq[threadIdx.x] = bq[threadIdx.x]; sbk[threadIdx.x] = bk[threadIdx.x];
        sbv[threadIdx.x] = bv[threadIdx.x]; sbs[threadIdx.x] = bs[threadIdx.x];
    }
    __syncthreads();
    int gid = blockIdx.x * blockDim.x + threadIdx.x;
    int n = gid >> 5, j = gid & 31;
    if (n >= N || j >= HID) return;
    float h[25];
    #pragma unroll
    for (int i = 0; i < 25; i++) h[i] = hn[(size_t)n * STR + i];
    float aq = sbq[j], ak = sbk[j], av = sbv[j], as = sbs[j];
    #pragma unroll
    for (int i = 0; i < 25; i++) {
        float hi = h[i];
        aq += hi * sWq[i * 25 + j];
        ak += hi * sWk[i * 25 + j];
        av += hi * sWv[i * 25 + j];
        as += hi * sWs[i * 25 + j];
    }
    size_t o = (size_t)n * STR + j;
    q[o] = aq; k[o] = ak; v[o] = av; hnext[o] = as;
}

// ---------------- fused node-centric attention, 4 lanes/node, packed edges ----------------
__global__ void k_attn_node(const int* __restrict__ rowptr, const int4* __restrict__ epack,
                            const float* __restrict__ q, const float* __restrict__ kk,
                            const float* __restrict__ v,
                            const float* __restrict__ We, const float* __restrict__ be,
                            float* __restrict__ hnext, int N) {
    int gid = blockIdx.x * blockDim.x + threadIdx.x;
    int n = gid >> 2, sub = gid & 3;
    if (n >= N) return;
    const float scale = 0.44721359549995793f;

    float qr[25];
    #pragma unroll
    for (int i = 0; i < 25; i++) qr[i] = q[(size_t)n * STR + i];

    float qW0[5], qW1[5], qbe[5];
    #pragma unroll
    for (int h = 0; h < 5; h++) {
        float a0 = 0.f, a1 = 0.f, ab = 0.f;
        #pragma unroll
        for (int c = 0; c < 5; c++) {
            int i = h * 5 + c;
            a0 += qr[i] * We[i];
            a1 += qr[i] * We[25 + i];
            ab += qr[i] * be[i];
        }
        qW0[h] = a0; qW1[h] = a1; qbe[h] = ab;
    }

    float accV[25];
    #pragma unroll
    for (int i = 0; i < 25; i++) accV[i] = 0.f;
    float den[5] = {0, 0, 0, 0, 0}, sA[5] = {0, 0, 0, 0, 0}, sG[5] = {0, 0, 0, 0, 0};

    int beg = rowptr[n], end = rowptr[n + 1];
    for (int p = beg + sub; p < end; p += 4) {
        int4 ep = epack[p];
        int s = ep.x;
        float a_ = __int_as_float(ep.y), gl = __int_as_float(ep.z);
        const float* kr = kk + (size_t)s * STR;
        const float* vr = v + (size_t)s * STR;
        #pragma unroll
        for (int h = 0; h < 5; h++) {
            float al = qW0[h] * a_ + qW1[h] * gl + qbe[h];
            #pragma unroll
            for (int c = 0; c < 5; c++) { int i = h * 5 + c; al += qr[i] * kr[i]; }
            float ex = __expf(al * scale);
            den[h] += ex;
            sA[h] += ex * a_;
            sG[h] += ex * gl;
            #pragma unroll
            for (int c = 0; c < 5; c++) { int i = h * 5 + c; accV[i] += ex * vr[i]; }
        }
    }

    #pragma unroll
    for (int off = 1; off < 4; off <<= 1) {
        #pragma unroll
        for (int i = 0; i < 25; i++) accV[i] += __shfl_xor(accV[i], off);
        #pragma unroll
        for (int h = 0; h < 5; h++) {
            den[h] += __shfl_xor(den[h], off);
            sA[h] += __shfl_xor(sA[h], off);
            sG[h] += __shfl_xor(sG[h], off);
        }
    }

    if (sub == 0) {
        #pragma unroll
        for (int h = 0; h < 5; h++) {
            float inv = 1.f / (den[h] + 1e-16f);
            #pragma unroll
            for (int c = 0; c < 5; c++) {
                int i = h * 5 + c;
                float agg = (accV[i] + sA[h] * We[i] + sG[h] * We[25 + i] + den[h] * be[i]) * inv;
                hnext[(size_t)n * STR + i] += agg;
            }
        }
    }
}

// ---------------- output ----------------
__global__ void k_out(const float* __restrict__ hn, const float* __restrict__ W,
                      const float* __restrict__ b, float* __restrict__ out, int N) {
    int n = blockIdx.x * blockDim.x + threadIdx.x;
    if (n >= N) return;
    float acc = b[0];
    #pragma unroll
    for (int i = 0; i < 25; i++) acc += hn[(size_t)n * STR + i] * W[i];
    out[n] = 1.f / (1.f + expf(-acc));
}

extern "C" void kernel_launch(void* const* d_in, const int* in_sizes, int n_in,
                              void* d_out, int out_size, void* d_ws, size_t ws_size,
                              hipStream_t stream) {
    const float* x      = (const float*)d_in[0];
    const float* token  = (const float*)d_in[1];
    const float* attr   = (const float*)d_in[2];
    const float* gumbel = (const float*)d_in[3];
    const int*   ei     = (const int*)d_in[4];
    const float* W0 = (const float*)d_in[5];
    const float* b0 = (const float*)d_in[6];
    const float* W1 = (const float*)d_in[7];
    const float* b1 = (const float*)d_in[8];
    const float* W2 = (const float*)d_in[9];
    const float* b2 = (const float*)d_in[10];
    const float* W3 = (const float*)d_in[11];
    const float* b3 = (const float*)d_in[12];
    const float* ilW = (const float*)d_in[13];
    const float* ilb = (const float*)d_in[14];
    const float* Wq = (const float*)d_in[15];
    const float* bq = (const float*)d_in[16];
    const float* Wk = (const float*)d_in[17];
    const float* bk = (const float*)d_in[18];
    const float* Wv = (const float*)d_in[19];
    const float* bv = (const float*)d_in[20];
    const float* We = (const float*)d_in[21];
    const float* be = (const float*)d_in[22];
    const float* Ws = (const float*)d_in[23];
    const float* bs = (const float*)d_in[24];
    const float* oW = (const float*)d_in[25];
    const float* ob = (const float*)d_in[26];

    const int N = in_sizes[0];
    const int E = in_sizes[2];
    const int nb_chunk = (N + CHUNK - 1) / CHUNK;

    char* ws = (char*)d_ws;
    size_t off = 0;
    auto alloc = [&](size_t nb) -> void* {
        void* p = ws + off;
        off += (nb + 255) & ~(size_t)255;
        return p;
    };
    float* hnA    = (float*)alloc((size_t)N * STR * 4);
    float* hnB    = (float*)alloc((size_t)N * STR * 4);
    float* q      = (float*)alloc((size_t)N * STR * 4);
    float* k      = (float*)alloc((size_t)N * STR * 4);
    float* v      = (float*)alloc((size_t)N * STR * 4);
    float* evalv  = (float*)alloc((size_t)E * 4);
    float* xt6    = (float*)alloc((size_t)N * 8 * 4);
    int*   cnt    = (int*)alloc((size_t)N * 4);
    int*   rowptr = (int*)alloc((size_t)(N + 1) * 4);
    int*   wpos   = (int*)alloc((size_t)N * 4);
    int*   bsum   = (int*)alloc((size_t)(nb_chunk + 1) * 4);
    int*   boff   = (int*)alloc((size_t)(nb_chunk + 1) * 4);
    int4*  epack  = (int4*)alloc((size_t)E * 16);
    int*   flcnt  = (int*)alloc(256);
    int*   fllist = (int*)alloc((size_t)E * 4);
    unsigned char* flagv = (unsigned char*)alloc((size_t)E);

    int nb_n32  = (N * STR + 255) / 256;
    int nb_n32b = (N * STR + 511) / 512;
    int nb_e    = (E + 255) / 256;
    int nb_e4   = ((E + 3) / 4 + 255) / 256;
    int nb_n4   = (N * 4 + 255) / 256;
    int nb_n    = (N + 255) / 256;
    int nb_cmp  = (E + 256 * CEPT - 1) / (256 * CEPT);

    const int mlp_blocks = 4096;
    const int mlp_waves  = mlp_blocks * 4;
    const int ntiles     = (E + 15) / 16;

    hipMemsetAsync(cnt, 0, (size_t)N * 4, stream);
    hipMemsetAsync(flcnt, 0, 4, stream);
    k_node_in<<<nb_n32, 256, 0, stream>>>(x, token, ilW, ilb, hnA, xt6, N);
    k_edge_mlp_mfma<<<mlp_blocks, 256, 0, stream>>>(ei, xt6, attr, gumbel,
                                                    W0, b0, W1, b1, W2, b2, W3, b3,
                                                    evalv, flagv, E, ntiles, mlp_waves);
    k_compact<<<nb_cmp, 256, 0, stream>>>(flagv, flcnt, fllist, E);
    k_edge_fb<<<2048, 256, 0, stream>>>(ei, xt6, attr, gumbel,
                                        W0, b0, W1, b1, W2, b2, W3, b3,
                                        fllist, flcnt, evalv, E, 2048 * 4);
    k_hist<<<nb_e4, 256, 0, stream>>>(ei, cnt, E);
    k_scan_partial<<<nb_chunk, 256, 0, stream>>>(cnt, bsum, N);
    k_scan_top<<<1, 64, 0, stream>>>(bsum, boff, rowptr, nb_chunk, N, E);
    k_scan_final<<<nb_chunk, 256, 0, stream>>>(cnt, boff, rowptr, wpos, N);
    k_scatter<<<nb_e, 256, 0, stream>>>(ei, attr, evalv, wpos, epack, E);

    float* cur = hnA;
    float* nxt = hnB;
    for (int l = 0; l < 3; l++) {
        k_qkvs<<<nb_n32b, 512, 0, stream>>>(cur, Wq + l * 625, bq + l * 25,
                                            Wk + l * 625, bk + l * 25,
                                            Wv + l * 625, bv + l * 25,
                                            Ws + l * 625, bs + l * 25,
                                            q, k, v, nxt, N);
        k_attn_node<<<nb_n4, 256, 0, stream>>>(rowptr, epack, q, k, v,
                                               We + l * 50, be + l * 25, nxt, N);
        float* t = cur; cur = nxt; nxt = t;
    }
    k_out<<<nb_n, 256, 0, stream>>>(cur, oW, ob, (float*)d_out, N);
}

// Round 14
// 1196.419 us; speedup vs baseline: 3.1279x; 1.3557x over previous
//
#include <hip/hip_runtime.h>
#include <math.h>

#define HID 25
#define STR 32   // padded node-feature row stride (128B rows)
#define CHUNK 1024
#define FBTHR 0.1f
#define RST 72   // LDS activation row stride in bf16 (144B; conflict-managed)
#define CEPT 32  // edges per thread in k_compact (8192/block)

typedef __attribute__((ext_vector_type(8))) short short8;
typedef __attribute__((ext_vector_type(4))) float f32x4;

__device__ __forceinline__ float gelu_f(float x) {
    return 0.5f * x * (1.0f + erff(x * 0.70710678118654752f));
}

// tanh-form gelu, 7 VALU ops: x*(1 - 1/(2^(x*(2.3022+0.1029*x^2)) + 1)).
// Constants fold sqrt(2/pi), 0.044715, and 2*log2(e). Max err ~1e-3 per
// activation -> z-margin err ~5e-3 << FBTHR; exact-erf fallback decides gates.
__device__ __forceinline__ float gelu_fast(float x) {
    float x2 = x * x;
    float c = fmaf(0.1029461f, x2, 2.3022077f);
    float m = x * c;
    float E;
    asm("v_exp_f32 %0, %1" : "=v"(E) : "v"(m));   // 2^m = e^{2u}
    float D = E + 1.0f;
    float R = __builtin_amdgcn_rcpf(D);
    return fmaf(-R, x, x);                        // x*(1-R)
}

__device__ __forceinline__ short f2bf(float f) {
    unsigned u = __float_as_uint(f);
    u = (u + 0x7fffu + ((u >> 16) & 1u)) >> 16;
    return (short)u;
}

// gather 4 consecutive MLP-input slots (k = grp*4 .. grp*4+3) for edge e
__device__ __forceinline__ void gather4(int e, int E, const int* __restrict__ ei,
                                        const float* __restrict__ xt6,
                                        const float* __restrict__ attr, int grp,
                                        float& v0, float& v1, float& v2, float& v3) {
    v0 = v1 = v2 = v3 = 0.f;
    if (e < E) {
        if (grp == 0) {
            const float4 f = *(const float4*)&xt6[(size_t)ei[e] * 8];
            v0 = f.x; v1 = f.y; v2 = f.z; v3 = f.w;
        } else if (grp == 1) {
            int s = ei[e], d = ei[E + e];
            const float2 lo = *(const float2*)&xt6[(size_t)s * 8 + 4];
            const float2 hi = *(const float2*)&xt6[(size_t)d * 8];
            v0 = lo.x; v1 = lo.y; v2 = hi.x; v3 = hi.y;
        } else if (grp == 2) {
            int d = ei[E + e];
            const float2 lo = *(const float2*)&xt6[(size_t)d * 8 + 2];
            const float2 hi = *(const float2*)&xt6[(size_t)d * 8 + 4];
            v0 = lo.x; v1 = lo.y; v2 = hi.x; v3 = hi.y;
        } else {
            v0 = attr[e];
        }
    }
}

// ---------------- node input linear + packed xt6 ----------------
__global__ void k_node_in(const float* __restrict__ x, const float* __restrict__ token,
                          const float* __restrict__ W, const float* __restrict__ b,
                          float* __restrict__ hn, float* __restrict__ xt6, int N) {
    int gid = blockIdx.x * blockDim.x + threadIdx.x;
    int n = gid >> 5, j = gid & 31;
    if (n >= N) return;
    if (j < 8) xt6[(size_t)n * 8 + j] = (j == 0) ? x[n] : ((j < 6) ? token[n * 5 + j - 1] : 0.f);
    if (j >= HID) return;
    float acc = b[j];
    acc += x[n] * W[j];
    #pragma unroll
    for (int i = 0; i < 5; i++) acc += token[n * 5 + i] * W[(i + 1) * HID + j];
    hn[(size_t)n * STR + j] = acc;
}

// ---------------- edge MLP via MFMA (bf16), col'-layout LDS ----------------
__global__ __launch_bounds__(256) void k_edge_mlp_mfma(
    const int* __restrict__ ei, const float* __restrict__ xt6,
    const float* __restrict__ attr, const float* __restrict__ gumbel,
    const float* __restrict__ W0, const float* __restrict__ b0,
    const float* __restrict__ W1, const float* __restrict__ b1,
    const float* __restrict__ W2, const float* __restrict__ b2,
    const float* __restrict__ W3, const float* __restrict__ b3,
    float* __restrict__ eval_, unsigned char* __restrict__ flagv,
    int E, int ntiles, int nwaves) {
    __shared__ short hbuf[4][16 * RST];
    const int lane = threadIdx.x & 63;
    const int wv = threadIdx.x >> 6;
    const int wid = blockIdx.x * 4 + wv;
    const int grp = lane >> 4, r2 = lane & 15;

    short8 w0f[4], w1f[2][4], w2f[2][4];
    #pragma unroll
    for (int nt = 0; nt < 4; nt++) {
        int col = r2 + 16 * nt;
        #pragma unroll
        for (int j = 0; j < 8; j++) {
            int k = grp * 4 + (j & 3) + 16 * (j >> 2);
            w0f[nt][j] = (k < 13 && col < 50) ? f2bf(W0[k * 50 + col]) : (short)0;
        }
    }
    #pragma unroll
    for (int kt = 0; kt < 2; kt++) {
        #pragma unroll
        for (int nt = 0; nt < 4; nt++) {
            int col = r2 + 16 * nt;
            #pragma unroll
            for (int j = 0; j < 8; j++) {
                int cW = (j & 3) * 16 + kt * 8 + grp * 2 + (j >> 2);
                w1f[kt][nt][j] = (cW < 50 && col < 50) ? f2bf(W1[cW * 50 + col]) : (short)0;
                w2f[kt][nt][j] = (cW < 50 && col < 50) ? f2bf(W2[cW * 50 + col]) : (short)0;
            }
        }
    }
    float b0v[4], b1v[4], b2v[4], w3dv[4];
    #pragma unroll
    for (int nt = 0; nt < 4; nt++) {
        int col = r2 + 16 * nt;
        b0v[nt] = (col < 50) ? b0[col] : 0.f;
        b1v[nt] = (col < 50) ? b1[col] : 0.f;
        b2v[nt] = (col < 50) ? b2[col] : 0.f;
        w3dv[nt] = (col < 50) ? (W3[col * 2 + 1] - W3[col * 2]) : 0.f;
    }
    const float b3d = b3[1] - b3[0];
    const f32x4 z4 = {0.f, 0.f, 0.f, 0.f};
    short* hb = &hbuf[wv][0];

    for (int t = wid; t < ntiles; t += nwaves) {
        const int base = t * 16;
        float g0, g1, g2, g3;
        gather4(base + r2, E, ei, xt6, attr, grp, g0, g1, g2, g3);
        short8 a0 = {f2bf(g0), f2bf(g1), f2bf(g2), f2bf(g3), 0, 0, 0, 0};

        // ---- layer 0 ----
        f32x4 c0 = __builtin_amdgcn_mfma_f32_16x16x32_bf16(a0, w0f[0], z4, 0, 0, 0);
        f32x4 c1 = __builtin_amdgcn_mfma_f32_16x16x32_bf16(a0, w0f[1], z4, 0, 0, 0);
        f32x4 c2 = __builtin_amdgcn_mfma_f32_16x16x32_bf16(a0, w0f[2], z4, 0, 0, 0);
        f32x4 c3 = __builtin_amdgcn_mfma_f32_16x16x32_bf16(a0, w0f[3], z4, 0, 0, 0);
        #pragma unroll
        for (int i = 0; i < 4; i++) {
            int row = grp * 4 + i;
            float v0 = gelu_fast(c0[i] + b0v[0]);
            float v1 = gelu_fast(c1[i] + b0v[1]);
            float v2 = gelu_fast(c2[i] + b0v[2]);
            float v3 = gelu_fast(c3[i] + b0v[3]);
            unsigned lo, hi;
            asm("v_cvt_pk_bf16_f32 %0, %1, %2" : "=v"(lo) : "v"(v0), "v"(v1));
            asm("v_cvt_pk_bf16_f32 %0, %1, %2" : "=v"(hi) : "v"(v2), "v"(v3));
            *(int2*)&hb[row * RST + r2 * 4] = make_int2((int)lo, (int)hi);
        }

        // ---- layer 1 ----
        {
            short8 k0 = *(const short8*)&hb[r2 * RST + 0 * 32 + grp * 8];
            short8 k1 = *(const short8*)&hb[r2 * RST + 1 * 32 + grp * 8];
            c0 = __builtin_amdgcn_mfma_f32_16x16x32_bf16(k1, w1f[1][0],
                 __builtin_amdgcn_mfma_f32_16x16x32_bf16(k0, w1f[0][0], z4, 0, 0, 0), 0, 0, 0);
            c1 = __builtin_amdgcn_mfma_f32_16x16x32_bf16(k1, w1f[1][1],
                 __builtin_amdgcn_mfma_f32_16x16x32_bf16(k0, w1f[0][1], z4, 0, 0, 0), 0, 0, 0);
            c2 = __builtin_amdgcn_mfma_f32_16x16x32_bf16(k1, w1f[1][2],
                 __builtin_amdgcn_mfma_f32_16x16x32_bf16(k0, w1f[0][2], z4, 0, 0, 0), 0, 0, 0);
            c3 = __builtin_amdgcn_mfma_f32_16x16x32_bf16(k1, w1f[1][3],
                 __builtin_amdgcn_mfma_f32_16x16x32_bf16(k0, w1f[0][3], z4, 0, 0, 0), 0, 0, 0);
        }
        #pragma unroll
        for (int i = 0; i < 4; i++) {
            int row = grp * 4 + i;
            float v0 = gelu_fast(c0[i] + b1v[0]);
            float v1 = gelu_fast(c1[i] + b1v[1]);
            float v2 = gelu_fast(c2[i] + b1v[2]);
            float v3 = gelu_fast(c3[i] + b1v[3]);
            unsigned lo, hi;
            asm("v_cvt_pk_bf16_f32 %0, %1, %2" : "=v"(lo) : "v"(v0), "v"(v1));
            asm("v_cvt_pk_bf16_f32 %0, %1, %2" : "=v"(hi) : "v"(v2), "v"(v3));
            *(int2*)&hb[row * RST + r2 * 4] = make_int2((int)lo, (int)hi);
        }

        // ---- layer 2 ----
        {
            short8 k0 = *(const short8*)&hb[r2 * RST + 0 * 32 + grp * 8];
            short8 k1 = *(const short8*)&hb[r2 * RST + 1 * 32 + grp * 8];
            c0 = __builtin_amdgcn_mfma_f32_16x16x32_bf16(k1, w2f[1][0],
                 __builtin_amdgcn_mfma_f32_16x16x32_bf16(k0, w2f[0][0], z4, 0, 0, 0), 0, 0, 0);
            c1 = __builtin_amdgcn_mfma_f32_16x16x32_bf16(k1, w2f[1][1],
                 __builtin_amdgcn_mfma_f32_16x16x32_bf16(k0, w2f[0][1], z4, 0, 0, 0), 0, 0, 0);
            c2 = __builtin_amdgcn_mfma_f32_16x16x32_bf16(k1, w2f[1][2],
                 __builtin_amdgcn_mfma_f32_16x16x32_bf16(k0, w2f[0][2], z4, 0, 0, 0), 0, 0, 0);
            c3 = __builtin_amdgcn_mfma_f32_16x16x32_bf16(k1, w2f[1][3],
                 __builtin_amdgcn_mfma_f32_16x16x32_bf16(k0, w2f[0][3], z4, 0, 0, 0), 0, 0, 0);
        }

        float z0 = 0.f, z1 = 0.f, z2 = 0.f, z3 = 0.f;
        #pragma unroll
        for (int i = 0; i < 4; i++) {
            float h0 = gelu_fast(c0[i] + b2v[0]), h1 = gelu_fast(c1[i] + b2v[1]);
            float h2 = gelu_fast(c2[i] + b2v[2]), h3 = gelu_fast(c3[i] + b2v[3]);
            float z = h0 * w3dv[0] + h1 * w3dv[1] + h2 * w3dv[2] + h3 * w3dv[3];
            if (i == 0) z0 = z; else if (i == 1) z1 = z; else if (i == 2) z2 = z; else z3 = z;
        }
        #pragma unroll
        for (int off = 1; off < 16; off <<= 1) {
            z0 += __shfl_xor(z0, off); z1 += __shfl_xor(z1, off);
            z2 += __shfl_xor(z2, off); z3 += __shfl_xor(z3, off);
        }
        if (r2 < 4) {
            int e2 = base + grp * 4 + r2;
            if (e2 < E) {
                float zsel = (r2 == 0) ? z0 : (r2 == 1) ? z1 : (r2 == 2) ? z2 : z3;
                float g0v = gumbel[2 * (long long)e2], g1v = gumbel[2 * (long long)e2 + 1];
                float m = zsel + b3d + g1v - g0v;
                eval_[e2] = (m > 0.f) ? 1.f : 0.f;
                flagv[e2] = (fabsf(m) < FBTHR) ? 1 : 0;
            }
        }
    }
}

// ---------------- block-aggregated flag -> list compaction ----------------
__global__ __launch_bounds__(256) void k_compact(const unsigned char* __restrict__ flagv,
                                                 int* __restrict__ flcnt,
                                                 int* __restrict__ fllist, int E) {
    __shared__ int s[256];
    __shared__ int sbase;
    const int t = threadIdx.x;
    const long long base = (long long)blockIdx.x * (256 * CEPT) + (long long)t * CEPT;

    unsigned char fl[CEPT];
    #pragma unroll
    for (int u = 0; u < CEPT; u += 16) {
        int4 w = make_int4(0, 0, 0, 0);
        if (base + u + 15 < (long long)E) {
            w = *(const int4*)&flagv[base + u];
        } else {
            #pragma unroll
            for (int b2 = 0; b2 < 16; b2++) {
                long long idx = base + u + b2;
                ((unsigned char*)&w)[b2] = (idx < (long long)E) ? flagv[idx] : 0;
            }
        }
        *(int4*)&fl[u] = w;
    }
    int cnt = 0;
    #pragma unroll
    for (int u = 0; u < CEPT; u++) cnt += fl[u];

    s[t] = cnt;
    __syncthreads();
    for (int off = 1; off < 256; off <<= 1) {
        int xv = (t >= off) ? s[t - off] : 0;
        __syncthreads();
        s[t] += xv;
        __syncthreads();
    }
    if (t == 255) sbase = (s[255] > 0) ? atomicAdd(flcnt, s[255]) : 0;
    __syncthreads();

    int pos = sbase + s[t] - cnt;
    #pragma unroll
    for (int u = 0; u < CEPT; u++) {
        if (fl[u]) fllist[pos++] = (int)(base + u);
    }
}

// ---------------- wave-cooperative exact-fp32 fallback ----------------
__global__ __launch_bounds__(256) void k_edge_fb(
    const int* __restrict__ ei, const float* __restrict__ xt6,
    const float* __restrict__ attr, const float* __restrict__ gumbel,
    const float* __restrict__ W0, const float* __restrict__ b0,
    const float* __restrict__ W1, const float* __restrict__ b1,
    const float* __restrict__ W2, const float* __restrict__ b2,
    const float* __restrict__ W3, const float* __restrict__ b3,
    const int* __restrict__ fllist, const int* __restrict__ flcnt,
    float* __restrict__ eval_, int E, int nwaves) {
    __shared__ float buf[4][2][2][64];
    const int lane = threadIdx.x & 63;
    const int wv = threadIdx.x >> 6;
    const int wid = blockIdx.x * 4 + wv;
    const int jw = (lane < 50) ? lane : 49;

    float w0r[16], w1r[52], w2r[52];
    #pragma unroll
    for (int k = 0; k < 13; k++) w0r[k] = W0[k * 50 + jw];
    w0r[13] = 0.f; w0r[14] = 0.f; w0r[15] = 0.f;
    #pragma unroll
    for (int k = 0; k < 50; k++) w1r[k] = W1[k * 50 + jw];
    w1r[50] = 0.f; w1r[51] = 0.f;
    #pragma unroll
    for (int k = 0; k < 50; k++) w2r[k] = W2[k * 50 + jw];
    w2r[50] = 0.f; w2r[51] = 0.f;
    const float b0r = b0[jw], b1r = b1[jw], b2r = b2[jw];
    const float b3_0 = b3[0], b3_1 = b3[1];
    const float w3d = (lane < 50) ? (W3[lane * 2 + 1] - W3[lane * 2]) : 0.f;

    const int g = lane >> 4, r = lane & 15;
    const int cnt = *flcnt;

    for (int base = wid * 2; base < cnt; base += nwaves * 2) {
        if (g < 2) {
            int idx = base + g;
            float val = 0.f;
            if (idx < cnt && r < 13) {
                int e = fllist[idx];
                if (r == 12) val = attr[e];
                else if (r < 6) val = xt6[(size_t)ei[e] * 8 + r];
                else val = xt6[(size_t)ei[E + e] * 8 + (r - 6)];
            }
            buf[wv][0][g][r] = val;
        }

        const float4* a4 = (const float4*)(&buf[wv][0][0][0]);
        const float4* c4 = (const float4*)(&buf[wv][0][1][0]);
        float tA = b0r, tB = b0r;
        #pragma unroll
        for (int c = 0; c < 4; c++) {
            float4 a = a4[c], b = c4[c];
            tA += a.x * w0r[4 * c];     tB += b.x * w0r[4 * c];
            tA += a.y * w0r[4 * c + 1]; tB += b.y * w0r[4 * c + 1];
            tA += a.z * w0r[4 * c + 2]; tB += b.z * w0r[4 * c + 2];
            tA += a.w * w0r[4 * c + 3]; tB += b.w * w0r[4 * c + 3];
        }
        buf[wv][1][0][lane] = gelu_f(tA);
        buf[wv][1][1][lane] = gelu_f(tB);

        const float4* p4 = (const float4*)(&buf[wv][1][0][0]);
        const float4* q4 = (const float4*)(&buf[wv][1][1][0]);
        tA = b1r; tB = b1r;
        #pragma unroll
        for (int c = 0; c < 13; c++) {
            float4 a = p4[c], b = q4[c];
            tA += a.x * w1r[4 * c];     tB += b.x * w1r[4 * c];
            tA += a.y * w1r[4 * c + 1]; tB += b.y * w1r[4 * c + 1];
            tA += a.z * w1r[4 * c + 2]; tB += b.z * w1r[4 * c + 2];
            tA += a.w * w1r[4 * c + 3]; tB += b.w * w1r[4 * c + 3];
        }
        buf[wv][0][0][lane] = gelu_f(tA);
        buf[wv][0][1][lane] = gelu_f(tB);

        tA = b2r; tB = b2r;
        #pragma unroll
        for (int c = 0; c < 13; c++) {
            float4 a = a4[c], b = c4[c];
            tA += a.x * w2r[4 * c];     tB += b.x * w2r[4 * c];
            tA += a.y * w2r[4 * c + 1]; tB += b.y * w2r[4 * c + 1];
            tA += a.z * w2r[4 * c + 2]; tB += b.z * w2r[4 * c + 2];
            tA += a.w * w2r[4 * c + 3]; tB += b.w * w2r[4 * c + 3];
        }
        float h3A = gelu_f(tA), h3B = gelu_f(tB);
        buf[wv][1][0][lane] = h3A;
        buf[wv][1][1][lane] = h3B;

        float zA = h3A * w3d, zB = h3B * w3d;
        #pragma unroll
        for (int off = 32; off > 0; off >>= 1) {
            zA += __shfl_xor(zA, off);
            zB += __shfl_xor(zB, off);
        }

        if (lane < 2) {
            int idx = base + lane;
            if (idx < cnt) {
                int e = fllist[idx];
                float z = (lane == 0) ? zA : zB;
                float g0v = gumbel[2 * (long long)e], g1v = gumbel[2 * (long long)e + 1];
                float m = z + (b3_1 - b3_0) + g1v - g0v;
                float dec;
                if (fabsf(m) < 1e-4f) {
                    float z0 = 0.f, z1 = 0.f;
                    for (int j = 0; j < 50; j++) {
                        float h = buf[wv][1][lane][j];
                        z0 += h * W3[2 * j];
                        z1 += h * W3[2 * j + 1];
                    }
                    z0 += b3_0; z1 += b3_1;
                    dec = (z1 + g1v > z0 + g0v) ? 1.f : 0.f;
                } else {
                    dec = (m > 0.f) ? 1.f : 0.f;
                }
                eval_[e] = dec;
            }
        }
    }
}

// ---------------- CSR build: histogram (x4) + scan + scatter(+pack) ----------------
__global__ void k_hist(const int* __restrict__ ei, int* __restrict__ cnt, int E) {
    int i = blockIdx.x * blockDim.x + threadIdx.x;
    int e = i * 4;
    if (e + 3 < E) {
        int4 d = *(const int4*)&ei[E + e];
        atomicAdd(&cnt[d.x], 1); atomicAdd(&cnt[d.y], 1);
        atomicAdd(&cnt[d.z], 1); atomicAdd(&cnt[d.w], 1);
    } else {
        for (int u = e; u < E; u++) atomicAdd(&cnt[ei[E + u]], 1);
    }
}

__global__ void k_scan_partial(const int* __restrict__ cnt, int* __restrict__ bsum, int N) {
    __shared__ int s[256];
    int b = blockIdx.x, t = threadIdx.x;
    int base = b * CHUNK + t * 4;
    int sum = 0;
    #pragma unroll
    for (int u = 0; u < 4; u++) { int idx = base + u; if (idx < N) sum += cnt[idx]; }
    s[t] = sum; __syncthreads();
    for (int off = 128; off > 0; off >>= 1) {
        if (t < off) s[t] += s[t + off];
        __syncthreads();
    }
    if (t == 0) bsum[b] = s[0];
}

__global__ void k_scan_top(const int* __restrict__ bsum, int* __restrict__ boff,
                           int* __restrict__ rowptr, int nb, int N, int E) {
    if (threadIdx.x == 0 && blockIdx.x == 0) {
        int run = 0;
        for (int i = 0; i < nb; i++) { boff[i] = run; run += bsum[i]; }
        rowptr[N] = E;
    }
}

__global__ void k_scan_final(const int* __restrict__ cnt, const int* __restrict__ boff,
                             int* __restrict__ rowptr, int* __restrict__ wpos, int N) {
    __shared__ int s[256];
    int b = blockIdx.x, t = threadIdx.x;
    int base = b * CHUNK + t * 4;
    int v0 = 0, v1 = 0, v2 = 0, v3 = 0;
    if (base     < N) v0 = cnt[base];
    if (base + 1 < N) v1 = cnt[base + 1];
    if (base + 2 < N) v2 = cnt[base + 2];
    if (base + 3 < N) v3 = cnt[base + 3];
    int ts = v0 + v1 + v2 + v3;
    s[t] = ts; __syncthreads();
    for (int off = 1; off < 256; off <<= 1) {
        int xv = (t >= off) ? s[t - off] : 0;
        __syncthreads();
        s[t] += xv;
        __syncthreads();
    }
    int excl = s[t] - ts + boff[b];
    if (base     < N) { rowptr[base]     = excl;                 wpos[base]     = excl; }
    if (base + 1 < N) { int p = excl + v0;           rowptr[base + 1] = p; wpos[base + 1] = p; }
    if (base + 2 < N) { int p = excl + v0 + v1;      rowptr[base + 2] = p; wpos[base + 2] = p; }
    if (base + 3 < N) { int p = excl + v0 + v1 + v2; rowptr[base + 3] = p; wpos[base + 3] = p; }
}

// scatter + pack per-edge record {src, attr, eval} at CSR position
__global__ void k_scatter(const int* __restrict__ ei, const float* __restrict__ attr,
                          const float* __restrict__ eval_, int* __restrict__ wpos,
                          int4* __restrict__ epack, int E) {
    int e = blockIdx.x * blockDim.x + threadIdx.x;
    if (e >= E) return;
    int d = ei[E + e];
    int p = atomicAdd(&wpos[d], 1);
    int4 rec;
    rec.x = ei[e];
    rec.y = __float_as_int(attr[e]);
    rec.z = __float_as_int(eval_[e]);
    rec.w = 0;
    epack[p] = rec;
}

// ---------------- per-layer node transform: q fp32, k/v packed bf16 (one 128B line) ----------------
__global__ void k_qkvs(const float* __restrict__ hn,
                       const float* __restrict__ Wq, const float* __restrict__ bq,
                       const float* __restrict__ Wk, const float* __restrict__ bk,
                       const float* __restrict__ Wv, const float* __restrict__ bv,
                       const float* __restrict__ Ws, const float* __restrict__ bs,
                       float* __restrict__ q, unsigned short* __restrict__ kvp,
                       float* __restrict__ hnext, int N) {
    __shared__ float sWq[625], sWk[625], sWv[625], sWs[625], sbq[25], sbk[25], sbv[25], sbs[25];
    for (int i = threadIdx.x; i < 625; i += blockDim.x) {
        sWq[i] = Wq[i]; sWk[i] = Wk[i]; sWv[i] = Wv[i]; sWs[i] = Ws[i];
    }
    if (threadIdx.x < 25) {
        sbq[threadIdx.x] = bq[threadIdx.x]; sbk[threadIdx.x] = bk[threadIdx.x];
        sbv[threadIdx.x] = bv[threadIdx.x]; sbs[threadIdx.x] = bs[threadIdx.x];
    }
    __syncthreads();
    int gid = blockIdx.x * blockDim.x + threadIdx.x;
    int n = gid >> 5, j = gid & 31;
    if (n >= N) return;
    if (j >= HID) {
        kvp[(size_t)n * 64 + j] = 0;
        kvp[(size_t)n * 64 + 32 + j] = 0;
        return;
    }
    float h[25];
    #pragma unroll
    for (int i = 0; i < 25; i++) h[i] = hn[(size_t)n * STR + i];
    float aq = sbq[j], ak = sbk[j], av = sbv[j], as = sbs[j];
    #pragma unroll
    for (int i = 0; i < 25; i++) {
        float hi = h[i];
        aq += hi * sWq[i * 25 + j];
        ak += hi * sWk[i * 25 + j];
        av += hi * sWv[i * 25 + j];
        as += hi * sWs[i * 25 + j];
    }
    q[(size_t)n * STR + j] = aq;
    hnext[(size_t)n * STR + j] = as;
    kvp[(size_t)n * 64 + j] = (unsigned short)f2bf(ak);
    kvp[(size_t)n * 64 + 32 + j] = (unsigned short)f2bf(av);
}

// ---------------- fused node-centric attention, 4 lanes/node, bf16 kv single-line ----------------
__global__ void k_attn_node(const int* __restrict__ rowptr, const int4* __restrict__ epack,
                            const float* __restrict__ q, const unsigned short* __restrict__ kvp,
                            const float* __restrict__ We, const float* __restrict__ be,
                            float* __restrict__ hnext, int N) {
    int gid = blockIdx.x * blockDim.x + threadIdx.x;
    int n = gid >> 2, sub = gid & 3;
    if (n >= N) return;
    const float scale = 0.44721359549995793f;

    float qr[25];
    #pragma unroll
    for (int i = 0; i < 25; i++) qr[i] = q[(size_t)n * STR + i];

    float qW0[5], qW1[5], qbe[5];
    #pragma unroll
    for (int h = 0; h < 5; h++) {
        float a0 = 0.f, a1 = 0.f, ab = 0.f;
        #pragma unroll
        for (int c = 0; c < 5; c++) {
            int i = h * 5 + c;
            a0 += qr[i] * We[i];
            a1 += qr[i] * We[25 + i];
            ab += qr[i] * be[i];
        }
        qW0[h] = a0; qW1[h] = a1; qbe[h] = ab;
    }

    float accV[25];
    #pragma unroll
    for (int i = 0; i < 25; i++) accV[i] = 0.f;
    float den[5] = {0, 0, 0, 0, 0}, sA[5] = {0, 0, 0, 0, 0}, sG[5] = {0, 0, 0, 0, 0};

    int beg = rowptr[n], end = rowptr[n + 1];
    for (int p = beg + sub; p < end; p += 4) {
        int4 ep = epack[p];
        int s = ep.x;
        float a_ = __int_as_float(ep.y), gl = __int_as_float(ep.z);
        const unsigned* kw = (const unsigned*)(kvp + (size_t)s * 64);

        float al[5];
        #pragma unroll
        for (int h = 0; h < 5; h++) al[h] = qW0[h] * a_ + qW1[h] * gl + qbe[h];
        #pragma unroll
        for (int w = 0; w < 12; w++) {
            unsigned u = kw[w];
            al[(2 * w) / 5]     = fmaf(__uint_as_float(u << 16), qr[2 * w], al[(2 * w) / 5]);
            al[(2 * w + 1) / 5] = fmaf(__uint_as_float(u & 0xffff0000u), qr[2 * w + 1], al[(2 * w + 1) / 5]);
        }
        al[4] = fmaf(__uint_as_float(kw[12] << 16), qr[24], al[4]);

        float exh[5];
        #pragma unroll
        for (int h = 0; h < 5; h++) {
            float ex = __expf(al[h] * scale);
            exh[h] = ex;
            den[h] += ex;
            sA[h] += ex * a_;
            sG[h] += ex * gl;
        }
        #pragma unroll
        for (int w = 0; w < 12; w++) {
            unsigned u = kw[16 + w];
            accV[2 * w]     = fmaf(exh[(2 * w) / 5], __uint_as_float(u << 16), accV[2 * w]);
            accV[2 * w + 1] = fmaf(exh[(2 * w + 1) / 5], __uint_as_float(u & 0xffff0000u), accV[2 * w + 1]);
        }
        accV[24] = fmaf(exh[4], __uint_as_float(kw[28] << 16), accV[24]);
    }

    #pragma unroll
    for (int off = 1; off < 4; off <<= 1) {
        #pragma unroll
        for (int i = 0; i < 25; i++) accV[i] += __shfl_xor(accV[i], off);
        #pragma unroll
        for (int h = 0; h < 5; h++) {
            den[h] += __shfl_xor(den[h], off);
            sA[h] += __shfl_xor(sA[h], off);
            sG[h] += __shfl_xor(sG[h], off);
        }
    }

    if (sub == 0) {
        #pragma unroll
        for (int h = 0; h < 5; h++) {
            float inv = 1.f / (den[h] + 1e-16f);
            #pragma unroll
            for (int c = 0; c < 5; c++) {
                int i = h * 5 + c;
                float agg = (accV[i] + sA[h] * We[i] + sG[h] * We[25 + i] + den[h] * be[i]) * inv;
                hnext[(size_t)n * STR + i] += agg;
            }
        }
    }
}

// ---------------- output ----------------
__global__ void k_out(const float* __restrict__ hn, const float* __restrict__ W,
                      const float* __restrict__ b, float* __restrict__ out, int N) {
    int n = blockIdx.x * blockDim.x + threadIdx.x;
    if (n >= N) return;
    float acc = b[0];
    #pragma unroll
    for (int i = 0; i < 25; i++) acc += hn[(size_t)n * STR + i] * W[i];
    out[n] = 1.f / (1.f + expf(-acc));
}

extern "C" void kernel_launch(void* const* d_in, const int* in_sizes, int n_in,
                              void* d_out, int out_size, void* d_ws, size_t ws_size,
                              hipStream_t stream) {
    const float* x      = (const float*)d_in[0];
    const float* token  = (const float*)d_in[1];
    const float* attr   = (const float*)d_in[2];
    const float* gumbel = (const float*)d_in[3];
    const int*   ei     = (const int*)d_in[4];
    const float* W0 = (const float*)d_in[5];
    const float* b0 = (const float*)d_in[6];
    const float* W1 = (const float*)d_in[7];
    const float* b1 = (const float*)d_in[8];
    const float* W2 = (const float*)d_in[9];
    const float* b2 = (const float*)d_in[10];
    const float* W3 = (const float*)d_in[11];
    const float* b3 = (const float*)d_in[12];
    const float* ilW = (const float*)d_in[13];
    const float* ilb = (const float*)d_in[14];
    const float* Wq = (const float*)d_in[15];
    const float* bq = (const float*)d_in[16];
    const float* Wk = (const float*)d_in[17];
    const float* bk = (const float*)d_in[18];
    const float* Wv = (const float*)d_in[19];
    const float* bv = (const float*)d_in[20];
    const float* We = (const float*)d_in[21];
    const float* be = (const float*)d_in[22];
    const float* Ws = (const float*)d_in[23];
    const float* bs = (const float*)d_in[24];
    const float* oW = (const float*)d_in[25];
    const float* ob = (const float*)d_in[26];

    const int N = in_sizes[0];
    const int E = in_sizes[2];
    const int nb_chunk = (N + CHUNK - 1) / CHUNK;

    char* ws = (char*)d_ws;
    size_t off = 0;
    auto alloc = [&](size_t nb) -> void* {
        void* p = ws + off;
        off += (nb + 255) & ~(size_t)255;
        return p;
    };
    float* hnA    = (float*)alloc((size_t)N * STR * 4);
    float* hnB    = (float*)alloc((size_t)N * STR * 4);
    float* q      = (float*)alloc((size_t)N * STR * 4);
    unsigned short* kvp = (unsigned short*)alloc((size_t)N * 64 * 2);
    float* evalv  = (float*)alloc((size_t)E * 4);
    float* xt6    = (float*)alloc((size_t)N * 8 * 4);
    int*   cnt    = (int*)alloc((size_t)N * 4);
    int*   rowptr = (int*)alloc((size_t)(N + 1) * 4);
    int*   wpos   = (int*)alloc((size_t)N * 4);
    int*   bsum   = (int*)alloc((size_t)(nb_chunk + 1) * 4);
    int*   boff   = (int*)alloc((size_t)(nb_chunk + 1) * 4);
    int4*  epack  = (int4*)alloc((size_t)E * 16);
    int*   flcnt  = (int*)alloc(256);
    int*   fllist = (int*)alloc((size_t)E * 4);
    unsigned char* flagv = (unsigned char*)alloc((size_t)E);

    int nb_n32  = (N * STR + 255) / 256;
    int nb_n32b = (N * STR + 511) / 512;
    int nb_e    = (E + 255) / 256;
    int nb_e4   = ((E + 3) / 4 + 255) / 256;
    int nb_n4   = (N * 4 + 255) / 256;
    int nb_n    = (N + 255) / 256;
    int nb_cmp  = (E + 256 * CEPT - 1) / (256 * CEPT);

    const int mlp_blocks = 4096;
    const int mlp_waves  = mlp_blocks * 4;
    const int ntiles     = (E + 15) / 16;

    hipMemsetAsync(cnt, 0, (size_t)N * 4, stream);
    hipMemsetAsync(flcnt, 0, 4, stream);
    k_node_in<<<nb_n32, 256, 0, stream>>>(x, token, ilW, ilb, hnA, xt6, N);
    k_edge_mlp_mfma<<<mlp_blocks, 256, 0, stream>>>(ei, xt6, attr, gumbel,
                                                    W0, b0, W1, b1, W2, b2, W3, b3,
                                                    evalv, flagv, E, ntiles, mlp_waves);
    k_compact<<<nb_cmp, 256, 0, stream>>>(flagv, flcnt, fllist, E);
    k_edge_fb<<<2048, 256, 0, stream>>>(ei, xt6, attr, gumbel,
                                        W0, b0, W1, b1, W2, b2, W3, b3,
                                        fllist, flcnt, evalv, E, 2048 * 4);
    k_hist<<<nb_e4, 256, 0, stream>>>(ei, cnt, E);
    k_scan_partial<<<nb_chunk, 256, 0, stream>>>(cnt, bsum, N);
    k_scan_top<<<1, 64, 0, stream>>>(bsum, boff, rowptr, nb_chunk, N, E);
    k_scan_final<<<nb_chunk, 256, 0, stream>>>(cnt, boff, rowptr, wpos, N);
    k_scatter<<<nb_e, 256, 0, stream>>>(ei, attr, evalv, wpos, epack, E);

    float* cur = hnA;
    float* nxt = hnB;
    for (int l = 0; l < 3; l++) {
        k_qkvs<<<nb_n32b, 512, 0, stream>>>(cur, Wq + l * 625, bq + l * 25,
                                            Wk + l * 625, bk + l * 25,
                                            Wv + l * 625, bv + l * 25,
                                            Ws + l * 625, bs + l * 25,
                                            q, kvp, nxt, N);
        k_attn_node<<<nb_n4, 256, 0, stream>>>(rowptr, epack, q, kvp,
                                               We + l * 50, be + l * 25, nxt, N);
        float* t = cur; cur = nxt; nxt = t;
    }
    k_out<<<nb_n, 256, 0, stream>>>(cur, oW, ob, (float*)d_out, N);
}

// Round 15
// 1172.537 us; speedup vs baseline: 3.1916x; 1.0204x over previous
//
#include <hip/hip_runtime.h>
#include <math.h>

#define HID 25
#define STR 32   // padded node-feature row stride (128B rows)
#define CHUNK 1024
#define FBTHR 0.1f
#define RST 72   // LDS activation row stride in bf16 (144B; conflict-managed)
#define CEPT 32  // edges per thread in k_compact (8192/block)

typedef __attribute__((ext_vector_type(8))) short short8;
typedef __attribute__((ext_vector_type(4))) float f32x4;

__device__ __forceinline__ float gelu_f(float x) {
    return 0.5f * x * (1.0f + erff(x * 0.70710678118654752f));
}

// tanh-form gelu, 7 VALU ops. Max err ~1e-3 -> z-margin err << FBTHR;
// exact-erf fallback decides all near-margin gates.
__device__ __forceinline__ float gelu_fast(float x) {
    float x2 = x * x;
    float c = fmaf(0.1029461f, x2, 2.3022077f);
    float m = x * c;
    float E;
    asm("v_exp_f32 %0, %1" : "=v"(E) : "v"(m));
    float D = E + 1.0f;
    float R = __builtin_amdgcn_rcpf(D);
    return fmaf(-R, x, x);
}

__device__ __forceinline__ short f2bf(float f) {
    unsigned u = __float_as_uint(f);
    u = (u + 0x7fffu + ((u >> 16) & 1u)) >> 16;
    return (short)u;
}

// gather 4 consecutive MLP-input slots (k = grp*4 .. grp*4+3) for edge e
__device__ __forceinline__ void gather4(int e, int E, const int* __restrict__ ei,
                                        const float* __restrict__ xt6,
                                        const float* __restrict__ attr, int grp,
                                        float& v0, float& v1, float& v2, float& v3) {
    v0 = v1 = v2 = v3 = 0.f;
    if (e < E) {
        if (grp == 0) {
            const float4 f = *(const float4*)&xt6[(size_t)ei[e] * 8];
            v0 = f.x; v1 = f.y; v2 = f.z; v3 = f.w;
        } else if (grp == 1) {
            int s = ei[e], d = ei[E + e];
            const float2 lo = *(const float2*)&xt6[(size_t)s * 8 + 4];
            const float2 hi = *(const float2*)&xt6[(size_t)d * 8];
            v0 = lo.x; v1 = lo.y; v2 = hi.x; v3 = hi.y;
        } else if (grp == 2) {
            int d = ei[E + e];
            const float2 lo = *(const float2*)&xt6[(size_t)d * 8 + 2];
            const float2 hi = *(const float2*)&xt6[(size_t)d * 8 + 4];
            v0 = lo.x; v1 = lo.y; v2 = hi.x; v3 = hi.y;
        } else {
            v0 = attr[e];
        }
    }
}

// ---------------- node input linear + packed xt6 ----------------
__global__ void k_node_in(const float* __restrict__ x, const float* __restrict__ token,
                          const float* __restrict__ W, const float* __restrict__ b,
                          float* __restrict__ hn, float* __restrict__ xt6, int N) {
    int gid = blockIdx.x * blockDim.x + threadIdx.x;
    int n = gid >> 5, j = gid & 31;
    if (n >= N) return;
    if (j < 8) xt6[(size_t)n * 8 + j] = (j == 0) ? x[n] : ((j < 6) ? token[n * 5 + j - 1] : 0.f);
    if (j >= HID) return;
    float acc = b[j];
    acc += x[n] * W[j];
    #pragma unroll
    for (int i = 0; i < 5; i++) acc += token[n * 5 + i] * W[(i + 1) * HID + j];
    hn[(size_t)n * STR + j] = acc;
}

// ---------------- edge MLP via MFMA (bf16), col'-layout LDS ----------------
__global__ __launch_bounds__(256) void k_edge_mlp_mfma(
    const int* __restrict__ ei, const float* __restrict__ xt6,
    const float* __restrict__ attr, const float* __restrict__ gumbel,
    const float* __restrict__ W0, const float* __restrict__ b0,
    const float* __restrict__ W1, const float* __restrict__ b1,
    const float* __restrict__ W2, const float* __restrict__ b2,
    const float* __restrict__ W3, const float* __restrict__ b3,
    float* __restrict__ eval_, unsigned char* __restrict__ flagv,
    int E, int ntiles, int nwaves) {
    __shared__ short hbuf[4][16 * RST];
    const int lane = threadIdx.x & 63;
    const int wv = threadIdx.x >> 6;
    const int wid = blockIdx.x * 4 + wv;
    const int grp = lane >> 4, r2 = lane & 15;

    short8 w0f[4], w1f[2][4], w2f[2][4];
    #pragma unroll
    for (int nt = 0; nt < 4; nt++) {
        int col = r2 + 16 * nt;
        #pragma unroll
        for (int j = 0; j < 8; j++) {
            int k = grp * 4 + (j & 3) + 16 * (j >> 2);
            w0f[nt][j] = (k < 13 && col < 50) ? f2bf(W0[k * 50 + col]) : (short)0;
        }
    }
    #pragma unroll
    for (int kt = 0; kt < 2; kt++) {
        #pragma unroll
        for (int nt = 0; nt < 4; nt++) {
            int col = r2 + 16 * nt;
            #pragma unroll
            for (int j = 0; j < 8; j++) {
                int cW = (j & 3) * 16 + kt * 8 + grp * 2 + (j >> 2);
                w1f[kt][nt][j] = (cW < 50 && col < 50) ? f2bf(W1[cW * 50 + col]) : (short)0;
                w2f[kt][nt][j] = (cW < 50 && col < 50) ? f2bf(W2[cW * 50 + col]) : (short)0;
            }
        }
    }
    float b0v[4], b1v[4], b2v[4], w3dv[4];
    #pragma unroll
    for (int nt = 0; nt < 4; nt++) {
        int col = r2 + 16 * nt;
        b0v[nt] = (col < 50) ? b0[col] : 0.f;
        b1v[nt] = (col < 50) ? b1[col] : 0.f;
        b2v[nt] = (col < 50) ? b2[col] : 0.f;
        w3dv[nt] = (col < 50) ? (W3[col * 2 + 1] - W3[col * 2]) : 0.f;
    }
    const float b3d = b3[1] - b3[0];
    const f32x4 z4 = {0.f, 0.f, 0.f, 0.f};
    short* hb = &hbuf[wv][0];

    for (int t = wid; t < ntiles; t += nwaves) {
        const int base = t * 16;
        float g0, g1, g2, g3;
        gather4(base + r2, E, ei, xt6, attr, grp, g0, g1, g2, g3);
        short8 a0 = {f2bf(g0), f2bf(g1), f2bf(g2), f2bf(g3), 0, 0, 0, 0};

        // ---- layer 0 ----
        f32x4 c0 = __builtin_amdgcn_mfma_f32_16x16x32_bf16(a0, w0f[0], z4, 0, 0, 0);
        f32x4 c1 = __builtin_amdgcn_mfma_f32_16x16x32_bf16(a0, w0f[1], z4, 0, 0, 0);
        f32x4 c2 = __builtin_amdgcn_mfma_f32_16x16x32_bf16(a0, w0f[2], z4, 0, 0, 0);
        f32x4 c3 = __builtin_amdgcn_mfma_f32_16x16x32_bf16(a0, w0f[3], z4, 0, 0, 0);
        #pragma unroll
        for (int i = 0; i < 4; i++) {
            int row = grp * 4 + i;
            float v0 = gelu_fast(c0[i] + b0v[0]);
            float v1 = gelu_fast(c1[i] + b0v[1]);
            float v2 = gelu_fast(c2[i] + b0v[2]);
            float v3 = gelu_fast(c3[i] + b0v[3]);
            unsigned lo, hi;
            asm("v_cvt_pk_bf16_f32 %0, %1, %2" : "=v"(lo) : "v"(v0), "v"(v1));
            asm("v_cvt_pk_bf16_f32 %0, %1, %2" : "=v"(hi) : "v"(v2), "v"(v3));
            *(int2*)&hb[row * RST + r2 * 4] = make_int2((int)lo, (int)hi);
        }

        // ---- layer 1 ----
        {
            short8 k0 = *(const short8*)&hb[r2 * RST + 0 * 32 + grp * 8];
            short8 k1 = *(const short8*)&hb[r2 * RST + 1 * 32 + grp * 8];
            c0 = __builtin_amdgcn_mfma_f32_16x16x32_bf16(k1, w1f[1][0],
                 __builtin_amdgcn_mfma_f32_16x16x32_bf16(k0, w1f[0][0], z4, 0, 0, 0), 0, 0, 0);
            c1 = __builtin_amdgcn_mfma_f32_16x16x32_bf16(k1, w1f[1][1],
                 __builtin_amdgcn_mfma_f32_16x16x32_bf16(k0, w1f[0][1], z4, 0, 0, 0), 0, 0, 0);
            c2 = __builtin_amdgcn_mfma_f32_16x16x32_bf16(k1, w1f[1][2],
                 __builtin_amdgcn_mfma_f32_16x16x32_bf16(k0, w1f[0][2], z4, 0, 0, 0), 0, 0, 0);
            c3 = __builtin_amdgcn_mfma_f32_16x16x32_bf16(k1, w1f[1][3],
                 __builtin_amdgcn_mfma_f32_16x16x32_bf16(k0, w1f[0][3], z4, 0, 0, 0), 0, 0, 0);
        }
        #pragma unroll
        for (int i = 0; i < 4; i++) {
            int row = grp * 4 + i;
            float v0 = gelu_fast(c0[i] + b1v[0]);
            float v1 = gelu_fast(c1[i] + b1v[1]);
            float v2 = gelu_fast(c2[i] + b1v[2]);
            float v3 = gelu_fast(c3[i] + b1v[3]);
            unsigned lo, hi;
            asm("v_cvt_pk_bf16_f32 %0, %1, %2" : "=v"(lo) : "v"(v0), "v"(v1));
            asm("v_cvt_pk_bf16_f32 %0, %1, %2" : "=v"(hi) : "v"(v2), "v"(v3));
            *(int2*)&hb[row * RST + r2 * 4] = make_int2((int)lo, (int)hi);
        }

        // ---- layer 2 ----
        {
            short8 k0 = *(const short8*)&hb[r2 * RST + 0 * 32 + grp * 8];
            short8 k1 = *(const short8*)&hb[r2 * RST + 1 * 32 + grp * 8];
            c0 = __builtin_amdgcn_mfma_f32_16x16x32_bf16(k1, w2f[1][0],
                 __builtin_amdgcn_mfma_f32_16x16x32_bf16(k0, w2f[0][0], z4, 0, 0, 0), 0, 0, 0);
            c1 = __builtin_amdgcn_mfma_f32_16x16x32_bf16(k1, w2f[1][1],
                 __builtin_amdgcn_mfma_f32_16x16x32_bf16(k0, w2f[0][1], z4, 0, 0, 0), 0, 0, 0);
            c2 = __builtin_amdgcn_mfma_f32_16x16x32_bf16(k1, w2f[1][2],
                 __builtin_amdgcn_mfma_f32_16x16x32_bf16(k0, w2f[0][2], z4, 0, 0, 0), 0, 0, 0);
            c3 = __builtin_amdgcn_mfma_f32_16x16x32_bf16(k1, w2f[1][3],
                 __builtin_amdgcn_mfma_f32_16x16x32_bf16(k0, w2f[0][3], z4, 0, 0, 0), 0, 0, 0);
        }

        float z0 = 0.f, z1 = 0.f, z2 = 0.f, z3 = 0.f;
        #pragma unroll
        for (int i = 0; i < 4; i++) {
            float h0 = gelu_fast(c0[i] + b2v[0]), h1 = gelu_fast(c1[i] + b2v[1]);
            float h2 = gelu_fast(c2[i] + b2v[2]), h3 = gelu_fast(c3[i] + b2v[3]);
            float z = h0 * w3dv[0] + h1 * w3dv[1] + h2 * w3dv[2] + h3 * w3dv[3];
            if (i == 0) z0 = z; else if (i == 1) z1 = z; else if (i == 2) z2 = z; else z3 = z;
        }
        #pragma unroll
        for (int off = 1; off < 16; off <<= 1) {
            z0 += __shfl_xor(z0, off); z1 += __shfl_xor(z1, off);
            z2 += __shfl_xor(z2, off); z3 += __shfl_xor(z3, off);
        }
        if (r2 < 4) {
            int e2 = base + grp * 4 + r2;
            if (e2 < E) {
                float zsel = (r2 == 0) ? z0 : (r2 == 1) ? z1 : (r2 == 2) ? z2 : z3;
                float g0v = gumbel[2 * (long long)e2], g1v = gumbel[2 * (long long)e2 + 1];
                float m = zsel + b3d + g1v - g0v;
                eval_[e2] = (m > 0.f) ? 1.f : 0.f;
                flagv[e2] = (fabsf(m) < FBTHR) ? 1 : 0;
            }
        }
    }
}

// ---------------- block-aggregated flag -> list compaction ----------------
__global__ __launch_bounds__(256) void k_compact(const unsigned char* __restrict__ flagv,
                                                 int* __restrict__ flcnt,
                                                 int* __restrict__ fllist, int E) {
    __shared__ int s[256];
    __shared__ int sbase;
    const int t = threadIdx.x;
    const long long base = (long long)blockIdx.x * (256 * CEPT) + (long long)t * CEPT;

    unsigned char fl[CEPT];
    #pragma unroll
    for (int u = 0; u < CEPT; u += 16) {
        int4 w = make_int4(0, 0, 0, 0);
        if (base + u + 15 < (long long)E) {
            w = *(const int4*)&flagv[base + u];
        } else {
            #pragma unroll
            for (int b2 = 0; b2 < 16; b2++) {
                long long idx = base + u + b2;
                ((unsigned char*)&w)[b2] = (idx < (long long)E) ? flagv[idx] : 0;
            }
        }
        *(int4*)&fl[u] = w;
    }
    int cnt = 0;
    #pragma unroll
    for (int u = 0; u < CEPT; u++) cnt += fl[u];

    s[t] = cnt;
    __syncthreads();
    for (int off = 1; off < 256; off <<= 1) {
        int xv = (t >= off) ? s[t - off] : 0;
        __syncthreads();
        s[t] += xv;
        __syncthreads();
    }
    if (t == 255) sbase = (s[255] > 0) ? atomicAdd(flcnt, s[255]) : 0;
    __syncthreads();

    int pos = sbase + s[t] - cnt;
    #pragma unroll
    for (int u = 0; u < CEPT; u++) {
        if (fl[u]) fllist[pos++] = (int)(base + u);
    }
}

// ---------------- wave-cooperative exact-fp32 fallback ----------------
__global__ __launch_bounds__(256) void k_edge_fb(
    const int* __restrict__ ei, const float* __restrict__ xt6,
    const float* __restrict__ attr, const float* __restrict__ gumbel,
    const float* __restrict__ W0, const float* __restrict__ b0,
    const float* __restrict__ W1, const float* __restrict__ b1,
    const float* __restrict__ W2, const float* __restrict__ b2,
    const float* __restrict__ W3, const float* __restrict__ b3,
    const int* __restrict__ fllist, const int* __restrict__ flcnt,
    float* __restrict__ eval_, int E, int nwaves) {
    __shared__ float buf[4][2][2][64];
    const int lane = threadIdx.x & 63;
    const int wv = threadIdx.x >> 6;
    const int wid = blockIdx.x * 4 + wv;
    const int jw = (lane < 50) ? lane : 49;

    float w0r[16], w1r[52], w2r[52];
    #pragma unroll
    for (int k = 0; k < 13; k++) w0r[k] = W0[k * 50 + jw];
    w0r[13] = 0.f; w0r[14] = 0.f; w0r[15] = 0.f;
    #pragma unroll
    for (int k = 0; k < 50; k++) w1r[k] = W1[k * 50 + jw];
    w1r[50] = 0.f; w1r[51] = 0.f;
    #pragma unroll
    for (int k = 0; k < 50; k++) w2r[k] = W2[k * 50 + jw];
    w2r[50] = 0.f; w2r[51] = 0.f;
    const float b0r = b0[jw], b1r = b1[jw], b2r = b2[jw];
    const float b3_0 = b3[0], b3_1 = b3[1];
    const float w3d = (lane < 50) ? (W3[lane * 2 + 1] - W3[lane * 2]) : 0.f;

    const int g = lane >> 4, r = lane & 15;
    const int cnt = *flcnt;

    for (int base = wid * 2; base < cnt; base += nwaves * 2) {
        if (g < 2) {
            int idx = base + g;
            float val = 0.f;
            if (idx < cnt && r < 13) {
                int e = fllist[idx];
                if (r == 12) val = attr[e];
                else if (r < 6) val = xt6[(size_t)ei[e] * 8 + r];
                else val = xt6[(size_t)ei[E + e] * 8 + (r - 6)];
            }
            buf[wv][0][g][r] = val;
        }

        const float4* a4 = (const float4*)(&buf[wv][0][0][0]);
        const float4* c4 = (const float4*)(&buf[wv][0][1][0]);
        float tA = b0r, tB = b0r;
        #pragma unroll
        for (int c = 0; c < 4; c++) {
            float4 a = a4[c], b = c4[c];
            tA += a.x * w0r[4 * c];     tB += b.x * w0r[4 * c];
            tA += a.y * w0r[4 * c + 1]; tB += b.y * w0r[4 * c + 1];
            tA += a.z * w0r[4 * c + 2]; tB += b.z * w0r[4 * c + 2];
            tA += a.w * w0r[4 * c + 3]; tB += b.w * w0r[4 * c + 3];
        }
        buf[wv][1][0][lane] = gelu_f(tA);
        buf[wv][1][1][lane] = gelu_f(tB);

        const float4* p4 = (const float4*)(&buf[wv][1][0][0]);
        const float4* q4 = (const float4*)(&buf[wv][1][1][0]);
        tA = b1r; tB = b1r;
        #pragma unroll
        for (int c = 0; c < 13; c++) {
            float4 a = p4[c], b = q4[c];
            tA += a.x * w1r[4 * c];     tB += b.x * w1r[4 * c];
            tA += a.y * w1r[4 * c + 1]; tB += b.y * w1r[4 * c + 1];
            tA += a.z * w1r[4 * c + 2]; tB += b.z * w1r[4 * c + 2];
            tA += a.w * w1r[4 * c + 3]; tB += b.w * w1r[4 * c + 3];
        }
        buf[wv][0][0][lane] = gelu_f(tA);
        buf[wv][0][1][lane] = gelu_f(tB);

        tA = b2r; tB = b2r;
        #pragma unroll
        for (int c = 0; c < 13; c++) {
            float4 a = a4[c], b = c4[c];
            tA += a.x * w2r[4 * c];     tB += b.x * w2r[4 * c];
            tA += a.y * w2r[4 * c + 1]; tB += b.y * w2r[4 * c + 1];
            tA += a.z * w2r[4 * c + 2]; tB += b.z * w2r[4 * c + 2];
            tA += a.w * w2r[4 * c + 3]; tB += b.w * w2r[4 * c + 3];
        }
        float h3A = gelu_f(tA), h3B = gelu_f(tB);
        buf[wv][1][0][lane] = h3A;
        buf[wv][1][1][lane] = h3B;

        float zA = h3A * w3d, zB = h3B * w3d;
        #pragma unroll
        for (int off = 32; off > 0; off >>= 1) {
            zA += __shfl_xor(zA, off);
            zB += __shfl_xor(zB, off);
        }

        if (lane < 2) {
            int idx = base + lane;
            if (idx < cnt) {
                int e = fllist[idx];
                float z = (lane == 0) ? zA : zB;
                float g0v = gumbel[2 * (long long)e], g1v = gumbel[2 * (long long)e + 1];
                float m = z + (b3_1 - b3_0) + g1v - g0v;
                float dec;
                if (fabsf(m) < 1e-4f) {
                    float z0 = 0.f, z1 = 0.f;
                    for (int j = 0; j < 50; j++) {
                        float h = buf[wv][1][lane][j];
                        z0 += h * W3[2 * j];
                        z1 += h * W3[2 * j + 1];
                    }
                    z0 += b3_0; z1 += b3_1;
                    dec = (z1 + g1v > z0 + g0v) ? 1.f : 0.f;
                } else {
                    dec = (m > 0.f) ? 1.f : 0.f;
                }
                eval_[e] = dec;
            }
        }
    }
}

// ---------------- CSR build: histogram (x4) + scan + scatter(+pack 8B) ----------------
__global__ void k_hist(const int* __restrict__ ei, int* __restrict__ cnt, int E) {
    int i = blockIdx.x * blockDim.x + threadIdx.x;
    int e = i * 4;
    if (e + 3 < E) {
        int4 d = *(const int4*)&ei[E + e];
        atomicAdd(&cnt[d.x], 1); atomicAdd(&cnt[d.y], 1);
        atomicAdd(&cnt[d.z], 1); atomicAdd(&cnt[d.w], 1);
    } else {
        for (int u = e; u < E; u++) atomicAdd(&cnt[ei[E + u]], 1);
    }
}

__global__ void k_scan_partial(const int* __restrict__ cnt, int* __restrict__ bsum, int N) {
    __shared__ int s[256];
    int b = blockIdx.x, t = threadIdx.x;
    int base = b * CHUNK + t * 4;
    int sum = 0;
    #pragma unroll
    for (int u = 0; u < 4; u++) { int idx = base + u; if (idx < N) sum += cnt[idx]; }
    s[t] = sum; __syncthreads();
    for (int off = 128; off > 0; off >>= 1) {
        if (t < off) s[t] += s[t + off];
        __syncthreads();
    }
    if (t == 0) bsum[b] = s[0];
}

__global__ void k_scan_top(const int* __restrict__ bsum, int* __restrict__ boff,
                           int* __restrict__ rowptr, int nb, int N, int E) {
    if (threadIdx.x == 0 && blockIdx.x == 0) {
        int run = 0;
        for (int i = 0; i < nb; i++) { boff[i] = run; run += bsum[i]; }
        rowptr[N] = E;
    }
}

__global__ void k_scan_final(const int* __restrict__ cnt, const int* __restrict__ boff,
                             int* __restrict__ rowptr, int* __restrict__ wpos, int N) {
    __shared__ int s[256];
    int b = blockIdx.x, t = threadIdx.x;
    int base = b * CHUNK + t * 4;
    int v0 = 0, v1 = 0, v2 = 0, v3 = 0;
    if (base     < N) v0 = cnt[base];
    if (base + 1 < N) v1 = cnt[base + 1];
    if (base + 2 < N) v2 = cnt[base + 2];
    if (base + 3 < N) v3 = cnt[base + 3];
    int ts = v0 + v1 + v2 + v3;
    s[t] = ts; __syncthreads();
    for (int off = 1; off < 256; off <<= 1) {
        int xv = (t >= off) ? s[t - off] : 0;
        __syncthreads();
        s[t] += xv;
        __syncthreads();
    }
    int excl = s[t] - ts + boff[b];
    if (base     < N) { rowptr[base]     = excl;                 wpos[base]     = excl; }
    if (base + 1 < N) { int p = excl + v0;           rowptr[base + 1] = p; wpos[base + 1] = p; }
    if (base + 2 < N) { int p = excl + v0 + v1;      rowptr[base + 2] = p; wpos[base + 2] = p; }
    if (base + 3 < N) { int p = excl + v0 + v1 + v2; rowptr[base + 3] = p; wpos[base + 3] = p; }
}

// scatter + pack 8B per-edge record {src, bf16(attr)<<16 | bf16(gate)} at CSR position
__global__ void k_scatter(const int* __restrict__ ei, const float* __restrict__ attr,
                          const float* __restrict__ eval_, int* __restrict__ wpos,
                          int2* __restrict__ epack, int E) {
    int e = blockIdx.x * blockDim.x + threadIdx.x;
    if (e >= E) return;
    int d = ei[E + e];
    int p = atomicAdd(&wpos[d], 1);
    unsigned ab = ((unsigned)(unsigned short)f2bf(attr[e]) << 16)
                | (unsigned)(unsigned short)f2bf(eval_[e]);
    epack[p] = make_int2(ei[e], (int)ab);
}

// ---------------- per-layer node transform: q fp32, k/v packed bf16 (one 128B line) ----------------
__global__ void k_qkvs(const float* __restrict__ hn,
                       const float* __restrict__ Wq, const float* __restrict__ bq,
                       const float* __restrict__ Wk, const float* __restrict__ bk,
                       const float* __restrict__ Wv, const float* __restrict__ bv,
                       const float* __restrict__ Ws, const float* __restrict__ bs,
                       float* __restrict__ q, unsigned short* __restrict__ kvp,
                       float* __restrict__ hnext, int N) {
    __shared__ float sWq[625], sWk[625], sWv[625], sWs[625], sbq[25], sbk[25], sbv[25], sbs[25];
    for (int i = threadIdx.x; i < 625; i += blockDim.x) {
        sWq[i] = Wq[i]; sWk[i] = Wk[i]; sWv[i] = Wv[i]; sWs[i] = Ws[i];
    }
    if (threadIdx.x < 25) {
        sbq[threadIdx.x] = bq[threadIdx.x]; sbk[threadIdx.x] = bk[threadIdx.x];
        sbv[threadIdx.x] = bv[threadIdx.x]; sbs[threadIdx.x] = bs[threadIdx.x];
    }
    __syncthreads();
    int gid = blockIdx.x * blockDim.x + threadIdx.x;
    int n = gid >> 5, j = gid & 31;
    if (n >= N) return;
    if (j >= HID) {
        kvp[(size_t)n * 64 + j] = 0;
        kvp[(size_t)n * 64 + 32 + j] = 0;
        return;
    }
    float h[25];
    #pragma unroll
    for (int i = 0; i < 25; i++) h[i] = hn[(size_t)n * STR + i];
    float aq = sbq[j], ak = sbk[j], av = sbv[j], as = sbs[j];
    #pragma unroll
    for (int i = 0; i < 25; i++) {
        float hi = h[i];
        aq += hi * sWq[i * 25 + j];
        ak += hi * sWk[i * 25 + j];
        av += hi * sWv[i * 25 + j];
        as += hi * sWs[i * 25 + j];
    }
    q[(size_t)n * STR + j] = aq;
    hnext[(size_t)n * STR + j] = as;
    kvp[(size_t)n * 64 + j] = (unsigned short)f2bf(ak);
    kvp[(size_t)n * 64 + 32 + j] = (unsigned short)f2bf(av);
}

// ---------------- fused node-centric attention, 8 lanes/node, bf16 kv single-line ----------------
__global__ void k_attn_node(const int* __restrict__ rowptr, const int2* __restrict__ epack,
                            const float* __restrict__ q, const unsigned short* __restrict__ kvp,
                            const float* __restrict__ We, const float* __restrict__ be,
                            float* __restrict__ hnext, int N) {
    int gid = blockIdx.x * blockDim.x + threadIdx.x;
    int n = gid >> 3, sub = gid & 7;
    if (n >= N) return;
    const float scale = 0.44721359549995793f;

    float qr[25];
    #pragma unroll
    for (int i = 0; i < 25; i++) qr[i] = q[(size_t)n * STR + i];

    float qW0[5], qW1[5], qbe[5];
    #pragma unroll
    for (int h = 0; h < 5; h++) {
        float a0 = 0.f, a1 = 0.f, ab = 0.f;
        #pragma unroll
        for (int c = 0; c < 5; c++) {
            int i = h * 5 + c;
            a0 += qr[i] * We[i];
            a1 += qr[i] * We[25 + i];
            ab += qr[i] * be[i];
        }
        qW0[h] = a0; qW1[h] = a1; qbe[h] = ab;
    }

    float accV[25];
    #pragma unroll
    for (int i = 0; i < 25; i++) accV[i] = 0.f;
    float den[5] = {0, 0, 0, 0, 0}, sA[5] = {0, 0, 0, 0, 0}, sG[5] = {0, 0, 0, 0, 0};

    int beg = rowptr[n], end = rowptr[n + 1];
    for (int p = beg + sub; p < end; p += 8) {
        int2 ep = epack[p];
        int s = ep.x;
        unsigned ab = (unsigned)ep.y;
        float a_ = __uint_as_float(ab & 0xffff0000u);
        float gl = __uint_as_float(ab << 16);
        const unsigned* kw = (const unsigned*)(kvp + (size_t)s * 64);

        float al[5];
        #pragma unroll
        for (int h = 0; h < 5; h++) al[h] = qW0[h] * a_ + qW1[h] * gl + qbe[h];
        #pragma unroll
        for (int w = 0; w < 12; w++) {
            unsigned u = kw[w];
            al[(2 * w) / 5]     = fmaf(__uint_as_float(u << 16), qr[2 * w], al[(2 * w) / 5]);
            al[(2 * w + 1) / 5] = fmaf(__uint_as_float(u & 0xffff0000u), qr[2 * w + 1], al[(2 * w + 1) / 5]);
        }
        al[4] = fmaf(__uint_as_float(kw[12] << 16), qr[24], al[4]);

        float exh[5];
        #pragma unroll
        for (int h = 0; h < 5; h++) {
            float ex = __expf(al[h] * scale);
            exh[h] = ex;
            den[h] += ex;
            sA[h] += ex * a_;
            sG[h] += ex * gl;
        }
        #pragma unroll
        for (int w = 0; w < 12; w++) {
            unsigned u = kw[16 + w];
            accV[2 * w]     = fmaf(exh[(2 * w) / 5], __uint_as_float(u << 16), accV[2 * w]);
            accV[2 * w + 1] = fmaf(exh[(2 * w + 1) / 5], __uint_as_float(u & 0xffff0000u), accV[2 * w + 1]);
        }
        accV[24] = fmaf(exh[4], __uint_as_float(kw[28] << 16), accV[24]);
    }

    #pragma unroll
    for (int off = 1; off < 8; off <<= 1) {
        #pragma unroll
        for (int i = 0; i < 25; i++) accV[i] += __shfl_xor(accV[i], off);
        #pragma unroll
        for (int h = 0; h < 5; h++) {
            den[h] += __shfl_xor(den[h], off);
            sA[h] += __shfl_xor(sA[h], off);
            sG[h] += __shfl_xor(sG[h], off);
        }
    }

    if (sub == 0) {
        #pragma unroll
        for (int h = 0; h < 5; h++) {
            float inv = 1.f / (den[h] + 1e-16f);
            #pragma unroll
            for (int c = 0; c < 5; c++) {
                int i = h * 5 + c;
                float agg = (accV[i] + sA[h] * We[i] + sG[h] * We[25 + i] + den[h] * be[i]) * inv;
                hnext[(size_t)n * STR + i] += agg;
            }
        }
    }
}

// ---------------- output ----------------
__global__ void k_out(const float* __restrict__ hn, const float* __restrict__ W,
                      const float* __restrict__ b, float* __restrict__ out, int N) {
    int n = blockIdx.x * blockDim.x + threadIdx.x;
    if (n >= N) return;
    float acc = b[0];
    #pragma unroll
    for (int i = 0; i < 25; i++) acc += hn[(size_t)n * STR + i] * W[i];
    out[n] = 1.f / (1.f + expf(-acc));
}

extern "C" void kernel_launch(void* const* d_in, const int* in_sizes, int n_in,
                              void* d_out, int out_size, void* d_ws, size_t ws_size,
                              hipStream_t stream) {
    const float* x      = (const float*)d_in[0];
    const float* token  = (const float*)d_in[1];
    const float* attr   = (const float*)d_in[2];
    const float* gumbel = (const float*)d_in[3];
    const int*   ei     = (const int*)d_in[4];
    const float* W0 = (const float*)d_in[5];
    const float* b0 = (const float*)d_in[6];
    const float* W1 = (const float*)d_in[7];
    const float* b1 = (const float*)d_in[8];
    const float* W2 = (const float*)d_in[9];
    const float* b2 = (const float*)d_in[10];
    const float* W3 = (const float*)d_in[11];
    const float* b3 = (const float*)d_in[12];
    const float* ilW = (const float*)d_in[13];
    const float* ilb = (const float*)d_in[14];
    const float* Wq = (const float*)d_in[15];
    const float* bq = (const float*)d_in[16];
    const float* Wk = (const float*)d_in[17];
    const float* bk = (const float*)d_in[18];
    const float* Wv = (const float*)d_in[19];
    const float* bv = (const float*)d_in[20];
    const float* We = (const float*)d_in[21];
    const float* be = (const float*)d_in[22];
    const float* Ws = (const float*)d_in[23];
    const float* bs = (const float*)d_in[24];
    const float* oW = (const float*)d_in[25];
    const float* ob = (const float*)d_in[26];

    const int N = in_sizes[0];
    const int E = in_sizes[2];
    const int nb_chunk = (N + CHUNK - 1) / CHUNK;

    char* ws = (char*)d_ws;
    size_t off = 0;
    auto alloc = [&](size_t nb) -> void* {
        void* p = ws + off;
        off += (nb + 255) & ~(size_t)255;
        return p;
    };
    float* hnA    = (float*)alloc((size_t)N * STR * 4);
    float* hnB    = (float*)alloc((size_t)N * STR * 4);
    float* q      = (float*)alloc((size_t)N * STR * 4);
    unsigned short* kvp = (unsigned short*)alloc((size_t)N * 64 * 2);
    float* evalv  = (float*)alloc((size_t)E * 4);
    float* xt6    = (float*)alloc((size_t)N * 8 * 4);
    int*   cnt    = (int*)alloc((size_t)N * 4);
    int*   rowptr = (int*)alloc((size_t)(N + 1) * 4);
    int*   wpos   = (int*)alloc((size_t)N * 4);
    int*   bsum   = (int*)alloc((size_t)(nb_chunk + 1) * 4);
    int*   boff   = (int*)alloc((size_t)(nb_chunk + 1) * 4);
    int2*  epack  = (int2*)alloc((size_t)E * 8);
    int*   flcnt  = (int*)alloc(256);
    int*   fllist = (int*)alloc((size_t)E * 4);
    unsigned char* flagv = (unsigned char*)alloc((size_t)E);

    int nb_n32  = (N * STR + 255) / 256;
    int nb_n32b = (N * STR + 511) / 512;
    int nb_e    = (E + 255) / 256;
    int nb_e4   = ((E + 3) / 4 + 255) / 256;
    int nb_n8   = (N * 8 + 255) / 256;
    int nb_n    = (N + 255) / 256;
    int nb_cmp  = (E + 256 * CEPT - 1) / (256 * CEPT);

    const int mlp_blocks = 4096;
    const int mlp_waves  = mlp_blocks * 4;
    const int ntiles     = (E + 15) / 16;

    hipMemsetAsync(cnt, 0, (size_t)N * 4, stream);
    hipMemsetAsync(flcnt, 0, 4, stream);
    k_node_in<<<nb_n32, 256, 0, stream>>>(x, token, ilW, ilb, hnA, xt6, N);
    k_edge_mlp_mfma<<<mlp_blocks, 256, 0, stream>>>(ei, xt6, attr, gumbel,
                                                    W0, b0, W1, b1, W2, b2, W3, b3,
                                                    evalv, flagv, E, ntiles, mlp_waves);
    k_compact<<<nb_cmp, 256, 0, stream>>>(flagv, flcnt, fllist, E);
    k_edge_fb<<<2048, 256, 0, stream>>>(ei, xt6, attr, gumbel,
                                        W0, b0, W1, b1, W2, b2, W3, b3,
                                        fllist, flcnt, evalv, E, 2048 * 4);
    k_hist<<<nb_e4, 256, 0, stream>>>(ei, cnt, E);
    k_scan_partial<<<nb_chunk, 256, 0, stream>>>(cnt, bsum, N);
    k_scan_top<<<1, 64, 0, stream>>>(bsum, boff, rowptr, nb_chunk, N, E);
    k_scan_final<<<nb_chunk, 256, 0, stream>>>(cnt, boff, rowptr, wpos, N);
    k_scatter<<<nb_e, 256, 0, stream>>>(ei, attr, evalv, wpos, epack, E);

    float* cur = hnA;
    float* nxt = hnB;
    for (int l = 0; l < 3; l++) {
        k_qkvs<<<nb_n32b, 512, 0, stream>>>(cur, Wq + l * 625, bq + l * 25,
                                            Wk + l * 625, bk + l * 25,
                                            Wv + l * 625, bv + l * 25,
                                            Ws + l * 625, bs + l * 25,
                                            q, kvp, nxt, N);
        k_attn_node<<<nb_n8, 256, 0, stream>>>(rowptr, epack, q, kvp,
                                               We + l * 50, be + l * 25, nxt, N);
        float* t = cur; cur = nxt; nxt = t;
    }
    k_out<<<nb_n, 256, 0, stream>>>(cur, oW, ob, (float*)d_out, N);
}